// Round 1
// baseline (2174.232 us; speedup 1.0000x reference)
//
#include <hip/hip_runtime.h>
#include <cstdint>
#include <cstddef>

#define DEV static __device__ __forceinline__

typedef float  f32x4 __attribute__((ext_vector_type(4)));
typedef short  s16x8 __attribute__((ext_vector_type(8)));
typedef unsigned short u16;
typedef unsigned short u16x4 __attribute__((ext_vector_type(4)));
typedef __bf16 bf16x8 __attribute__((ext_vector_type(8)));

DEV float bf2f(u16 v){ union { unsigned u; float f; } x; x.u = ((unsigned)v) << 16; return x.f; }
DEV u16 f2bf(float f){ union { float f; unsigned u; } x; x.f = f; unsigned u = x.u;
                       u += 0x7fffu + ((u >> 16) & 1u); return (u16)(u >> 16); }

DEV f32x4 mfma16(s16x8 a, s16x8 b, f32x4 c){
  return __builtin_amdgcn_mfma_f32_16x16x32_bf16(
      __builtin_bit_cast(bf16x8, a), __builtin_bit_cast(bf16x8, b), c, 0, 0, 0);
}

// async global->LDS, 16B per lane; LDS dest = wave-uniform base + lane*16
DEV void gld16(const void* g, void* l){
  __builtin_amdgcn_global_load_lds(
      (const __attribute__((address_space(1))) void*)(uintptr_t)g,
      (__attribute__((address_space(3))) void*)(unsigned)(uintptr_t)l,
      16, 0, 0);
}

// ---------------- transpose + fp32->bf16 convert: src[K][N] -> dst[N][K] ----------------
__global__ void __launch_bounds__(256)
transpose_cvt(const float* __restrict__ src, u16* __restrict__ dst, int K, int N){
  int z = blockIdx.z;
  src += (size_t)z * K * N;
  dst += (size_t)z * K * N;
  __shared__ float t[32][33];
  int n0 = blockIdx.x * 32, k0 = blockIdx.y * 32;
#pragma unroll
  for (int i = 0; i < 4; ++i)
    t[threadIdx.y + 8*i][threadIdx.x] = src[(size_t)(k0 + threadIdx.y + 8*i) * N + n0 + threadIdx.x];
  __syncthreads();
#pragma unroll
  for (int i = 0; i < 4; ++i)
    dst[(size_t)(n0 + threadIdx.y + 8*i) * K + k0 + threadIdx.x] = f2bf(t[threadIdx.x][threadIdx.y + 8*i]);
}

// ---------------- fp32 -> bf16 flat convert (bias) ----------------
__global__ void __launch_bounds__(256)
cvt_bias(const float* __restrict__ in, u16* __restrict__ out){
  size_t i = ((size_t)blockIdx.x * 256 + threadIdx.x) * 4;
  f32x4 v = *(const f32x4*)(in + i);
  u16x4 o;
#pragma unroll
  for (int j = 0; j < 4; ++j) o[j] = f2bf(v[j]);
  *(u16x4*)(out + i) = o;
}

// ---------------- LayerNorm over D=768, one block per row ----------------
template<typename OUT>
__global__ void __launch_bounds__(256)
ln_kernel(const float* __restrict__ x, const float* __restrict__ w,
          const float* __restrict__ bsh, OUT* __restrict__ out){
  int row = blockIdx.x, tid = threadIdx.x;
  const float* xr = x + (size_t)row * 768;
  float v0 = xr[tid], v1 = xr[tid + 256], v2 = xr[tid + 512];
  float s = v0 + v1 + v2, s2 = v0*v0 + v1*v1 + v2*v2;
#pragma unroll
  for (int off = 1; off < 64; off <<= 1){ s += __shfl_xor(s, off); s2 += __shfl_xor(s2, off); }
  __shared__ float red[8];
  int wid = tid >> 6;
  if ((tid & 63) == 0){ red[wid] = s; red[wid + 4] = s2; }
  __syncthreads();
  s  = red[0] + red[1] + red[2] + red[3];
  s2 = red[4] + red[5] + red[6] + red[7];
  float m = s * (1.f/768.f);
  float var = s2 * (1.f/768.f) - m * m;
  float rstd = rsqrtf(var + 1e-5f);
  OUT* orow = out + (size_t)row * 768;
#pragma unroll
  for (int i = 0; i < 3; ++i){
    int c = tid + 256 * i;
    float vv = (i == 0 ? v0 : (i == 1 ? v1 : v2));
    float o = (vv - m) * rstd * w[c] + bsh[c];
    if constexpr (sizeof(OUT) == 2) orow[c] = f2bf(o);
    else                            orow[c] = o;
  }
}

// ---------------- bf16 GEMM: C[M,N] = A[M,K] @ B[K,N], B given transposed [N][K] --------
// 128x128 tile, BK=32, 4 waves (2x2), m97 structure.
// EPI 0: store bf16 into Cb (ldc, possibly pre-offset)
// EPI 1: Cf[row*ldc+col] = acc + bias[col] + resid[row*ldc+col]  (fp32, in-place safe)
// EPI 2: Cb = bf16( gelu(acc + bias[col]) )   exact gelu
template<int EPI>
__global__ void __launch_bounds__(256)
gemm_bf16(const u16* __restrict__ A, int lda, const u16* __restrict__ Bt, int ldb,
          int nk, u16* __restrict__ Cb, float* __restrict__ Cf, int ldc,
          const float* __restrict__ bias, const float* __restrict__ resid){
  __shared__ u16 As[128 * 32];
  __shared__ u16 Bs[128 * 32];
  const int tid = threadIdx.x, w = tid >> 6, lane = tid & 63;
  const int l16 = lane & 15, g = lane >> 4;
  const int m0 = blockIdx.x * 128, n0 = blockIdx.y * 128;
  const int wm = (w >> 1) * 64, wn = (w & 1) * 64;
  f32x4 acc[4][4] = {};

  // staging map: linear LDS byte L = (w + 4i)*1024 + lane*16  ->  row = L>>6, short-col = (L&63)>>1
  const int L0 = (w) * 1024 + lane * 16;
  const int L1 = (w + 4) * 1024 + lane * 16;
  const int r0 = L0 >> 6, c0 = (L0 & 63) >> 1;
  const int r1 = L1 >> 6, c1 = (L1 & 63) >> 1;
  const u16* a0 = A  + (size_t)(m0 + r0) * lda + c0;
  const u16* a1 = A  + (size_t)(m0 + r1) * lda + c1;
  const u16* b0 = Bt + (size_t)(n0 + r0) * ldb + c0;
  const u16* b1 = Bt + (size_t)(n0 + r1) * ldb + c1;
  char* asb = (char*)As; char* bsb = (char*)Bs;

  for (int kt = 0; kt < nk; ++kt){
    const int k0 = kt * 32;
    __syncthreads();                       // protect LDS from previous iter readers
    gld16(a0 + k0, asb + (w    ) * 1024);
    gld16(a1 + k0, asb + (w + 4) * 1024);
    gld16(b0 + k0, bsb + (w    ) * 1024);
    gld16(b1 + k0, bsb + (w + 4) * 1024);
    __syncthreads();                       // drains vmcnt(0): LDS tiles ready

    s16x8 af[4], bfv[4];
#pragma unroll
    for (int mi = 0; mi < 4; ++mi)
      af[mi] = *(const s16x8*)(As + (wm + mi*16 + l16) * 32 + 8 * g);
#pragma unroll
    for (int ni = 0; ni < 4; ++ni)
      bfv[ni] = *(const s16x8*)(Bs + (wn + ni*16 + l16) * 32 + 8 * g);
#pragma unroll
    for (int mi = 0; mi < 4; ++mi)
#pragma unroll
      for (int ni = 0; ni < 4; ++ni)
        acc[mi][ni] = mfma16(af[mi], bfv[ni], acc[mi][ni]);
  }

  // epilogue: C/D layout col = lane&15, row = 4*(lane>>4)+r  [HW-verified]
#pragma unroll
  for (int mi = 0; mi < 4; ++mi){
    const int rg = m0 + wm + mi*16 + 4*g;
#pragma unroll
    for (int ni = 0; ni < 4; ++ni){
      const int col = n0 + wn + ni*16 + l16;
      f32x4 v = acc[mi][ni];
#pragma unroll
      for (int r = 0; r < 4; ++r){
        const int row = rg + r;
        if constexpr (EPI == 0){
          Cb[(size_t)row * ldc + col] = f2bf(v[r]);
        } else if constexpr (EPI == 1){
          Cf[(size_t)row * ldc + col] = v[r] + bias[col] + resid[(size_t)row * ldc + col];
        } else {
          float t = v[r] + bias[col];
          float ge = 0.5f * t * (1.0f + erff(t * 0.7071067811865476f));
          Cb[(size_t)row * ldc + col] = f2bf(ge);
        }
      }
    }
  }
}

// ---------------- fused flash attention with additive bias ----------------
// qkv: [4096][2304] bf16 rows = b*2048+n, cols = q|k|v each H*64
// bias: [12][2048][2048] (BT = u16 bf16, or float straight from input)
// out: [4096][768] bf16, already merged heads, softmax-normalized
// grid (16 qtiles, 12 heads, 2 batch), 256 threads = 4 waves, 32 q-rows/wave, KV step 64.
template<typename BT>
__global__ void __launch_bounds__(256)
attn_kernel(const u16* __restrict__ qkv, const BT* __restrict__ bias, u16* __restrict__ out){
  __shared__ u16 Ks[64 * 64];       // [kv][dh], XOR-swizzled rows
  __shared__ u16 Vt[64 * 72];       // [dh][kv+pad]
  __shared__ u16 Bs[128 * 64];      // bias tile [q][kv], XOR-swizzled rows
  __shared__ u16 Pl[4 * 32 * 72];   // per-wave P [q][kv+pad]

  const int tid = threadIdx.x, w = tid >> 6, lane = tid & 63;
  const int l16 = lane & 15, g = lane >> 4;
  const int qt = blockIdx.x, h = blockIdx.y, b = blockIdx.z;
  const int rowbase = b * 2048;
  const int q0 = qt * 128;
  const int qw = q0 + w * 32;
  const float SCALE = 0.125f;

  // Q fragments (B-operand of swapped QK^T): qf[ks][ni], 8 bf16 contiguous along dh
  s16x8 qf[2][2];
#pragma unroll
  for (int ni = 0; ni < 2; ++ni){
    const u16* qrow = qkv + (size_t)(rowbase + qw + l16 + 16*ni) * 2304 + h * 64;
#pragma unroll
    for (int ks = 0; ks < 2; ++ks)
      qf[ks][ni] = *(const s16x8*)(qrow + 32*ks + 8*g);
  }

  f32x4 oacc[2][4] = {};
  float mrun[2] = {-3.0e38f, -3.0e38f};
  float lrun[2] = {0.f, 0.f};

  const int kvr = tid >> 2, c4 = tid & 3;
  const int qb = tid >> 1, half = tid & 1;

  for (int kv0 = 0; kv0 < 2048; kv0 += 64){
    __syncthreads();
    { // stage K [64][64], rows swizzled: short-col ^= (row&7)<<3
      const u16* kg = qkv + (size_t)(rowbase + kv0 + kvr) * 2304 + 768 + h * 64;
      s16x8 ka = *(const s16x8*)(kg + c4 * 8);
      s16x8 kb = *(const s16x8*)(kg + (c4 + 4) * 8);
      const int sw = (kvr & 7) << 3;
      *(s16x8*)(Ks + kvr * 64 + ((c4 * 8) ^ sw)) = ka;
      *(s16x8*)(Ks + kvr * 64 + (((c4 + 4) * 8) ^ sw)) = kb;
    }
    { // stage V transposed: Vt[dh][kv]
      const u16* vg = qkv + (size_t)(rowbase + kv0 + kvr) * 2304 + 1536 + h * 64;
      s16x8 va = *(const s16x8*)(vg + c4 * 8);
      s16x8 vb = *(const s16x8*)(vg + (c4 + 4) * 8);
#pragma unroll
      for (int j = 0; j < 8; ++j){
        Vt[(c4 * 8 + j) * 72 + kvr]       = va[j];
        Vt[((c4 + 4) * 8 + j) * 72 + kvr] = vb[j];
      }
    }
    { // stage bias tile [128 q][64 kv] as bf16, rows swizzled
      const int sw = (qb & 7) << 3;
      if constexpr (sizeof(BT) == 2){
        const u16* bg = (const u16*)bias + ((size_t)h * 2048 + q0 + qb) * 2048 + kv0;
#pragma unroll
        for (int rr = 0; rr < 4; ++rr){
          const int ch = half + 2 * rr;
          s16x8 t = *(const s16x8*)(bg + ch * 8);
          *(s16x8*)(Bs + qb * 64 + ((ch * 8) ^ sw)) = t;
        }
      } else {
        const float* bg = (const float*)bias + ((size_t)h * 2048 + q0 + qb) * 2048 + kv0;
#pragma unroll
        for (int rr = 0; rr < 4; ++rr){
          const int ch = half + 2 * rr;
          f32x4 f0 = *(const f32x4*)(bg + ch * 8);
          f32x4 f1 = *(const f32x4*)(bg + ch * 8 + 4);
          s16x8 t;
#pragma unroll
          for (int j = 0; j < 4; ++j){ t[j] = (short)f2bf(f0[j]); t[4 + j] = (short)f2bf(f1[j]); }
          *(s16x8*)(Bs + qb * 64 + ((ch * 8) ^ sw)) = t;
        }
      }
    }
    __syncthreads();

    // ---- S^T = K * Q^T  (st[mi][ni]: q = l16+16ni (col), kv = 4g+r+16mi (row)) ----
    f32x4 st[4][2] = {};
    const int swr = (l16 & 7) << 3;
#pragma unroll
    for (int mi = 0; mi < 4; ++mi){
      const int row = l16 + 16 * mi;
      s16x8 kf0 = *(const s16x8*)(Ks + row * 64 + ((8 * g) ^ swr));
      s16x8 kf1 = *(const s16x8*)(Ks + row * 64 + ((32 + 8 * g) ^ swr));
#pragma unroll
      for (int ni = 0; ni < 2; ++ni){
        st[mi][ni] = mfma16(kf0, qf[0][ni], st[mi][ni]);
        st[mi][ni] = mfma16(kf1, qf[1][ni], st[mi][ni]);
      }
    }

    // ---- scale + bias + online softmax per q column ----
    float alpha[2];
#pragma unroll
    for (int ni = 0; ni < 2; ++ni){
      const int qrow = w * 32 + l16 + 16 * ni;        // block-local q for Bs
      float tmax = -3.0e38f;
#pragma unroll
      for (int mi = 0; mi < 4; ++mi){
        u16x4 bb = *(const u16x4*)(Bs + qrow * 64 + ((16 * mi + 4 * g) ^ swr));
#pragma unroll
        for (int r = 0; r < 4; ++r){
          float t = st[mi][ni][r] * SCALE + bf2f(bb[r]);
          st[mi][ni][r] = t;
          tmax = fmaxf(tmax, t);
        }
      }
      tmax = fmaxf(tmax, __shfl_xor(tmax, 16));
      tmax = fmaxf(tmax, __shfl_xor(tmax, 32));
      float mnew = fmaxf(mrun[ni], tmax);
      alpha[ni] = __expf(mrun[ni] - mnew);
      mrun[ni] = mnew;
      float ssum = 0.f;
#pragma unroll
      for (int mi = 0; mi < 4; ++mi){
        u16x4 pk;
#pragma unroll
        for (int r = 0; r < 4; ++r){
          float pv = __expf(st[mi][ni][r] - mnew);
          ssum += pv;
          pk[r] = f2bf(pv);
        }
        *(u16x4*)(Pl + w * 2304 + (l16 + 16 * ni) * 72 + 16 * mi + 4 * g) = pk;
      }
      ssum += __shfl_xor(ssum, 16);
      ssum += __shfl_xor(ssum, 32);
      lrun[ni] = lrun[ni] * alpha[ni] + ssum;
    }

    // ---- rescale O (O rows q = 4g+r+16mi2; alpha lives at lanes with l16 == q%16) ----
#pragma unroll
    for (int mi2 = 0; mi2 < 2; ++mi2){
#pragma unroll
      for (int r = 0; r < 4; ++r){
        float aq = __shfl(alpha[mi2], 20 * g + r);
#pragma unroll
        for (int ni2 = 0; ni2 < 4; ++ni2) oacc[mi2][ni2][r] *= aq;
      }
    }

    // ---- O += P @ V ----
#pragma unroll
    for (int ks2 = 0; ks2 < 2; ++ks2){
      s16x8 pf[2], vf[4];
#pragma unroll
      for (int mi2 = 0; mi2 < 2; ++mi2)
        pf[mi2] = *(const s16x8*)(Pl + w * 2304 + (mi2 * 16 + l16) * 72 + 32 * ks2 + 8 * g);
#pragma unroll
      for (int ni2 = 0; ni2 < 4; ++ni2)
        vf[ni2] = *(const s16x8*)(Vt + (l16 + 16 * ni2) * 72 + 32 * ks2 + 8 * g);
#pragma unroll
      for (int mi2 = 0; mi2 < 2; ++mi2)
#pragma unroll
        for (int ni2 = 0; ni2 < 4; ++ni2)
          oacc[mi2][ni2] = mfma16(pf[mi2], vf[ni2], oacc[mi2][ni2]);
    }
  }

  // ---- finalize: divide by l, write merged-head output ----
#pragma unroll
  for (int mi2 = 0; mi2 < 2; ++mi2){
#pragma unroll
    for (int r = 0; r < 4; ++r){
      float lq = __shfl(lrun[mi2], 20 * g + r);
      float inv = 1.0f / lq;
      const int row = rowbase + qw + 16 * mi2 + 4 * g + r;
#pragma unroll
      for (int ni2 = 0; ni2 < 4; ++ni2)
        out[(size_t)row * 768 + h * 64 + l16 + 16 * ni2] = f2bf(oacc[mi2][ni2][r] * inv);
    }
  }
}

// ============================== host ==============================
extern "C" void kernel_launch(void* const* d_in, const int* in_sizes, int n_in,
                              void* d_out, int out_size, void* d_ws, size_t ws_size,
                              hipStream_t stream){
  const float* in_x    = (const float*)d_in[0];
  const float* in_ctx  = (const float*)d_in[1];
  const float* in_bias = (const float*)d_in[2];
  const float* ln1_w = (const float*)d_in[3];
  const float* ln1_b = (const float*)d_in[4];
  const float* w_qkv = (const float*)d_in[5];
  const float* w_so  = (const float*)d_in[6];
  const float* b_so  = (const float*)d_in[7];
  const float* ln2_w = (const float*)d_in[8];
  const float* ln2_b = (const float*)d_in[9];
  const float* w_q   = (const float*)d_in[10];
  const float* w_k   = (const float*)d_in[11];
  const float* w_v   = (const float*)d_in[12];
  const float* w_co  = (const float*)d_in[13];
  const float* b_co  = (const float*)d_in[14];
  const float* ln3_w = (const float*)d_in[15];
  const float* ln3_b = (const float*)d_in[16];
  const float* w_f1  = (const float*)d_in[17];
  const float* b_f1  = (const float*)d_in[18];
  const float* w_f2  = (const float*)d_in[19];
  const float* b_f2  = (const float*)d_in[20];
  const float* lnout_w = (const float*)d_in[21];
  const float* lnout_b = (const float*)d_in[22];

  char* p = (char*)d_ws;
  float* xbuf  = (float*)p;  p += 4096ll * 768 * 4;
  u16* xn      = (u16*)p;    p += 4096ll * 768 * 2;
  u16* cn      = (u16*)p;    p += 4096ll * 768 * 2;
  u16* qkvb    = (u16*)p;    p += 4096ll * 2304 * 2;
  u16* attO    = (u16*)p;    p += 4096ll * 768 * 2;
  u16* ffh     = (u16*)p;    p += 4096ll * 3072 * 2;
  u16* wqkvT   = (u16*)p;    p += 4ll * 2304 * 768 * 2;
  u16* wsoT    = (u16*)p;    p += 4ll * 768 * 768 * 2;
  u16* wqT     = (u16*)p;    p += 4ll * 768 * 768 * 2;
  u16* wkT     = (u16*)p;    p += 4ll * 768 * 768 * 2;
  u16* wvT     = (u16*)p;    p += 4ll * 768 * 768 * 2;
  u16* wcoT    = (u16*)p;    p += 4ll * 768 * 768 * 2;
  u16* wf1T    = (u16*)p;    p += 4ll * 3072 * 768 * 2;
  u16* wf2T    = (u16*)p;    p += 4ll * 768 * 3072 * 2;
  u16* biasbf  = (u16*)p;    p += 12ll * 2048 * 2048 * 2;
  const bool bf16bias = ((size_t)(p - (char*)d_ws) <= ws_size);  // 240 MiB full / 144 MiB w/o bias

  hipMemcpyAsync(xbuf, in_x, 4096ll * 768 * 4, hipMemcpyDeviceToDevice, stream);

  const dim3 tb(32, 8);
  transpose_cvt<<<dim3(72, 24, 4), tb, 0, stream>>>(w_qkv, wqkvT, 768, 2304);
  transpose_cvt<<<dim3(24, 24, 4), tb, 0, stream>>>(w_so,  wsoT,  768, 768);
  transpose_cvt<<<dim3(24, 24, 4), tb, 0, stream>>>(w_q,   wqT,   768, 768);
  transpose_cvt<<<dim3(24, 24, 4), tb, 0, stream>>>(w_k,   wkT,   768, 768);
  transpose_cvt<<<dim3(24, 24, 4), tb, 0, stream>>>(w_v,   wvT,   768, 768);
  transpose_cvt<<<dim3(24, 24, 4), tb, 0, stream>>>(w_co,  wcoT,  768, 768);
  transpose_cvt<<<dim3(96, 24, 4), tb, 0, stream>>>(w_f1,  wf1T,  768, 3072);
  transpose_cvt<<<dim3(24, 96, 4), tb, 0, stream>>>(w_f2,  wf2T,  3072, 768);
  if (bf16bias) cvt_bias<<<49152, 256, 0, stream>>>(in_bias, biasbf);

  const dim3 ag(16, 12, 2);
  for (int i = 0; i < 4; ++i){
    // self-attention block
    ln_kernel<u16><<<4096, 256, 0, stream>>>(xbuf, ln1_w + i*768, ln1_b + i*768, xn);
    gemm_bf16<0><<<dim3(32, 18), 256, 0, stream>>>(xn, 768, wqkvT + (size_t)i*2304*768, 768, 24,
                                                   qkvb, nullptr, 2304, nullptr, nullptr);
    if (bf16bias) attn_kernel<u16>  <<<ag, 256, 0, stream>>>(qkvb, biasbf,  attO);
    else          attn_kernel<float><<<ag, 256, 0, stream>>>(qkvb, in_bias, attO);
    gemm_bf16<1><<<dim3(32, 6), 256, 0, stream>>>(attO, 768, wsoT + (size_t)i*768*768, 768, 24,
                                                  nullptr, xbuf, 768, b_so + i*768, xbuf);
    // cross-attention block
    ln_kernel<u16><<<4096, 256, 0, stream>>>(xbuf,   ln2_w + i*768, ln2_b + i*768, xn);
    ln_kernel<u16><<<4096, 256, 0, stream>>>(in_ctx, ln2_w + i*768, ln2_b + i*768, cn);
    gemm_bf16<0><<<dim3(32, 6), 256, 0, stream>>>(xn, 768, wqT + (size_t)i*768*768, 768, 24,
                                                  qkvb,        nullptr, 2304, nullptr, nullptr);
    gemm_bf16<0><<<dim3(32, 6), 256, 0, stream>>>(cn, 768, wkT + (size_t)i*768*768, 768, 24,
                                                  qkvb + 768,  nullptr, 2304, nullptr, nullptr);
    gemm_bf16<0><<<dim3(32, 6), 256, 0, stream>>>(cn, 768, wvT + (size_t)i*768*768, 768, 24,
                                                  qkvb + 1536, nullptr, 2304, nullptr, nullptr);
    if (bf16bias) attn_kernel<u16>  <<<ag, 256, 0, stream>>>(qkvb, biasbf,  attO);
    else          attn_kernel<float><<<ag, 256, 0, stream>>>(qkvb, in_bias, attO);
    gemm_bf16<1><<<dim3(32, 6), 256, 0, stream>>>(attO, 768, wcoT + (size_t)i*768*768, 768, 24,
                                                  nullptr, xbuf, 768, b_co + i*768, xbuf);
    // FFN block
    ln_kernel<u16><<<4096, 256, 0, stream>>>(xbuf, ln3_w + i*768, ln3_b + i*768, xn);
    gemm_bf16<2><<<dim3(32, 24), 256, 0, stream>>>(xn, 768, wf1T + (size_t)i*3072*768, 768, 24,
                                                   ffh, nullptr, 3072, b_f1 + i*3072, nullptr);
    gemm_bf16<1><<<dim3(32, 6), 256, 0, stream>>>(ffh, 3072, wf2T + (size_t)i*768*3072, 3072, 96,
                                                  nullptr, xbuf, 768, b_f2 + i*768, xbuf);
  }
  ln_kernel<float><<<4096, 256, 0, stream>>>(xbuf, lnout_w, lnout_b, (float*)d_out);
}

// Round 2
// 1667.120 us; speedup vs baseline: 1.3042x; 1.3042x over previous
//
#include <hip/hip_runtime.h>
#include <cstdint>
#include <cstddef>

#define DEV static __device__ __forceinline__

typedef float  f32x4 __attribute__((ext_vector_type(4)));
typedef short  s16x8 __attribute__((ext_vector_type(8)));
typedef unsigned short u16;
typedef unsigned short u16x2 __attribute__((ext_vector_type(2)));
typedef unsigned short u16x4 __attribute__((ext_vector_type(4)));
typedef __bf16 bf16x8 __attribute__((ext_vector_type(8)));

DEV float bf2f(u16 v){ union { unsigned u; float f; } x; x.u = ((unsigned)v) << 16; return x.f; }
DEV u16 f2bf(float f){ union { float f; unsigned u; } x; x.f = f; unsigned u = x.u;
                       u += 0x7fffu + ((u >> 16) & 1u); return (u16)(u >> 16); }

DEV f32x4 mfma16(s16x8 a, s16x8 b, f32x4 c){
  return __builtin_amdgcn_mfma_f32_16x16x32_bf16(
      __builtin_bit_cast(bf16x8, a), __builtin_bit_cast(bf16x8, b), c, 0, 0, 0);
}

// async global->LDS, 16B per lane; LDS dest = wave-uniform base + lane*16
DEV void gld16(const void* g, void* l){
  __builtin_amdgcn_global_load_lds(
      (const __attribute__((address_space(1))) void*)(uintptr_t)g,
      (__attribute__((address_space(3))) void*)(unsigned)(uintptr_t)l,
      16, 0, 0);
}

// ---------------- transpose + fp32->bf16 convert: src[K][N] -> dst[N][K] ----------------
__global__ void __launch_bounds__(256)
transpose_cvt(const float* __restrict__ src, u16* __restrict__ dst, int K, int N,
              size_t dzstride){
  int z = blockIdx.z;
  src += (size_t)z * K * N;
  dst += (size_t)z * dzstride;
  __shared__ float t[32][33];
  int n0 = blockIdx.x * 32, k0 = blockIdx.y * 32;
#pragma unroll
  for (int i = 0; i < 4; ++i)
    t[threadIdx.y + 8*i][threadIdx.x] = src[(size_t)(k0 + threadIdx.y + 8*i) * N + n0 + threadIdx.x];
  __syncthreads();
#pragma unroll
  for (int i = 0; i < 4; ++i)
    dst[(size_t)(n0 + threadIdx.y + 8*i) * K + k0 + threadIdx.x] = f2bf(t[threadIdx.x][threadIdx.y + 8*i]);
}

// ---------------- fp32 -> bf16 flat convert (bias) ----------------
__global__ void __launch_bounds__(256)
cvt_bias(const float* __restrict__ in, u16* __restrict__ out){
  size_t i = ((size_t)blockIdx.x * 256 + threadIdx.x) * 4;
  f32x4 v = *(const f32x4*)(in + i);
  u16x4 o;
#pragma unroll
  for (int j = 0; j < 4; ++j) o[j] = f2bf(v[j]);
  *(u16x4*)(out + i) = o;
}

// ---------------- LayerNorm over D=768, one block per row ----------------
template<typename OUT>
__global__ void __launch_bounds__(256)
ln_kernel(const float* __restrict__ x, const float* __restrict__ w,
          const float* __restrict__ bsh, OUT* __restrict__ out){
  int row = blockIdx.x, tid = threadIdx.x;
  const float* xr = x + (size_t)row * 768;
  float v0 = xr[tid], v1 = xr[tid + 256], v2 = xr[tid + 512];
  float s = v0 + v1 + v2, s2 = v0*v0 + v1*v1 + v2*v2;
#pragma unroll
  for (int off = 1; off < 64; off <<= 1){ s += __shfl_xor(s, off); s2 += __shfl_xor(s2, off); }
  __shared__ float red[8];
  int wid = tid >> 6;
  if ((tid & 63) == 0){ red[wid] = s; red[wid + 4] = s2; }
  __syncthreads();
  s  = red[0] + red[1] + red[2] + red[3];
  s2 = red[4] + red[5] + red[6] + red[7];
  float m = s * (1.f/768.f);
  float var = s2 * (1.f/768.f) - m * m;
  float rstd = rsqrtf(var + 1e-5f);
  OUT* orow = out + (size_t)row * 768;
#pragma unroll
  for (int i = 0; i < 3; ++i){
    int c = tid + 256 * i;
    float vv = (i == 0 ? v0 : (i == 1 ? v1 : v2));
    float o = (vv - m) * rstd * w[c] + bsh[c];
    if constexpr (sizeof(OUT) == 2) orow[c] = f2bf(o);
    else                            orow[c] = o;
  }
}

// ---------------- bf16 GEMM: C[M,N] = A[M,K] @ B[K,N], B given transposed [N][K] --------
// BM=128 x BN (128 or 64) tile, BK=32, 4 waves (2x2), m97 structure.
// EPI 0: store bf16 into Cb; EPI 1: Cf = acc + bias[col] + resid (fp32);
// EPI 2: Cb = bf16(gelu(acc + bias[col])) exact.
template<int BN, int EPI>
__global__ void __launch_bounds__(256)
gemm_bf16(const u16* __restrict__ A, int lda, const u16* __restrict__ Bt, int ldb,
          int nk, u16* __restrict__ Cb, float* __restrict__ Cf, int ldc,
          const float* __restrict__ bias, const float* __restrict__ resid){
  constexpr int NT = BN / 32;             // N fragments per wave
  __shared__ u16 As[128 * 32];
  __shared__ u16 Bs[BN * 32];
  const int tid = threadIdx.x, w = tid >> 6, lane = tid & 63;
  const int l16 = lane & 15, g = lane >> 4;
  const int m0 = blockIdx.x * 128, n0 = blockIdx.y * BN;
  const int wm = (w >> 1) * 64, wn = (w & 1) * (BN / 2);
  f32x4 acc[4][NT] = {};

  // A staging: chunks L = (w+4i)*1024 + lane*16 bytes -> row = L>>6, short-col = (L&63)>>1
  const int L0 = w * 1024 + lane * 16;
  const int L1 = (w + 4) * 1024 + lane * 16;
  const u16* a0 = A + (size_t)(m0 + (L0 >> 6)) * lda + ((L0 & 63) >> 1);
  const u16* a1 = A + (size_t)(m0 + (L1 >> 6)) * lda + ((L1 & 63) >> 1);
  // B staging
  const u16* b0; const u16* b1 = nullptr;
  if constexpr (BN == 128){
    b0 = Bt + (size_t)(n0 + (L0 >> 6)) * ldb + ((L0 & 63) >> 1);
    b1 = Bt + (size_t)(n0 + (L1 >> 6)) * ldb + ((L1 & 63) >> 1);
  } else {
    const int Lb = tid * 16;
    b0 = Bt + (size_t)(n0 + (Lb >> 6)) * ldb + ((Lb & 63) >> 1);
  }
  char* asb = (char*)As; char* bsb = (char*)Bs;

  for (int kt = 0; kt < nk; ++kt){
    const int k0 = kt * 32;
    __syncthreads();
    gld16(a0 + k0, asb + (w    ) * 1024);
    gld16(a1 + k0, asb + (w + 4) * 1024);
    if constexpr (BN == 128){
      gld16(b0 + k0, bsb + (w    ) * 1024);
      gld16(b1 + k0, bsb + (w + 4) * 1024);
    } else {
      gld16(b0 + k0, bsb + w * 1024);
    }
    __syncthreads();

    s16x8 af[4], bfv[NT];
#pragma unroll
    for (int mi = 0; mi < 4; ++mi)
      af[mi] = *(const s16x8*)(As + (wm + mi*16 + l16) * 32 + 8 * g);
#pragma unroll
    for (int ni = 0; ni < NT; ++ni)
      bfv[ni] = *(const s16x8*)(Bs + (wn + ni*16 + l16) * 32 + 8 * g);
#pragma unroll
    for (int mi = 0; mi < 4; ++mi)
#pragma unroll
      for (int ni = 0; ni < NT; ++ni)
        acc[mi][ni] = mfma16(af[mi], bfv[ni], acc[mi][ni]);
  }

  // epilogue: C/D layout col = lane&15, row = 4*(lane>>4)+r
#pragma unroll
  for (int mi = 0; mi < 4; ++mi){
    const int rg = m0 + wm + mi*16 + 4*g;
#pragma unroll
    for (int ni = 0; ni < NT; ++ni){
      const int col = n0 + wn + ni*16 + l16;
      f32x4 v = acc[mi][ni];
#pragma unroll
      for (int r = 0; r < 4; ++r){
        const int row = rg + r;
        if constexpr (EPI == 0){
          Cb[(size_t)row * ldc + col] = f2bf(v[r]);
        } else if constexpr (EPI == 1){
          Cf[(size_t)row * ldc + col] = v[r] + bias[col] + resid[(size_t)row * ldc + col];
        } else {
          float t = v[r] + bias[col];
          float ge = 0.5f * t * (1.0f + erff(t * 0.7071067811865476f));
          Cb[(size_t)row * ldc + col] = f2bf(ge);
        }
      }
    }
  }
}

// ---------------- fused flash attention with additive bias (v2, pipelined) ----------------
// q-tile 64 (4 waves x 16 q-rows), KV step 64. grid (32, 12, 2).
// K & bias: global_load_lds double-buffered, XOR-swizzled via pre-swizzled SOURCE (16B chunks).
// V: reg-staged (issue-early/write-late), chunk-swizzled b128 LDS writes, single buffer.
__global__ void __launch_bounds__(256)
attn_kernel(const u16* __restrict__ qkv, const u16* __restrict__ bias, u16* __restrict__ out){
  __shared__ __align__(16) u16 Ks [2 * 4096];   // [buf][row64][chunk8*8] chunk c holds global chunk c^(row&7)
  __shared__ __align__(16) u16 Bsh[2 * 4096];   // same swizzle, rows = block-local q
  __shared__ __align__(16) u16 Vt [4096];       // [dh64][kv-chunk swizzled]
  __shared__ __align__(16) u16 Pl [4 * 1024];   // per-wave P [q16][kv chunk swizzled]

  const int tid = threadIdx.x, w = tid >> 6, lane = tid & 63;
  const int l16 = lane & 15, g = lane >> 4;
  const int qt = blockIdx.x, h = blockIdx.y, b = blockIdx.z;
  const int rowbase = b * 2048, q0 = qt * 64;
  const float SCALE = 0.125f;

  // --- K/bias gld source addresses (pre-swizzled) ---
  const int ci0 = w * 64 + lane, ci1 = ci0 + 256;
  const int r0 = ci0 >> 3, sc0 = ci0 & 7, r1 = ci1 >> 3, sc1 = ci1 & 7;
  const u16* kp0 = qkv + (size_t)(rowbase + r0) * 2304 + 768 + h * 64 + (((sc0 ^ (r0 & 7)) & 7) << 3);
  const u16* kp1 = qkv + (size_t)(rowbase + r1) * 2304 + 768 + h * 64 + (((sc1 ^ (r1 & 7)) & 7) << 3);
  const u16* bp0 = bias + ((size_t)h * 2048 + q0 + r0) * 2048 + (((sc0 ^ (r0 & 7)) & 7) << 3);
  const u16* bp1 = bias + ((size_t)h * 2048 + q0 + r1) * 2048 + (((sc1 ^ (r1 & 7)) & 7) << 3);
  // --- V staging: thread covers dh0,dh0+1 x kv rows vs*8..vs*8+7 ---
  const int dh0 = (tid & 31) * 2, vs = tid >> 5;
  const u16* vp = qkv + (size_t)(rowbase + vs * 8) * 2304 + 1536 + h * 64 + dh0;
  u16x2 vr[8];

  // --- Q fragments: B-operand, col = q_local = l16 ---
  const u16* qrow = qkv + (size_t)(rowbase + q0 + w * 16 + l16) * 2304 + h * 64;
  s16x8 qf0 = *(const s16x8*)(qrow + 8 * g);
  s16x8 qf1 = *(const s16x8*)(qrow + 32 + 8 * g);

  f32x4 oacc[4] = {};
  float mrun = -3.0e38f, lrun = 0.f;

  const int sw = l16 & 7;

  // prologue: stage tile 0
  {
    char* kb = (char*)Ks + w * 1024;
    gld16(kp0, kb); gld16(kp1, kb + 4096);
    char* bb = (char*)Bsh + w * 1024;
    gld16(bp0, bb); gld16(bp1, bb + 4096);
#pragma unroll
    for (int i = 0; i < 8; ++i) vr[i] = *(const u16x2*)(vp + (size_t)i * 2304);
  }
  __syncthreads();
  {
    s16x8 vA, vB;
#pragma unroll
    for (int j = 0; j < 8; ++j){ vA[j] = (short)vr[j][0]; vB[j] = (short)vr[j][1]; }
    *(s16x8*)(Vt + dh0 * 64 + ((vs ^ (dh0 & 7)) << 3)) = vA;
    *(s16x8*)(Vt + (dh0 + 1) * 64 + ((vs ^ ((dh0 + 1) & 7)) << 3)) = vB;
  }
  __syncthreads();

  int cb = 0;
  for (int t = 0; t < 32; ++t){
    // issue prefetch of tile t+1
    if (t < 31){
      const size_t koff = (size_t)(t + 1) * 64 * 2304;
      char* kb = (char*)Ks + (cb ^ 1) * 8192 + w * 1024;
      gld16(kp0 + koff, kb); gld16(kp1 + koff, kb + 4096);
      char* bb = (char*)Bsh + (cb ^ 1) * 8192 + w * 1024;
      gld16(bp0 + (t + 1) * 64, bb); gld16(bp1 + (t + 1) * 64, bb + 4096);
      const u16* p = vp + koff;
#pragma unroll
      for (int i = 0; i < 8; ++i) vr[i] = *(const u16x2*)(p + (size_t)i * 2304);
    }

    // ---- compute on tile t ----
    const u16* Kb = Ks + cb * 4096;
    const u16* Bb = Bsh + cb * 4096;

    // S^T = K * Q^T : lane holds q = l16, kv = 16mi + 4g + r
    f32x4 st[4];
#pragma unroll
    for (int mi = 0; mi < 4; ++mi){
      const int row = l16 + 16 * mi;
      s16x8 kf0 = *(const s16x8*)(Kb + row * 64 + ((g ^ sw) << 3));
      s16x8 kf1 = *(const s16x8*)(Kb + row * 64 + (((g + 4) ^ sw) << 3));
      f32x4 z = {};
      z = mfma16(kf0, qf0, z);
      st[mi] = mfma16(kf1, qf1, z);
    }

    // scale + bias + online softmax (per lane, one q)
    const int brow = w * 16 + l16;
    float tmax = -3.0e38f;
#pragma unroll
    for (int mi = 0; mi < 4; ++mi){
      u16x4 bb = *(const u16x4*)(Bb + brow * 64 + (((2*mi + (g >> 1)) ^ sw) << 3) + 4 * (g & 1));
#pragma unroll
      for (int r = 0; r < 4; ++r){
        float v = st[mi][r] * SCALE + bf2f(bb[r]);
        st[mi][r] = v;
        tmax = fmaxf(tmax, v);
      }
    }
    tmax = fmaxf(tmax, __shfl_xor(tmax, 16));
    tmax = fmaxf(tmax, __shfl_xor(tmax, 32));
    float mnew = fmaxf(mrun, tmax);
    float alpha = __expf(mrun - mnew);
    mrun = mnew;
    float ssum = 0.f;
#pragma unroll
    for (int mi = 0; mi < 4; ++mi){
      u16x4 pk;
#pragma unroll
      for (int r = 0; r < 4; ++r){
        float pv = __expf(st[mi][r] - mnew);
        ssum += pv;
        pk[r] = f2bf(pv);
      }
      *(u16x4*)(Pl + w * 1024 + l16 * 64 + (((2*mi + (g >> 1)) ^ sw) << 3) + 4 * (g & 1)) = pk;
    }
    ssum += __shfl_xor(ssum, 16);
    ssum += __shfl_xor(ssum, 32);
    lrun = lrun * alpha + ssum;

    // rescale O: row q_local = 4g + r
#pragma unroll
    for (int r = 0; r < 4; ++r){
      float aq = __shfl(alpha, 4 * g + r);
#pragma unroll
      for (int ni = 0; ni < 4; ++ni) oacc[ni][r] *= aq;
    }

    // O += P @ V
#pragma unroll
    for (int ks2 = 0; ks2 < 2; ++ks2){
      s16x8 pf = *(const s16x8*)(Pl + w * 1024 + l16 * 64 + (((4*ks2 + g) ^ sw) << 3));
#pragma unroll
      for (int ni = 0; ni < 4; ++ni){
        const int dh = l16 + 16 * ni;
        s16x8 vf = *(const s16x8*)(Vt + dh * 64 + (((4*ks2 + g) ^ sw) << 3));
        oacc[ni] = mfma16(pf, vf, oacc[ni]);
      }
    }

    __syncthreads();                 // drains vmcnt (prefetch landed) + all waves done reading
    if (t < 31){
      s16x8 vA, vB;
#pragma unroll
      for (int j = 0; j < 8; ++j){ vA[j] = (short)vr[j][0]; vB[j] = (short)vr[j][1]; }
      *(s16x8*)(Vt + dh0 * 64 + ((vs ^ (dh0 & 7)) << 3)) = vA;
      *(s16x8*)(Vt + (dh0 + 1) * 64 + ((vs ^ ((dh0 + 1) & 7)) << 3)) = vB;
    }
    __syncthreads();                 // Vt(t+1) visible
    cb ^= 1;
  }

  // finalize: divide by l, write merged-head output; row q_local = 4g+r
#pragma unroll
  for (int r = 0; r < 4; ++r){
    float lq = __shfl(lrun, 4 * g + r);
    float inv = 1.0f / lq;
    const int row = rowbase + q0 + w * 16 + 4 * g + r;
#pragma unroll
    for (int ni = 0; ni < 4; ++ni)
      out[(size_t)row * 768 + h * 64 + l16 + 16 * ni] = f2bf(oacc[ni][r] * inv);
  }
}

// ============================== host ==============================
extern "C" void kernel_launch(void* const* d_in, const int* in_sizes, int n_in,
                              void* d_out, int out_size, void* d_ws, size_t ws_size,
                              hipStream_t stream){
  const float* in_x    = (const float*)d_in[0];
  const float* in_ctx  = (const float*)d_in[1];
  const float* in_bias = (const float*)d_in[2];
  const float* ln1_w = (const float*)d_in[3];
  const float* ln1_b = (const float*)d_in[4];
  const float* w_qkv = (const float*)d_in[5];
  const float* w_so  = (const float*)d_in[6];
  const float* b_so  = (const float*)d_in[7];
  const float* ln2_w = (const float*)d_in[8];
  const float* ln2_b = (const float*)d_in[9];
  const float* w_q   = (const float*)d_in[10];
  const float* w_k   = (const float*)d_in[11];
  const float* w_v   = (const float*)d_in[12];
  const float* w_co  = (const float*)d_in[13];
  const float* b_co  = (const float*)d_in[14];
  const float* ln3_w = (const float*)d_in[15];
  const float* ln3_b = (const float*)d_in[16];
  const float* w_f1  = (const float*)d_in[17];
  const float* b_f1  = (const float*)d_in[18];
  const float* w_f2  = (const float*)d_in[19];
  const float* b_f2  = (const float*)d_in[20];
  const float* lnout_w = (const float*)d_in[21];
  const float* lnout_b = (const float*)d_in[22];

  char* p = (char*)d_ws;
  float* xbuf  = (float*)p;  p += 4096ll * 768 * 4;
  u16* xn      = (u16*)p;    p += 4096ll * 768 * 2;
  u16* cn      = (u16*)p;    p += 4096ll * 768 * 2;
  u16* qkvb    = (u16*)p;    p += 4096ll * 2304 * 2;
  u16* attO    = (u16*)p;    p += 4096ll * 768 * 2;
  u16* ffh     = (u16*)p;    p += 4096ll * 3072 * 2;
  u16* wqkvT   = (u16*)p;    p += 4ll * 2304 * 768 * 2;
  u16* wsoT    = (u16*)p;    p += 4ll * 768 * 768 * 2;
  u16* wqT     = (u16*)p;    p += 4ll * 768 * 768 * 2;
  u16* wkvT    = (u16*)p;    p += 4ll * 1536 * 768 * 2;   // per layer: [k rows 0..767 | v rows 768..1535]
  u16* wcoT    = (u16*)p;    p += 4ll * 768 * 768 * 2;
  u16* wf1T    = (u16*)p;    p += 4ll * 3072 * 768 * 2;
  u16* wf2T    = (u16*)p;    p += 4ll * 768 * 3072 * 2;
  u16* biasbf  = (u16*)p;    p += 12ll * 2048 * 2048 * 2;

  hipMemcpyAsync(xbuf, in_x, 4096ll * 768 * 4, hipMemcpyDeviceToDevice, stream);

  const dim3 tb(32, 8);
  transpose_cvt<<<dim3(72, 24, 4), tb, 0, stream>>>(w_qkv, wqkvT, 768, 2304, 2304ll*768);
  transpose_cvt<<<dim3(24, 24, 4), tb, 0, stream>>>(w_so,  wsoT,  768, 768,  768ll*768);
  transpose_cvt<<<dim3(24, 24, 4), tb, 0, stream>>>(w_q,   wqT,   768, 768,  768ll*768);
  transpose_cvt<<<dim3(24, 24, 4), tb, 0, stream>>>(w_k,   wkvT,            768, 768, 1536ll*768);
  transpose_cvt<<<dim3(24, 24, 4), tb, 0, stream>>>(w_v,   wkvT + 768ll*768,768, 768, 1536ll*768);
  transpose_cvt<<<dim3(24, 24, 4), tb, 0, stream>>>(w_co,  wcoT,  768, 768,  768ll*768);
  transpose_cvt<<<dim3(96, 24, 4), tb, 0, stream>>>(w_f1,  wf1T,  768, 3072, 3072ll*768);
  transpose_cvt<<<dim3(24, 96, 4), tb, 0, stream>>>(w_f2,  wf2T,  3072, 768, 768ll*3072);
  cvt_bias<<<49152, 256, 0, stream>>>(in_bias, biasbf);

  const dim3 ag(32, 12, 2);
  for (int i = 0; i < 4; ++i){
    // self-attention block
    ln_kernel<u16><<<4096, 256, 0, stream>>>(xbuf, ln1_w + i*768, ln1_b + i*768, xn);
    gemm_bf16<128,0><<<dim3(32, 18), 256, 0, stream>>>(xn, 768, wqkvT + (size_t)i*2304*768, 768, 24,
                                                       qkvb, nullptr, 2304, nullptr, nullptr);
    attn_kernel<<<ag, 256, 0, stream>>>(qkvb, biasbf, attO);
    gemm_bf16<64,1><<<dim3(32, 12), 256, 0, stream>>>(attO, 768, wsoT + (size_t)i*768*768, 768, 24,
                                                      nullptr, xbuf, 768, b_so + i*768, xbuf);
    // cross-attention block
    ln_kernel<u16><<<4096, 256, 0, stream>>>(xbuf,   ln2_w + i*768, ln2_b + i*768, xn);
    ln_kernel<u16><<<4096, 256, 0, stream>>>(in_ctx, ln2_w + i*768, ln2_b + i*768, cn);
    gemm_bf16<64,0><<<dim3(32, 12), 256, 0, stream>>>(xn, 768, wqT + (size_t)i*768*768, 768, 24,
                                                      qkvb, nullptr, 2304, nullptr, nullptr);
    gemm_bf16<64,0><<<dim3(32, 24), 256, 0, stream>>>(cn, 768, wkvT + (size_t)i*1536*768, 768, 24,
                                                      qkvb + 768, nullptr, 2304, nullptr, nullptr);
    attn_kernel<<<ag, 256, 0, stream>>>(qkvb, biasbf, attO);
    gemm_bf16<64,1><<<dim3(32, 12), 256, 0, stream>>>(attO, 768, wcoT + (size_t)i*768*768, 768, 24,
                                                      nullptr, xbuf, 768, b_co + i*768, xbuf);
    // FFN block
    ln_kernel<u16><<<4096, 256, 0, stream>>>(xbuf, ln3_w + i*768, ln3_b + i*768, xn);
    gemm_bf16<128,2><<<dim3(32, 24), 256, 0, stream>>>(xn, 768, wf1T + (size_t)i*3072*768, 768, 24,
                                                       ffh, nullptr, 3072, b_f1 + i*3072, nullptr);
    gemm_bf16<64,1><<<dim3(32, 12), 256, 0, stream>>>(ffh, 3072, wf2T + (size_t)i*768*3072, 3072, 96,
                                                      nullptr, xbuf, 768, b_f2 + i*768, xbuf);
  }
  ln_kernel<float><<<4096, 256, 0, stream>>>(xbuf, lnout_w, lnout_b, (float*)d_out);
}

// Round 3
// 1481.246 us; speedup vs baseline: 1.4678x; 1.1255x over previous
//
#include <hip/hip_runtime.h>
#include <cstdint>
#include <cstddef>

#define DEV static __device__ __forceinline__

typedef float  f32x4 __attribute__((ext_vector_type(4)));
typedef short  s16x8 __attribute__((ext_vector_type(8)));
typedef unsigned short u16;
typedef unsigned short u16x2 __attribute__((ext_vector_type(2)));
typedef unsigned short u16x4 __attribute__((ext_vector_type(4)));
typedef __bf16 bf16x8 __attribute__((ext_vector_type(8)));

#define LOG2E 1.4426950408889634f
#define QSCALE_CONST 0.18033688011112042f   /* 0.125 * log2(e) */

DEV float bf2f(u16 v){ union { unsigned u; float f; } x; x.u = ((unsigned)v) << 16; return x.f; }
DEV u16 f2bf(float f){ return __builtin_bit_cast(u16, (__bf16)f); }   // RNE via v_cvt (pk-fusable)

DEV float fexp2(float x){
#if __has_builtin(__builtin_amdgcn_exp2f)
  return __builtin_amdgcn_exp2f(x);
#else
  return exp2f(x);
#endif
}

DEV f32x4 mfma16(s16x8 a, s16x8 b, f32x4 c){
  return __builtin_amdgcn_mfma_f32_16x16x32_bf16(
      __builtin_bit_cast(bf16x8, a), __builtin_bit_cast(bf16x8, b), c, 0, 0, 0);
}

// async global->LDS, 16B per lane; LDS dest = wave-uniform base + lane*16
DEV void gld16(const void* g, void* l){
  __builtin_amdgcn_global_load_lds(
      (const __attribute__((address_space(1))) void*)(uintptr_t)g,
      (__attribute__((address_space(3))) void*)(unsigned)(uintptr_t)l,
      16, 0, 0);
}

// ---------------- transpose + fp32->bf16 convert: src[K][N] -> dst[N][K] ----------------
__global__ void __launch_bounds__(256)
transpose_cvt(const float* __restrict__ src, u16* __restrict__ dst, int K, int N,
              size_t dzstride){
  int z = blockIdx.z;
  src += (size_t)z * K * N;
  dst += (size_t)z * dzstride;
  __shared__ float t[32][33];
  int n0 = blockIdx.x * 32, k0 = blockIdx.y * 32;
#pragma unroll
  for (int i = 0; i < 4; ++i)
    t[threadIdx.y + 8*i][threadIdx.x] = src[(size_t)(k0 + threadIdx.y + 8*i) * N + n0 + threadIdx.x];
  __syncthreads();
#pragma unroll
  for (int i = 0; i < 4; ++i)
    dst[(size_t)(n0 + threadIdx.y + 8*i) * K + k0 + threadIdx.x] = f2bf(t[threadIdx.x][threadIdx.y + 8*i]);
}

// ---------------- fp32 -> bf16 convert with *log2e (bias) ----------------
__global__ void __launch_bounds__(256)
cvt_bias(const float* __restrict__ in, u16* __restrict__ out){
  size_t i = ((size_t)blockIdx.x * 256 + threadIdx.x) * 4;
  f32x4 v = *(const f32x4*)(in + i);
  u16x4 o;
#pragma unroll
  for (int j = 0; j < 4; ++j) o[j] = f2bf(v[j] * LOG2E);
  *(u16x4*)(out + i) = o;
}

// ---------------- LayerNorm over D=768, one block per row ----------------
// If x1 != nullptr: blocks [4096..8191) process x1 -> o1 (dual-source dispatch).
template<typename OUT>
__global__ void __launch_bounds__(256)
ln_kernel(const float* __restrict__ x0, const float* __restrict__ x1,
          const float* __restrict__ w, const float* __restrict__ bsh,
          OUT* __restrict__ o0, OUT* __restrict__ o1){
  int row = blockIdx.x, tid = threadIdx.x;
  const float* xr; OUT* orow;
  if (row < 4096){ xr = x0 + (size_t)row * 768; orow = o0 + (size_t)row * 768; }
  else           { xr = x1 + (size_t)(row - 4096) * 768; orow = o1 + (size_t)(row - 4096) * 768; }
  float v0 = xr[tid], v1 = xr[tid + 256], v2 = xr[tid + 512];
  float s = v0 + v1 + v2, s2 = v0*v0 + v1*v1 + v2*v2;
#pragma unroll
  for (int off = 1; off < 64; off <<= 1){ s += __shfl_xor(s, off); s2 += __shfl_xor(s2, off); }
  __shared__ float red[8];
  int wid = tid >> 6;
  if ((tid & 63) == 0){ red[wid] = s; red[wid + 4] = s2; }
  __syncthreads();
  s  = red[0] + red[1] + red[2] + red[3];
  s2 = red[4] + red[5] + red[6] + red[7];
  float m = s * (1.f/768.f);
  float var = s2 * (1.f/768.f) - m * m;
  float rstd = rsqrtf(var + 1e-5f);
#pragma unroll
  for (int i = 0; i < 3; ++i){
    int c = tid + 256 * i;
    float vv = (i == 0 ? v0 : (i == 1 ? v1 : v2));
    float o = (vv - m) * rstd * w[c] + bsh[c];
    if constexpr (sizeof(OUT) == 2) orow[c] = f2bf(o);
    else                            orow[c] = o;
  }
}

// ---------------- bf16 GEMM, double-buffered pipelined staging ----------------
// C[M,N] = A[M,K] @ B[K,N], B given transposed [N][K]. BM=128 x BN(128|64), BK=32, 4 waves.
// EPI 0: bf16 store; EPI 1: fp32 acc+bias[col]+resid; EPI 2: bf16 gelu(acc+bias);
// EPI 3: bf16 store, cols<768 scaled by QSCALE_CONST (pre-scaled Q for exp2-domain attn).
template<int BN, int EPI>
__global__ void __launch_bounds__(256)
gemm_bf16(const u16* __restrict__ A, int lda, const u16* __restrict__ Bt, int ldb,
          int nk, u16* __restrict__ Cb, float* __restrict__ Cf, int ldc,
          const float* __restrict__ bias, const float* __restrict__ resid){
  constexpr int NT = BN / 32;             // N fragments per wave
  __shared__ u16 As[2][128 * 32];
  __shared__ u16 Bs[2][BN * 32];
  const int tid = threadIdx.x, w = tid >> 6, lane = tid & 63;
  const int l16 = lane & 15, g = lane >> 4;
  const int m0 = blockIdx.x * 128, n0 = blockIdx.y * BN;
  const int wm = (w >> 1) * 64, wn = (w & 1) * (BN / 2);
  f32x4 acc[4][NT] = {};

  // staging map: chunk L = (w+4i)*1024 + lane*16 bytes -> row = L>>6, short-col = (L&63)>>1
  const int L0 = w * 1024 + lane * 16;
  const int L1 = (w + 4) * 1024 + lane * 16;
  const u16* a0 = A + (size_t)(m0 + (L0 >> 6)) * lda + ((L0 & 63) >> 1);
  const u16* a1 = A + (size_t)(m0 + (L1 >> 6)) * lda + ((L1 & 63) >> 1);
  const u16* b0; const u16* b1 = nullptr;
  if constexpr (BN == 128){
    b0 = Bt + (size_t)(n0 + (L0 >> 6)) * ldb + ((L0 & 63) >> 1);
    b1 = Bt + (size_t)(n0 + (L1 >> 6)) * ldb + ((L1 & 63) >> 1);
  } else {
    const int Lb = tid * 16;
    b0 = Bt + (size_t)(n0 + (Lb >> 6)) * ldb + ((Lb & 63) >> 1);
  }

  // prologue: stage k-tile 0 into buffer 0
  {
    char* ab = (char*)As[0]; char* bb = (char*)Bs[0];
    gld16(a0, ab + w * 1024); gld16(a1, ab + (w + 4) * 1024);
    if constexpr (BN == 128){ gld16(b0, bb + w * 1024); gld16(b1, bb + (w + 4) * 1024); }
    else                    { gld16(b0, bb + w * 1024); }
  }
  __syncthreads();     // vmcnt(0) drained: tile 0 ready

  int cb = 0;
  for (int kt = 0; kt < nk; ++kt){
    if (kt + 1 < nk){  // issue prefetch of tile kt+1 into buf^1
      const int k1 = (kt + 1) * 32;
      char* ab = (char*)As[cb ^ 1]; char* bb = (char*)Bs[cb ^ 1];
      gld16(a0 + k1, ab + w * 1024); gld16(a1 + k1, ab + (w + 4) * 1024);
      if constexpr (BN == 128){ gld16(b0 + k1, bb + w * 1024); gld16(b1 + k1, bb + (w + 4) * 1024); }
      else                    { gld16(b0 + k1, bb + w * 1024); }
    }

    const u16* Ab = As[cb]; const u16* Bb = Bs[cb];
    s16x8 af[4], bfv[NT];
#pragma unroll
    for (int mi = 0; mi < 4; ++mi)
      af[mi] = *(const s16x8*)(Ab + (wm + mi*16 + l16) * 32 + 8 * g);
#pragma unroll
    for (int ni = 0; ni < NT; ++ni)
      bfv[ni] = *(const s16x8*)(Bb + (wn + ni*16 + l16) * 32 + 8 * g);
#pragma unroll
    for (int mi = 0; mi < 4; ++mi)
#pragma unroll
      for (int ni = 0; ni < NT; ++ni)
        acc[mi][ni] = mfma16(af[mi], bfv[ni], acc[mi][ni]);

    __syncthreads();   // readers done with buf cb; prefetch into cb^1 landed (vmcnt0)
    cb ^= 1;
  }

  // epilogue: C/D layout col = lane&15, row = 4*(lane>>4)+r
#pragma unroll
  for (int mi = 0; mi < 4; ++mi){
    const int rg = m0 + wm + mi*16 + 4*g;
#pragma unroll
    for (int ni = 0; ni < NT; ++ni){
      const int col = n0 + wn + ni*16 + l16;
      f32x4 v = acc[mi][ni];
#pragma unroll
      for (int r = 0; r < 4; ++r){
        const int row = rg + r;
        if constexpr (EPI == 0){
          Cb[(size_t)row * ldc + col] = f2bf(v[r]);
        } else if constexpr (EPI == 1){
          Cf[(size_t)row * ldc + col] = v[r] + bias[col] + resid[(size_t)row * ldc + col];
        } else if constexpr (EPI == 2){
          float t = v[r] + bias[col];
          float ge = 0.5f * t * (1.0f + erff(t * 0.7071067811865476f));
          Cb[(size_t)row * ldc + col] = f2bf(ge);
        } else {
          float sc = (col < 768) ? QSCALE_CONST : 1.0f;
          Cb[(size_t)row * ldc + col] = f2bf(v[r] * sc);
        }
      }
    }
  }
}

// ---------------- fused flash attention, exp2-domain, pipelined ----------------
// q pre-scaled by 0.125*log2e; bias pre-scaled by log2e. Softmax in log2 domain.
// q-tile 64 (4 waves x 16 q-rows), KV step 64. grid (32, 12, 2).
__global__ void __launch_bounds__(256)
attn_kernel(const u16* __restrict__ qkv, const u16* __restrict__ bias, u16* __restrict__ out){
  __shared__ __align__(16) u16 Ks [2 * 4096];   // [buf][row64][chunk8*8], chunk c holds global chunk c^(row&7)
  __shared__ __align__(16) u16 Bsh[2 * 4096];   // same swizzle, rows = block-local q
  __shared__ __align__(16) u16 Vt [4096];       // [dh64][kv chunk swizzled]
  __shared__ __align__(16) u16 Pl [4 * 1024];   // per-wave P [q16][kv chunk swizzled]

  const int tid = threadIdx.x, w = tid >> 6, lane = tid & 63;
  const int l16 = lane & 15, g = lane >> 4;
  const int qt = blockIdx.x, h = blockIdx.y, b = blockIdx.z;
  const int rowbase = b * 2048, q0 = qt * 64;

  // --- K/bias gld source addresses (pre-swizzled) ---
  const int ci0 = w * 64 + lane, ci1 = ci0 + 256;
  const int r0 = ci0 >> 3, sc0 = ci0 & 7, r1 = ci1 >> 3, sc1 = ci1 & 7;
  const u16* kp0 = qkv + (size_t)(rowbase + r0) * 2304 + 768 + h * 64 + (((sc0 ^ (r0 & 7)) & 7) << 3);
  const u16* kp1 = qkv + (size_t)(rowbase + r1) * 2304 + 768 + h * 64 + (((sc1 ^ (r1 & 7)) & 7) << 3);
  const u16* bp0 = bias + ((size_t)h * 2048 + q0 + r0) * 2048 + (((sc0 ^ (r0 & 7)) & 7) << 3);
  const u16* bp1 = bias + ((size_t)h * 2048 + q0 + r1) * 2048 + (((sc1 ^ (r1 & 7)) & 7) << 3);
  // --- V staging: thread covers dh0,dh0+1 x kv rows vs*8..vs*8+7 ---
  const int dh0 = (tid & 31) * 2, vs = tid >> 5;
  const u16* vp = qkv + (size_t)(rowbase + vs * 8) * 2304 + 1536 + h * 64 + dh0;
  u16x2 vr[8];

  // --- Q fragments: B-operand, col = q_local = l16 ---
  const u16* qrow = qkv + (size_t)(rowbase + q0 + w * 16 + l16) * 2304 + h * 64;
  s16x8 qf0 = *(const s16x8*)(qrow + 8 * g);
  s16x8 qf1 = *(const s16x8*)(qrow + 32 + 8 * g);

  f32x4 oacc[4] = {};
  float mrun = -3.0e38f, lrun = 0.f;
  const int sw = l16 & 7;

  // prologue: stage tile 0
  {
    char* kb = (char*)Ks + w * 1024;
    gld16(kp0, kb); gld16(kp1, kb + 4096);
    char* bb = (char*)Bsh + w * 1024;
    gld16(bp0, bb); gld16(bp1, bb + 4096);
#pragma unroll
    for (int i = 0; i < 8; ++i) vr[i] = *(const u16x2*)(vp + (size_t)i * 2304);
  }
  __syncthreads();
  {
    s16x8 vA, vB;
#pragma unroll
    for (int j = 0; j < 8; ++j){ vA[j] = (short)vr[j][0]; vB[j] = (short)vr[j][1]; }
    *(s16x8*)(Vt + dh0 * 64 + ((vs ^ (dh0 & 7)) << 3)) = vA;
    *(s16x8*)(Vt + (dh0 + 1) * 64 + ((vs ^ ((dh0 + 1) & 7)) << 3)) = vB;
  }
  __syncthreads();

  int cb = 0;
  for (int t = 0; t < 32; ++t){
    if (t < 31){  // issue prefetch of tile t+1
      const size_t koff = (size_t)(t + 1) * 64 * 2304;
      char* kb = (char*)Ks + (cb ^ 1) * 8192 + w * 1024;
      gld16(kp0 + koff, kb); gld16(kp1 + koff, kb + 4096);
      char* bb = (char*)Bsh + (cb ^ 1) * 8192 + w * 1024;
      gld16(bp0 + (t + 1) * 64, bb); gld16(bp1 + (t + 1) * 64, bb + 4096);
      const u16* p = vp + koff;
#pragma unroll
      for (int i = 0; i < 8; ++i) vr[i] = *(const u16x2*)(p + (size_t)i * 2304);
    }

    const u16* Kb = Ks + cb * 4096;
    const u16* Bb = Bsh + cb * 4096;

    // S2^T = K * Q2^T (log2-domain scores): lane holds q = l16, kv = 16mi + 4g + r
    f32x4 st[4];
#pragma unroll
    for (int mi = 0; mi < 4; ++mi){
      const int row = l16 + 16 * mi;
      s16x8 kf0 = *(const s16x8*)(Kb + row * 64 + ((g ^ sw) << 3));
      s16x8 kf1 = *(const s16x8*)(Kb + row * 64 + (((g + 4) ^ sw) << 3));
      f32x4 z = {};
      z = mfma16(kf0, qf0, z);
      st[mi] = mfma16(kf1, qf1, z);
    }

    // + bias (log2 domain) + online softmax
    const int brow = w * 16 + l16;
    float tmax = -3.0e38f;
#pragma unroll
    for (int mi = 0; mi < 4; ++mi){
      u16x4 bb = *(const u16x4*)(Bb + brow * 64 + (((2*mi + (g >> 1)) ^ sw) << 3) + 4 * (g & 1));
#pragma unroll
      for (int r = 0; r < 4; ++r){
        float v = st[mi][r] + bf2f(bb[r]);
        st[mi][r] = v;
        tmax = fmaxf(tmax, v);
      }
    }
    tmax = fmaxf(tmax, __shfl_xor(tmax, 16));
    tmax = fmaxf(tmax, __shfl_xor(tmax, 32));
    // defer-max (T13): only rescale when the running max grows by > 8 (log2)
    if (!__all(tmax <= mrun + 8.f)){
      float mnew = fmaxf(mrun, tmax);
      float al = fexp2(mrun - mnew);
      mrun = mnew;
      lrun *= al;
#pragma unroll
      for (int r = 0; r < 4; ++r){
        float aq = __shfl(al, 4 * g + r);
#pragma unroll
        for (int ni = 0; ni < 4; ++ni) oacc[ni][r] *= aq;
      }
    }
    float ssum = 0.f;
#pragma unroll
    for (int mi = 0; mi < 4; ++mi){
      u16x4 pk;
#pragma unroll
      for (int r = 0; r < 4; ++r){
        float pv = fexp2(st[mi][r] - mrun);
        ssum += pv;
        pk[r] = f2bf(pv);
      }
      *(u16x4*)(Pl + w * 1024 + l16 * 64 + (((2*mi + (g >> 1)) ^ sw) << 3) + 4 * (g & 1)) = pk;
    }
    ssum += __shfl_xor(ssum, 16);
    ssum += __shfl_xor(ssum, 32);
    lrun += ssum;

    // O += P @ V
#pragma unroll
    for (int ks2 = 0; ks2 < 2; ++ks2){
      s16x8 pf = *(const s16x8*)(Pl + w * 1024 + l16 * 64 + (((4*ks2 + g) ^ sw) << 3));
#pragma unroll
      for (int ni = 0; ni < 4; ++ni){
        const int dh = l16 + 16 * ni;
        s16x8 vf = *(const s16x8*)(Vt + dh * 64 + (((4*ks2 + g) ^ sw) << 3));
        oacc[ni] = mfma16(pf, vf, oacc[ni]);
      }
    }

    __syncthreads();                 // prefetch landed; all waves done reading Vt
    if (t < 31){
      s16x8 vA, vB;
#pragma unroll
      for (int j = 0; j < 8; ++j){ vA[j] = (short)vr[j][0]; vB[j] = (short)vr[j][1]; }
      *(s16x8*)(Vt + dh0 * 64 + ((vs ^ (dh0 & 7)) << 3)) = vA;
      *(s16x8*)(Vt + (dh0 + 1) * 64 + ((vs ^ ((dh0 + 1) & 7)) << 3)) = vB;
    }
    __syncthreads();                 // Vt(t+1) visible
    cb ^= 1;
  }

  // finalize: divide by l, write merged-head output; row q_local = 4g+r
#pragma unroll
  for (int r = 0; r < 4; ++r){
    float lq = __shfl(lrun, 4 * g + r);
    float inv = 1.0f / lq;
    const int row = rowbase + q0 + w * 16 + 4 * g + r;
#pragma unroll
    for (int ni = 0; ni < 4; ++ni)
      out[(size_t)row * 768 + h * 64 + l16 + 16 * ni] = f2bf(oacc[ni][r] * inv);
  }
}

// ============================== host ==============================
extern "C" void kernel_launch(void* const* d_in, const int* in_sizes, int n_in,
                              void* d_out, int out_size, void* d_ws, size_t ws_size,
                              hipStream_t stream){
  const float* in_x    = (const float*)d_in[0];
  const float* in_ctx  = (const float*)d_in[1];
  const float* in_bias = (const float*)d_in[2];
  const float* ln1_w = (const float*)d_in[3];
  const float* ln1_b = (const float*)d_in[4];
  const float* w_qkv = (const float*)d_in[5];
  const float* w_so  = (const float*)d_in[6];
  const float* b_so  = (const float*)d_in[7];
  const float* ln2_w = (const float*)d_in[8];
  const float* ln2_b = (const float*)d_in[9];
  const float* w_q   = (const float*)d_in[10];
  const float* w_k   = (const float*)d_in[11];
  const float* w_v   = (const float*)d_in[12];
  const float* w_co  = (const float*)d_in[13];
  const float* b_co  = (const float*)d_in[14];
  const float* ln3_w = (const float*)d_in[15];
  const float* ln3_b = (const float*)d_in[16];
  const float* w_f1  = (const float*)d_in[17];
  const float* b_f1  = (const float*)d_in[18];
  const float* w_f2  = (const float*)d_in[19];
  const float* b_f2  = (const float*)d_in[20];
  const float* lnout_w = (const float*)d_in[21];
  const float* lnout_b = (const float*)d_in[22];

  char* p = (char*)d_ws;
  float* xbuf  = (float*)p;  p += 4096ll * 768 * 4;
  u16* xn      = (u16*)p;    p += 4096ll * 768 * 2;
  u16* cn      = (u16*)p;    p += 4096ll * 768 * 2;
  u16* qkvb    = (u16*)p;    p += 4096ll * 2304 * 2;
  u16* attO    = (u16*)p;    p += 4096ll * 768 * 2;
  u16* ffh     = (u16*)p;    p += 4096ll * 3072 * 2;
  u16* wqkvT   = (u16*)p;    p += 4ll * 2304 * 768 * 2;
  u16* wsoT    = (u16*)p;    p += 4ll * 768 * 768 * 2;
  u16* wqT     = (u16*)p;    p += 4ll * 768 * 768 * 2;
  u16* wkvT    = (u16*)p;    p += 4ll * 1536 * 768 * 2;   // per layer: [k | v] row-blocks
  u16* wcoT    = (u16*)p;    p += 4ll * 768 * 768 * 2;
  u16* wf1T    = (u16*)p;    p += 4ll * 3072 * 768 * 2;
  u16* wf2T    = (u16*)p;    p += 4ll * 768 * 3072 * 2;
  u16* biasbf  = (u16*)p;    p += 12ll * 2048 * 2048 * 2;

  hipMemcpyAsync(xbuf, in_x, 4096ll * 768 * 4, hipMemcpyDeviceToDevice, stream);

  const dim3 tb(32, 8);
  transpose_cvt<<<dim3(72, 24, 4), tb, 0, stream>>>(w_qkv, wqkvT, 768, 2304, 2304ll*768);
  transpose_cvt<<<dim3(24, 24, 4), tb, 0, stream>>>(w_so,  wsoT,  768, 768,  768ll*768);
  transpose_cvt<<<dim3(24, 24, 4), tb, 0, stream>>>(w_q,   wqT,   768, 768,  768ll*768);
  transpose_cvt<<<dim3(24, 24, 4), tb, 0, stream>>>(w_k,   wkvT,             768, 768, 1536ll*768);
  transpose_cvt<<<dim3(24, 24, 4), tb, 0, stream>>>(w_v,   wkvT + 768ll*768, 768, 768, 1536ll*768);
  transpose_cvt<<<dim3(24, 24, 4), tb, 0, stream>>>(w_co,  wcoT,  768, 768,  768ll*768);
  transpose_cvt<<<dim3(96, 24, 4), tb, 0, stream>>>(w_f1,  wf1T,  768, 3072, 3072ll*768);
  transpose_cvt<<<dim3(24, 96, 4), tb, 0, stream>>>(w_f2,  wf2T,  3072, 768, 768ll*3072);
  cvt_bias<<<49152, 256, 0, stream>>>(in_bias, biasbf);

  const dim3 ag(32, 12, 2);
  for (int i = 0; i < 4; ++i){
    // self-attention block
    ln_kernel<u16><<<4096, 256, 0, stream>>>(xbuf, nullptr, ln1_w + i*768, ln1_b + i*768, xn, nullptr);
    gemm_bf16<128,3><<<dim3(32, 18), 256, 0, stream>>>(xn, 768, wqkvT + (size_t)i*2304*768, 768, 24,
                                                       qkvb, nullptr, 2304, nullptr, nullptr);
    attn_kernel<<<ag, 256, 0, stream>>>(qkvb, biasbf, attO);
    gemm_bf16<64,1><<<dim3(32, 12), 256, 0, stream>>>(attO, 768, wsoT + (size_t)i*768*768, 768, 24,
                                                      nullptr, xbuf, 768, b_so + i*768, xbuf);
    // cross-attention block (dual LN in one dispatch)
    ln_kernel<u16><<<8192, 256, 0, stream>>>(xbuf, in_ctx, ln2_w + i*768, ln2_b + i*768, xn, cn);
    gemm_bf16<64,3><<<dim3(32, 12), 256, 0, stream>>>(xn, 768, wqT + (size_t)i*768*768, 768, 24,
                                                      qkvb, nullptr, 2304, nullptr, nullptr);
    gemm_bf16<64,0><<<dim3(32, 24), 256, 0, stream>>>(cn, 768, wkvT + (size_t)i*1536*768, 768, 24,
                                                      qkvb + 768, nullptr, 2304, nullptr, nullptr);
    attn_kernel<<<ag, 256, 0, stream>>>(qkvb, biasbf, attO);
    gemm_bf16<64,1><<<dim3(32, 12), 256, 0, stream>>>(attO, 768, wcoT + (size_t)i*768*768, 768, 24,
                                                      nullptr, xbuf, 768, b_co + i*768, xbuf);
    // FFN block
    ln_kernel<u16><<<4096, 256, 0, stream>>>(xbuf, nullptr, ln3_w + i*768, ln3_b + i*768, xn, nullptr);
    gemm_bf16<128,2><<<dim3(32, 24), 256, 0, stream>>>(xn, 768, wf1T + (size_t)i*3072*768, 768, 24,
                                                       ffh, nullptr, 3072, b_f1 + i*3072, nullptr);
    gemm_bf16<64,1><<<dim3(32, 12), 256, 0, stream>>>(ffh, 3072, wf2T + (size_t)i*768*3072, 3072, 96,
                                                      nullptr, xbuf, 768, b_f2 + i*768, xbuf);
  }
  ln_kernel<float><<<4096, 256, 0, stream>>>(xbuf, nullptr, lnout_w, lnout_b, (float*)d_out, nullptr);
}

// Round 4
// 1459.752 us; speedup vs baseline: 1.4895x; 1.0147x over previous
//
#include <hip/hip_runtime.h>
#include <cstdint>
#include <cstddef>

#define DEV static __device__ __forceinline__

typedef float  f32x4 __attribute__((ext_vector_type(4)));
typedef short  s16x8 __attribute__((ext_vector_type(8)));
typedef unsigned short u16;
typedef unsigned short u16x2 __attribute__((ext_vector_type(2)));
typedef unsigned short u16x4 __attribute__((ext_vector_type(4)));
typedef __bf16 bf16x8 __attribute__((ext_vector_type(8)));

#define LOG2E 1.4426950408889634f
#define QSCALE_CONST 0.18033688011112042f   /* 0.125 * log2(e) */

DEV float bf2f(u16 v){ union { unsigned u; float f; } x; x.u = ((unsigned)v) << 16; return x.f; }
DEV u16 f2bf(float f){ return __builtin_bit_cast(u16, (__bf16)f); }   // RNE via v_cvt

DEV float fexp2(float x){
#if __has_builtin(__builtin_amdgcn_exp2f)
  return __builtin_amdgcn_exp2f(x);
#else
  return exp2f(x);
#endif
}

DEV f32x4 mfma16(s16x8 a, s16x8 b, f32x4 c){
  return __builtin_amdgcn_mfma_f32_16x16x32_bf16(
      __builtin_bit_cast(bf16x8, a), __builtin_bit_cast(bf16x8, b), c, 0, 0, 0);
}

// async global->LDS, 16B per lane; LDS dest = wave-uniform base + lane*16
DEV void gld16(const void* g, void* l){
  __builtin_amdgcn_global_load_lds(
      (const __attribute__((address_space(1))) void*)(uintptr_t)g,
      (__attribute__((address_space(3))) void*)(unsigned)(uintptr_t)l,
      16, 0, 0);
}

// ---------------- transpose + fp32->bf16 convert: src[K][N] -> dst[N][K] ----------------
__global__ void __launch_bounds__(256)
transpose_cvt(const float* __restrict__ src, u16* __restrict__ dst, int K, int N,
              size_t dzstride){
  int z = blockIdx.z;
  src += (size_t)z * K * N;
  dst += (size_t)z * dzstride;
  __shared__ float t[32][33];
  int n0 = blockIdx.x * 32, k0 = blockIdx.y * 32;
#pragma unroll
  for (int i = 0; i < 4; ++i)
    t[threadIdx.y + 8*i][threadIdx.x] = src[(size_t)(k0 + threadIdx.y + 8*i) * N + n0 + threadIdx.x];
  __syncthreads();
#pragma unroll
  for (int i = 0; i < 4; ++i)
    dst[(size_t)(n0 + threadIdx.y + 8*i) * K + k0 + threadIdx.x] = f2bf(t[threadIdx.x][threadIdx.y + 8*i]);
}

// ---------------- fp32 -> bf16 convert with *log2e (bias) ----------------
__global__ void __launch_bounds__(256)
cvt_bias(const float* __restrict__ in, u16* __restrict__ out){
  size_t i = ((size_t)blockIdx.x * 256 + threadIdx.x) * 4;
  f32x4 v = *(const f32x4*)(in + i);
  u16x4 o;
#pragma unroll
  for (int j = 0; j < 4; ++j) o[j] = f2bf(v[j] * LOG2E);
  *(u16x4*)(out + i) = o;
}

// ---------------- LayerNorm over D=768, one block per row ----------------
template<typename OUT>
__global__ void __launch_bounds__(256)
ln_kernel(const float* __restrict__ x0, const float* __restrict__ x1,
          const float* __restrict__ w, const float* __restrict__ bsh,
          OUT* __restrict__ o0, OUT* __restrict__ o1){
  int row = blockIdx.x, tid = threadIdx.x;
  const float* xr; OUT* orow;
  if (row < 4096){ xr = x0 + (size_t)row * 768; orow = o0 + (size_t)row * 768; }
  else           { xr = x1 + (size_t)(row - 4096) * 768; orow = o1 + (size_t)(row - 4096) * 768; }
  float v0 = xr[tid], v1 = xr[tid + 256], v2 = xr[tid + 512];
  float s = v0 + v1 + v2, s2 = v0*v0 + v1*v1 + v2*v2;
#pragma unroll
  for (int off = 1; off < 64; off <<= 1){ s += __shfl_xor(s, off); s2 += __shfl_xor(s2, off); }
  __shared__ float red[8];
  int wid = tid >> 6;
  if ((tid & 63) == 0){ red[wid] = s; red[wid + 4] = s2; }
  __syncthreads();
  s  = red[0] + red[1] + red[2] + red[3];
  s2 = red[4] + red[5] + red[6] + red[7];
  float m = s * (1.f/768.f);
  float var = s2 * (1.f/768.f) - m * m;
  float rstd = rsqrtf(var + 1e-5f);
#pragma unroll
  for (int i = 0; i < 3; ++i){
    int c = tid + 256 * i;
    float vv = (i == 0 ? v0 : (i == 1 ? v1 : v2));
    float o = (vv - m) * rstd * w[c] + bsh[c];
    if constexpr (sizeof(OUT) == 2) orow[c] = f2bf(o);
    else                            orow[c] = o;
  }
}

// ---------------- bf16 GEMM, double-buffered pipelined staging ----------------
// C[M,N] = A[M,K] @ B[K,N], B given transposed [N][K]. BM=128 x BN(128|64), BK=32, 4 waves.
// EPI 0: bf16 store; EPI 1: fp32 acc+bias[col]+resid; EPI 2: bf16 gelu(acc+bias);
// EPI 3: bf16 store, cols<768 scaled by QSCALE_CONST;
// EPI 4: merged cross q/k/v: z=0:(A,Bt)= (A,Bt) scaled, z=1/2:(A2, Bt2[+768*768]), out += z*768.
template<int BN, int EPI>
__global__ void __launch_bounds__(256)
gemm_bf16(const u16* __restrict__ A, int lda, const u16* __restrict__ Bt, int ldb,
          int nk, u16* __restrict__ Cb, float* __restrict__ Cf, int ldc,
          const float* __restrict__ bias, const float* __restrict__ resid,
          const u16* __restrict__ A2, const u16* __restrict__ Bt2){
  constexpr int NT = BN / 32;             // N fragments per wave
  __shared__ u16 As[2][128 * 32];
  __shared__ u16 Bs[2][BN * 32];
  float colscale = 1.0f;
  if constexpr (EPI == 4){
    const int z = blockIdx.z;
    if (z == 0){ colscale = QSCALE_CONST; }
    else { A = A2; Bt = Bt2 + (size_t)(z - 1) * 768 * 768; }
    Cb += z * 768;
  }
  const int tid = threadIdx.x, w = tid >> 6, lane = tid & 63;
  const int l16 = lane & 15, g = lane >> 4;
  const int m0 = blockIdx.x * 128, n0 = blockIdx.y * BN;
  const int wm = (w >> 1) * 64, wn = (w & 1) * (BN / 2);
  f32x4 acc[4][NT] = {};

  // staging map: chunk L = (w+4i)*1024 + lane*16 bytes -> row = L>>6, short-col = (L&63)>>1
  const int L0 = w * 1024 + lane * 16;
  const int L1 = (w + 4) * 1024 + lane * 16;
  const u16* a0 = A + (size_t)(m0 + (L0 >> 6)) * lda + ((L0 & 63) >> 1);
  const u16* a1 = A + (size_t)(m0 + (L1 >> 6)) * lda + ((L1 & 63) >> 1);
  const u16* b0; const u16* b1 = nullptr;
  if constexpr (BN == 128){
    b0 = Bt + (size_t)(n0 + (L0 >> 6)) * ldb + ((L0 & 63) >> 1);
    b1 = Bt + (size_t)(n0 + (L1 >> 6)) * ldb + ((L1 & 63) >> 1);
  } else {
    const int Lb = tid * 16;
    b0 = Bt + (size_t)(n0 + (Lb >> 6)) * ldb + ((Lb & 63) >> 1);
  }

  // prologue: stage k-tile 0 into buffer 0
  {
    char* ab = (char*)As[0]; char* bb = (char*)Bs[0];
    gld16(a0, ab + w * 1024); gld16(a1, ab + (w + 4) * 1024);
    if constexpr (BN == 128){ gld16(b0, bb + w * 1024); gld16(b1, bb + (w + 4) * 1024); }
    else                    { gld16(b0, bb + w * 1024); }
  }
  __syncthreads();     // vmcnt(0) drained: tile 0 ready

  int cb = 0;
  for (int kt = 0; kt < nk; ++kt){
    if (kt + 1 < nk){  // issue prefetch of tile kt+1 into buf^1
      const int k1 = (kt + 1) * 32;
      char* ab = (char*)As[cb ^ 1]; char* bb = (char*)Bs[cb ^ 1];
      gld16(a0 + k1, ab + w * 1024); gld16(a1 + k1, ab + (w + 4) * 1024);
      if constexpr (BN == 128){ gld16(b0 + k1, bb + w * 1024); gld16(b1 + k1, bb + (w + 4) * 1024); }
      else                    { gld16(b0 + k1, bb + w * 1024); }
    }

    const u16* Ab = As[cb]; const u16* Bb = Bs[cb];
    s16x8 af[4], bfv[NT];
#pragma unroll
    for (int mi = 0; mi < 4; ++mi)
      af[mi] = *(const s16x8*)(Ab + (wm + mi*16 + l16) * 32 + 8 * g);
#pragma unroll
    for (int ni = 0; ni < NT; ++ni)
      bfv[ni] = *(const s16x8*)(Bb + (wn + ni*16 + l16) * 32 + 8 * g);
#pragma unroll
    for (int mi = 0; mi < 4; ++mi)
#pragma unroll
      for (int ni = 0; ni < NT; ++ni)
        acc[mi][ni] = mfma16(af[mi], bfv[ni], acc[mi][ni]);

    __syncthreads();   // readers done with buf cb; prefetch into cb^1 landed (vmcnt0)
    cb ^= 1;
  }

  // epilogue: C/D layout col = lane&15, row = 4*(lane>>4)+r
#pragma unroll
  for (int mi = 0; mi < 4; ++mi){
    const int rg = m0 + wm + mi*16 + 4*g;
#pragma unroll
    for (int ni = 0; ni < NT; ++ni){
      const int col = n0 + wn + ni*16 + l16;
      f32x4 v = acc[mi][ni];
#pragma unroll
      for (int r = 0; r < 4; ++r){
        const int row = rg + r;
        if constexpr (EPI == 0){
          Cb[(size_t)row * ldc + col] = f2bf(v[r]);
        } else if constexpr (EPI == 1){
          Cf[(size_t)row * ldc + col] = v[r] + bias[col] + resid[(size_t)row * ldc + col];
        } else if constexpr (EPI == 2){
          float t = v[r] + bias[col];
          float ge = 0.5f * t * (1.0f + erff(t * 0.7071067811865476f));
          Cb[(size_t)row * ldc + col] = f2bf(ge);
        } else if constexpr (EPI == 3){
          float sc = (col < 768) ? QSCALE_CONST : 1.0f;
          Cb[(size_t)row * ldc + col] = f2bf(v[r] * sc);
        } else {
          Cb[(size_t)row * ldc + col] = f2bf(v[r] * colscale);
        }
      }
    }
  }
}

// ---------------- fused flash attention v3: bias in regs, Vt dbuf, 1 barrier/tile ------
// q pre-scaled by 0.125*log2e; bias pre-scaled by log2e (exp2-domain softmax).
// q-tile 64 (4 waves x 16 q-rows), KV step 64. grid (32, 12, 2). LDS 40KB -> 4 blocks/CU.
__global__ void __launch_bounds__(256)
attn_kernel(const u16* __restrict__ qkv, const u16* __restrict__ bias, u16* __restrict__ out){
  __shared__ __align__(16) u16 Ks[2][4096];   // [buf][row64][chunk8*8], chunk c holds global chunk c^(row&7)
  __shared__ __align__(16) u16 Vt[2][4096];   // [buf][dh64][kv chunk swizzled]
  __shared__ __align__(16) u16 Pl[4][1024];   // per-wave P [q16][kv chunk swizzled]

  const int tid = threadIdx.x, w = tid >> 6, lane = tid & 63;
  const int l16 = lane & 15, g = lane >> 4;
  const int qt = blockIdx.x, h = blockIdx.y, b = blockIdx.z;
  const int rowbase = b * 2048, q0 = qt * 64;

  // --- K gld source addresses (pre-swizzled, 16B chunk granular) ---
  const int ci0 = w * 64 + lane, ci1 = ci0 + 256;
  const int r0 = ci0 >> 3, sc0 = ci0 & 7, r1 = ci1 >> 3, sc1 = ci1 & 7;
  const u16* kp0 = qkv + (size_t)(rowbase + r0) * 2304 + 768 + h * 64 + (((sc0 ^ (r0 & 7)) & 7) << 3);
  const u16* kp1 = qkv + (size_t)(rowbase + r1) * 2304 + 768 + h * 64 + (((sc1 ^ (r1 & 7)) & 7) << 3);
  // --- V staging: thread covers dh0,dh0+1 x kv rows vs*8..vs*8+7 ---
  const int dh0 = (tid & 31) * 2, vs = tid >> 5;
  const u16* vp = qkv + (size_t)(rowbase + vs * 8) * 2304 + 1536 + h * 64 + dh0;
  u16x2 vr[8];
  // --- bias: per-lane direct loads; lane owns q = q0 + 16w + l16, cols kv0+16mi+4g ---
  const u16* bptr = bias + ((size_t)h * 2048 + q0 + w * 16 + l16) * 2048 + 4 * g;
  u16x4 brc[4], brn[4];

  // --- Q fragments: B-operand, col = q_local = l16 ---
  const u16* qrow = qkv + (size_t)(rowbase + q0 + w * 16 + l16) * 2304 + h * 64;
  s16x8 qf0 = *(const s16x8*)(qrow + 8 * g);
  s16x8 qf1 = *(const s16x8*)(qrow + 32 + 8 * g);

  f32x4 oacc[4] = {};
  float mrun = -3.0e38f, lrun = 0.f;
  const int sw = l16 & 7;

  // prologue: stage tile 0 (K -> Ks[0], V -> Vt[0], bias -> brc)
  {
    char* kb = (char*)Ks[0] + w * 1024;
    gld16(kp0, kb); gld16(kp1, kb + 4096);
#pragma unroll
    for (int i = 0; i < 8; ++i) vr[i] = *(const u16x2*)(vp + (size_t)i * 2304);
#pragma unroll
    for (int mi = 0; mi < 4; ++mi) brc[mi] = *(const u16x4*)(bptr + 16 * mi);
    s16x8 vA, vB;
#pragma unroll
    for (int j = 0; j < 8; ++j){ vA[j] = (short)vr[j][0]; vB[j] = (short)vr[j][1]; }
    *(s16x8*)(Vt[0] + dh0 * 64 + ((vs ^ (dh0 & 7)) << 3)) = vA;
    *(s16x8*)(Vt[0] + (dh0 + 1) * 64 + ((vs ^ ((dh0 + 1) & 7)) << 3)) = vB;
  }
  __syncthreads();

  for (int t = 0; t < 32; ++t){
    const int cb = t & 1;
    if (t < 31){  // prefetch tile t+1: K -> Ks[cb^1], V -> regs, bias -> brn
      const size_t koff = (size_t)(t + 1) * 64 * 2304;
      char* kb = (char*)Ks[cb ^ 1] + w * 1024;
      gld16(kp0 + koff, kb); gld16(kp1 + koff, kb + 4096);
      const u16* p = vp + koff;
#pragma unroll
      for (int i = 0; i < 8; ++i) vr[i] = *(const u16x2*)(p + (size_t)i * 2304);
      const u16* bp = bptr + (t + 1) * 64;
#pragma unroll
      for (int mi = 0; mi < 4; ++mi) brn[mi] = *(const u16x4*)(bp + 16 * mi);
    }

    // S2^T = K * Q2^T (log2-domain scores): lane holds q = l16, kv = 16mi + 4g + r
    f32x4 st[4];
#pragma unroll
    for (int mi = 0; mi < 4; ++mi){
      const int row = l16 + 16 * mi;
      s16x8 kf0 = *(const s16x8*)(Ks[cb] + row * 64 + ((g ^ sw) << 3));
      s16x8 kf1 = *(const s16x8*)(Ks[cb] + row * 64 + (((g + 4) ^ sw) << 3));
      f32x4 z = {};
      z = mfma16(kf0, qf0, z);
      st[mi] = mfma16(kf1, qf1, z);
    }

    // + bias (regs) + online softmax (per lane, one q)
    float tmax = -3.0e38f;
#pragma unroll
    for (int mi = 0; mi < 4; ++mi){
#pragma unroll
      for (int r = 0; r < 4; ++r){
        float v = st[mi][r] + bf2f(brc[mi][r]);
        st[mi][r] = v;
        tmax = fmaxf(tmax, v);
      }
    }
    tmax = fmaxf(tmax, __shfl_xor(tmax, 16));
    tmax = fmaxf(tmax, __shfl_xor(tmax, 32));
    // defer-max (T13): only rescale when the running max grows by > 8 (log2)
    if (!__all(tmax <= mrun + 8.f)){
      float mnew = fmaxf(mrun, tmax);
      float al = fexp2(mrun - mnew);
      mrun = mnew;
      lrun *= al;
#pragma unroll
      for (int r = 0; r < 4; ++r){
        float aq = __shfl(al, 4 * g + r);
#pragma unroll
        for (int ni = 0; ni < 4; ++ni) oacc[ni][r] *= aq;
      }
    }
    float ssum = 0.f;
#pragma unroll
    for (int mi = 0; mi < 4; ++mi){
      u16x4 pk;
#pragma unroll
      for (int r = 0; r < 4; ++r){
        float pv = fexp2(st[mi][r] - mrun);
        ssum += pv;
        pk[r] = f2bf(pv);
      }
      *(u16x4*)(Pl[w] + l16 * 64 + (((2*mi + (g >> 1)) ^ sw) << 3) + 4 * (g & 1)) = pk;
    }
    ssum += __shfl_xor(ssum, 16);
    ssum += __shfl_xor(ssum, 32);
    lrun += ssum;

    // O += P @ V (reads Vt[cb])
#pragma unroll
    for (int ks2 = 0; ks2 < 2; ++ks2){
      s16x8 pf = *(const s16x8*)(Pl[w] + l16 * 64 + (((4*ks2 + g) ^ sw) << 3));
#pragma unroll
      for (int ni = 0; ni < 4; ++ni){
        const int dh = l16 + 16 * ni;
        s16x8 vf = *(const s16x8*)(Vt[cb] + dh * 64 + (((4*ks2 + g) ^ sw) << 3));
        oacc[ni] = mfma16(pf, vf, oacc[ni]);
      }
    }

    if (t < 31){  // write V(t+1) into Vt[cb^1]; safe: last read of Vt[cb^1] was PV(t-1)
      s16x8 vA, vB;
#pragma unroll
      for (int j = 0; j < 8; ++j){ vA[j] = (short)vr[j][0]; vB[j] = (short)vr[j][1]; }
      *(s16x8*)(Vt[cb ^ 1] + dh0 * 64 + ((vs ^ (dh0 & 7)) << 3)) = vA;
      *(s16x8*)(Vt[cb ^ 1] + (dh0 + 1) * 64 + ((vs ^ ((dh0 + 1) & 7)) << 3)) = vB;
#pragma unroll
      for (int mi = 0; mi < 4; ++mi) brc[mi] = brn[mi];
    }
    __syncthreads();   // single barrier: K(t+1) in LDS, Vt[cb^1] visible, WAR for next gld
  }

  // finalize: divide by l, write merged-head output; row q_local = 4g+r
#pragma unroll
  for (int r = 0; r < 4; ++r){
    float lq = __shfl(lrun, 4 * g + r);
    float inv = 1.0f / lq;
    const int row = rowbase + q0 + w * 16 + 4 * g + r;
#pragma unroll
    for (int ni = 0; ni < 4; ++ni)
      out[(size_t)row * 768 + h * 64 + l16 + 16 * ni] = f2bf(oacc[ni][r] * inv);
  }
}

// ============================== host ==============================
extern "C" void kernel_launch(void* const* d_in, const int* in_sizes, int n_in,
                              void* d_out, int out_size, void* d_ws, size_t ws_size,
                              hipStream_t stream){
  const float* in_x    = (const float*)d_in[0];
  const float* in_ctx  = (const float*)d_in[1];
  const float* in_bias = (const float*)d_in[2];
  const float* ln1_w = (const float*)d_in[3];
  const float* ln1_b = (const float*)d_in[4];
  const float* w_qkv = (const float*)d_in[5];
  const float* w_so  = (const float*)d_in[6];
  const float* b_so  = (const float*)d_in[7];
  const float* ln2_w = (const float*)d_in[8];
  const float* ln2_b = (const float*)d_in[9];
  const float* w_q   = (const float*)d_in[10];
  const float* w_k   = (const float*)d_in[11];
  const float* w_v   = (const float*)d_in[12];
  const float* w_co  = (const float*)d_in[13];
  const float* b_co  = (const float*)d_in[14];
  const float* ln3_w = (const float*)d_in[15];
  const float* ln3_b = (const float*)d_in[16];
  const float* w_f1  = (const float*)d_in[17];
  const float* b_f1  = (const float*)d_in[18];
  const float* w_f2  = (const float*)d_in[19];
  const float* b_f2  = (const float*)d_in[20];
  const float* lnout_w = (const float*)d_in[21];
  const float* lnout_b = (const float*)d_in[22];

  char* p = (char*)d_ws;
  float* xbuf  = (float*)p;  p += 4096ll * 768 * 4;
  u16* xn      = (u16*)p;    p += 4096ll * 768 * 2;
  u16* cn      = (u16*)p;    p += 4096ll * 768 * 2;
  u16* qkvb    = (u16*)p;    p += 4096ll * 2304 * 2;
  u16* attO    = (u16*)p;    p += 4096ll * 768 * 2;
  u16* ffh     = (u16*)p;    p += 4096ll * 3072 * 2;
  u16* wqkvT   = (u16*)p;    p += 4ll * 2304 * 768 * 2;
  u16* wsoT    = (u16*)p;    p += 4ll * 768 * 768 * 2;
  u16* wqT     = (u16*)p;    p += 4ll * 768 * 768 * 2;
  u16* wkvT    = (u16*)p;    p += 4ll * 1536 * 768 * 2;   // per layer: [k | v] row-blocks
  u16* wcoT    = (u16*)p;    p += 4ll * 768 * 768 * 2;
  u16* wf1T    = (u16*)p;    p += 4ll * 3072 * 768 * 2;
  u16* wf2T    = (u16*)p;    p += 4ll * 768 * 3072 * 2;
  u16* biasbf  = (u16*)p;    p += 12ll * 2048 * 2048 * 2;

  hipMemcpyAsync(xbuf, in_x, 4096ll * 768 * 4, hipMemcpyDeviceToDevice, stream);

  const dim3 tb(32, 8);
  transpose_cvt<<<dim3(72, 24, 4), tb, 0, stream>>>(w_qkv, wqkvT, 768, 2304, 2304ll*768);
  transpose_cvt<<<dim3(24, 24, 4), tb, 0, stream>>>(w_so,  wsoT,  768, 768,  768ll*768);
  transpose_cvt<<<dim3(24, 24, 4), tb, 0, stream>>>(w_q,   wqT,   768, 768,  768ll*768);
  transpose_cvt<<<dim3(24, 24, 4), tb, 0, stream>>>(w_k,   wkvT,             768, 768, 1536ll*768);
  transpose_cvt<<<dim3(24, 24, 4), tb, 0, stream>>>(w_v,   wkvT + 768ll*768, 768, 768, 1536ll*768);
  transpose_cvt<<<dim3(24, 24, 4), tb, 0, stream>>>(w_co,  wcoT,  768, 768,  768ll*768);
  transpose_cvt<<<dim3(96, 24, 4), tb, 0, stream>>>(w_f1,  wf1T,  768, 3072, 3072ll*768);
  transpose_cvt<<<dim3(24, 96, 4), tb, 0, stream>>>(w_f2,  wf2T,  3072, 768, 768ll*3072);
  cvt_bias<<<49152, 256, 0, stream>>>(in_bias, biasbf);

  const dim3 ag(32, 12, 2);
  for (int i = 0; i < 4; ++i){
    // self-attention block
    ln_kernel<u16><<<4096, 256, 0, stream>>>(xbuf, nullptr, ln1_w + i*768, ln1_b + i*768, xn, nullptr);
    gemm_bf16<128,3><<<dim3(32, 18), 256, 0, stream>>>(xn, 768, wqkvT + (size_t)i*2304*768, 768, 24,
                                                       qkvb, nullptr, 2304, nullptr, nullptr, nullptr, nullptr);
    attn_kernel<<<ag, 256, 0, stream>>>(qkvb, biasbf, attO);
    gemm_bf16<64,1><<<dim3(32, 12), 256, 0, stream>>>(attO, 768, wsoT + (size_t)i*768*768, 768, 24,
                                                      nullptr, xbuf, 768, b_so + i*768, xbuf, nullptr, nullptr);
    // cross-attention block (dual LN in one dispatch; merged q/k/v projection)
    ln_kernel<u16><<<8192, 256, 0, stream>>>(xbuf, in_ctx, ln2_w + i*768, ln2_b + i*768, xn, cn);
    gemm_bf16<64,4><<<dim3(32, 12, 3), 256, 0, stream>>>(xn, 768, wqT + (size_t)i*768*768, 768, 24,
                                                         qkvb, nullptr, 2304, nullptr, nullptr,
                                                         cn, wkvT + (size_t)i*1536*768);
    attn_kernel<<<ag, 256, 0, stream>>>(qkvb, biasbf, attO);
    gemm_bf16<64,1><<<dim3(32, 12), 256, 0, stream>>>(attO, 768, wcoT + (size_t)i*768*768, 768, 24,
                                                      nullptr, xbuf, 768, b_co + i*768, xbuf, nullptr, nullptr);
    // FFN block
    ln_kernel<u16><<<4096, 256, 0, stream>>>(xbuf, nullptr, ln3_w + i*768, ln3_b + i*768, xn, nullptr);
    gemm_bf16<128,2><<<dim3(32, 24), 256, 0, stream>>>(xn, 768, wf1T + (size_t)i*3072*768, 768, 24,
                                                       ffh, nullptr, 3072, b_f1 + i*3072, nullptr, nullptr, nullptr);
    gemm_bf16<64,1><<<dim3(32, 12), 256, 0, stream>>>(ffh, 3072, wf2T + (size_t)i*768*3072, 3072, 96,
                                                      nullptr, xbuf, 768, b_f2 + i*768, xbuf, nullptr, nullptr);
  }
  ln_kernel<float><<<4096, 256, 0, stream>>>(xbuf, nullptr, lnout_w, lnout_b, (float*)d_out, nullptr);
}

// Round 5
// 1458.607 us; speedup vs baseline: 1.4906x; 1.0008x over previous
//
#include <hip/hip_runtime.h>
#include <cstdint>
#include <cstddef>

#define DEV static __device__ __forceinline__

typedef float  f32x4 __attribute__((ext_vector_type(4)));
typedef short  s16x8 __attribute__((ext_vector_type(8)));
typedef unsigned short u16;
typedef unsigned short u16x2 __attribute__((ext_vector_type(2)));
typedef unsigned short u16x4 __attribute__((ext_vector_type(4)));
typedef __bf16 bf16x8 __attribute__((ext_vector_type(8)));

#define LOG2E 1.4426950408889634f
#define QSCALE_CONST 0.18033688011112042f   /* 0.125 * log2(e) */

DEV float bf2f(u16 v){ union { unsigned u; float f; } x; x.u = ((unsigned)v) << 16; return x.f; }
DEV u16 f2bf(float f){ return __builtin_bit_cast(u16, (__bf16)f); }   // RNE via v_cvt

DEV float fexp2(float x){
#if __has_builtin(__builtin_amdgcn_exp2f)
  return __builtin_amdgcn_exp2f(x);
#else
  return exp2f(x);
#endif
}

DEV f32x4 mfma16(s16x8 a, s16x8 b, f32x4 c){
  return __builtin_amdgcn_mfma_f32_16x16x32_bf16(
      __builtin_bit_cast(bf16x8, a), __builtin_bit_cast(bf16x8, b), c, 0, 0, 0);
}

// async global->LDS, 16B per lane; LDS dest = wave-uniform base + lane*16
DEV void gld16(const void* g, void* l){
  __builtin_amdgcn_global_load_lds(
      (const __attribute__((address_space(1))) void*)(uintptr_t)g,
      (__attribute__((address_space(3))) void*)(unsigned)(uintptr_t)l,
      16, 0, 0);
}

// ---------------- transpose + fp32->bf16 convert: src[K][N] -> dst[N][K] ----------------
__global__ void __launch_bounds__(256)
transpose_cvt(const float* __restrict__ src, u16* __restrict__ dst, int K, int N,
              size_t dzstride){
  int z = blockIdx.z;
  src += (size_t)z * K * N;
  dst += (size_t)z * dzstride;
  __shared__ float t[32][33];
  int n0 = blockIdx.x * 32, k0 = blockIdx.y * 32;
#pragma unroll
  for (int i = 0; i < 4; ++i)
    t[threadIdx.y + 8*i][threadIdx.x] = src[(size_t)(k0 + threadIdx.y + 8*i) * N + n0 + threadIdx.x];
  __syncthreads();
#pragma unroll
  for (int i = 0; i < 4; ++i)
    dst[(size_t)(n0 + threadIdx.y + 8*i) * K + k0 + threadIdx.x] = f2bf(t[threadIdx.x][threadIdx.y + 8*i]);
}

// ---------------- fp32 -> bf16 convert with *log2e (bias) ----------------
__global__ void __launch_bounds__(256)
cvt_bias(const float* __restrict__ in, u16* __restrict__ out){
  size_t i = ((size_t)blockIdx.x * 256 + threadIdx.x) * 4;
  f32x4 v = *(const f32x4*)(in + i);
  u16x4 o;
#pragma unroll
  for (int j = 0; j < 4; ++j) o[j] = f2bf(v[j] * LOG2E);
  *(u16x4*)(out + i) = o;
}

// ---------------- LayerNorm over D=768, one block per row ----------------
template<typename OUT>
__global__ void __launch_bounds__(256)
ln_kernel(const float* __restrict__ x0, const float* __restrict__ x1,
          const float* __restrict__ w, const float* __restrict__ bsh,
          OUT* __restrict__ o0, OUT* __restrict__ o1){
  int row = blockIdx.x, tid = threadIdx.x;
  const float* xr; OUT* orow;
  if (row < 4096){ xr = x0 + (size_t)row * 768; orow = o0 + (size_t)row * 768; }
  else           { xr = x1 + (size_t)(row - 4096) * 768; orow = o1 + (size_t)(row - 4096) * 768; }
  float v0 = xr[tid], v1 = xr[tid + 256], v2 = xr[tid + 512];
  float s = v0 + v1 + v2, s2 = v0*v0 + v1*v1 + v2*v2;
#pragma unroll
  for (int off = 1; off < 64; off <<= 1){ s += __shfl_xor(s, off); s2 += __shfl_xor(s2, off); }
  __shared__ float red[8];
  int wid = tid >> 6;
  if ((tid & 63) == 0){ red[wid] = s; red[wid + 4] = s2; }
  __syncthreads();
  s  = red[0] + red[1] + red[2] + red[3];
  s2 = red[4] + red[5] + red[6] + red[7];
  float m = s * (1.f/768.f);
  float var = s2 * (1.f/768.f) - m * m;
  float rstd = rsqrtf(var + 1e-5f);
#pragma unroll
  for (int i = 0; i < 3; ++i){
    int c = tid + 256 * i;
    float vv = (i == 0 ? v0 : (i == 1 ? v1 : v2));
    float o = (vv - m) * rstd * w[c] + bsh[c];
    if constexpr (sizeof(OUT) == 2) orow[c] = f2bf(o);
    else                            orow[c] = o;
  }
}

// ---------------- bf16 GEMM, double-buffered pipelined staging ----------------
// C[M,N] = A[M,K] @ B[K,N], B given transposed [N][K]. BM=128 x BN(128|64), BK=32, 4 waves.
// EPI 0: bf16 store; EPI 1: fp32 acc+bias[col]+resid; EPI 2: bf16 gelu(acc+bias);
// EPI 3: bf16 store, cols<768 scaled by QSCALE_CONST;
// EPI 4: merged cross q/k/v: z=0:(A,Bt)= (A,Bt) scaled, z=1/2:(A2, Bt2[+768*768]), out += z*768.
template<int BN, int EPI>
__global__ void __launch_bounds__(256)
gemm_bf16(const u16* __restrict__ A, int lda, const u16* __restrict__ Bt, int ldb,
          int nk, u16* __restrict__ Cb, float* __restrict__ Cf, int ldc,
          const float* __restrict__ bias, const float* __restrict__ resid,
          const u16* __restrict__ A2, const u16* __restrict__ Bt2){
  constexpr int NT = BN / 32;             // N fragments per wave
  __shared__ u16 As[2][128 * 32];
  __shared__ u16 Bs[2][BN * 32];
  float colscale = 1.0f;
  if constexpr (EPI == 4){
    const int z = blockIdx.z;
    if (z == 0){ colscale = QSCALE_CONST; }
    else { A = A2; Bt = Bt2 + (size_t)(z - 1) * 768 * 768; }
    Cb += z * 768;
  }
  const int tid = threadIdx.x, w = tid >> 6, lane = tid & 63;
  const int l16 = lane & 15, g = lane >> 4;
  const int m0 = blockIdx.x * 128, n0 = blockIdx.y * BN;
  const int wm = (w >> 1) * 64, wn = (w & 1) * (BN / 2);
  f32x4 acc[4][NT] = {};

  // staging map: chunk L = (w+4i)*1024 + lane*16 bytes -> row = L>>6, short-col = (L&63)>>1
  const int L0 = w * 1024 + lane * 16;
  const int L1 = (w + 4) * 1024 + lane * 16;
  const u16* a0 = A + (size_t)(m0 + (L0 >> 6)) * lda + ((L0 & 63) >> 1);
  const u16* a1 = A + (size_t)(m0 + (L1 >> 6)) * lda + ((L1 & 63) >> 1);
  const u16* b0; const u16* b1 = nullptr;
  if constexpr (BN == 128){
    b0 = Bt + (size_t)(n0 + (L0 >> 6)) * ldb + ((L0 & 63) >> 1);
    b1 = Bt + (size_t)(n0 + (L1 >> 6)) * ldb + ((L1 & 63) >> 1);
  } else {
    const int Lb = tid * 16;
    b0 = Bt + (size_t)(n0 + (Lb >> 6)) * ldb + ((Lb & 63) >> 1);
  }

  // prologue: stage k-tile 0 into buffer 0
  {
    char* ab = (char*)As[0]; char* bb = (char*)Bs[0];
    gld16(a0, ab + w * 1024); gld16(a1, ab + (w + 4) * 1024);
    if constexpr (BN == 128){ gld16(b0, bb + w * 1024); gld16(b1, bb + (w + 4) * 1024); }
    else                    { gld16(b0, bb + w * 1024); }
  }
  __syncthreads();     // vmcnt(0) drained: tile 0 ready

  int cb = 0;
  for (int kt = 0; kt < nk; ++kt){
    if (kt + 1 < nk){  // issue prefetch of tile kt+1 into buf^1
      const int k1 = (kt + 1) * 32;
      char* ab = (char*)As[cb ^ 1]; char* bb = (char*)Bs[cb ^ 1];
      gld16(a0 + k1, ab + w * 1024); gld16(a1 + k1, ab + (w + 4) * 1024);
      if constexpr (BN == 128){ gld16(b0 + k1, bb + w * 1024); gld16(b1 + k1, bb + (w + 4) * 1024); }
      else                    { gld16(b0 + k1, bb + w * 1024); }
    }

    const u16* Ab = As[cb]; const u16* Bb = Bs[cb];
    s16x8 af[4], bfv[NT];
#pragma unroll
    for (int mi = 0; mi < 4; ++mi)
      af[mi] = *(const s16x8*)(Ab + (wm + mi*16 + l16) * 32 + 8 * g);
#pragma unroll
    for (int ni = 0; ni < NT; ++ni)
      bfv[ni] = *(const s16x8*)(Bb + (wn + ni*16 + l16) * 32 + 8 * g);
#pragma unroll
    for (int mi = 0; mi < 4; ++mi)
#pragma unroll
      for (int ni = 0; ni < NT; ++ni)
        acc[mi][ni] = mfma16(af[mi], bfv[ni], acc[mi][ni]);

    __syncthreads();   // readers done with buf cb; prefetch into cb^1 landed (vmcnt0)
    cb ^= 1;
  }

  // epilogue: C/D layout col = lane&15, row = 4*(lane>>4)+r
#pragma unroll
  for (int mi = 0; mi < 4; ++mi){
    const int rg = m0 + wm + mi*16 + 4*g;
#pragma unroll
    for (int ni = 0; ni < NT; ++ni){
      const int col = n0 + wn + ni*16 + l16;
      f32x4 v = acc[mi][ni];
#pragma unroll
      for (int r = 0; r < 4; ++r){
        const int row = rg + r;
        if constexpr (EPI == 0){
          Cb[(size_t)row * ldc + col] = f2bf(v[r]);
        } else if constexpr (EPI == 1){
          Cf[(size_t)row * ldc + col] = v[r] + bias[col] + resid[(size_t)row * ldc + col];
        } else if constexpr (EPI == 2){
          float t = v[r] + bias[col];
          float ge = 0.5f * t * (1.0f + erff(t * 0.7071067811865476f));
          Cb[(size_t)row * ldc + col] = f2bf(ge);
        } else if constexpr (EPI == 3){
          float sc = (col < 768) ? QSCALE_CONST : 1.0f;
          Cb[(size_t)row * ldc + col] = f2bf(v[r] * sc);
        } else {
          Cb[(size_t)row * ldc + col] = f2bf(v[r] * colscale);
        }
      }
    }
  }
}

// ---------------- fused flash attention v3: bias in regs, Vt dbuf, 1 barrier/tile ------
// q pre-scaled by 0.125*log2e; bias pre-scaled by log2e (exp2-domain softmax).
// q-tile 64 (4 waves x 16 q-rows), KV step 64. grid (32, 12, 2). LDS 40KB -> 4 blocks/CU.
__global__ void __launch_bounds__(256)
attn_kernel(const u16* __restrict__ qkv, const u16* __restrict__ bias, u16* __restrict__ out){
  __shared__ __align__(16) u16 Ks[2][4096];   // [buf][row64][chunk8*8], chunk c holds global chunk c^(row&7)
  __shared__ __align__(16) u16 Vt[2][4096];   // [buf][dh64][kv chunk swizzled]
  __shared__ __align__(16) u16 Pl[4][1024];   // per-wave P [q16][kv chunk swizzled]

  const int tid = threadIdx.x, w = tid >> 6, lane = tid & 63;
  const int l16 = lane & 15, g = lane >> 4;
  const int qt = blockIdx.x, h = blockIdx.y, b = blockIdx.z;
  const int rowbase = b * 2048, q0 = qt * 64;

  // --- K gld source addresses (pre-swizzled, 16B chunk granular) ---
  const int ci0 = w * 64 + lane, ci1 = ci0 + 256;
  const int r0 = ci0 >> 3, sc0 = ci0 & 7, r1 = ci1 >> 3, sc1 = ci1 & 7;
  const u16* kp0 = qkv + (size_t)(rowbase + r0) * 2304 + 768 + h * 64 + (((sc0 ^ (r0 & 7)) & 7) << 3);
  const u16* kp1 = qkv + (size_t)(rowbase + r1) * 2304 + 768 + h * 64 + (((sc1 ^ (r1 & 7)) & 7) << 3);
  // --- V staging: thread covers dh0,dh0+1 x kv rows vs*8..vs*8+7 ---
  const int dh0 = (tid & 31) * 2, vs = tid >> 5;
  const u16* vp = qkv + (size_t)(rowbase + vs * 8) * 2304 + 1536 + h * 64 + dh0;
  u16x2 vr[8];
  // --- bias: per-lane direct loads; lane owns q = q0 + 16w + l16, cols kv0+16mi+4g ---
  const u16* bptr = bias + ((size_t)h * 2048 + q0 + w * 16 + l16) * 2048 + 4 * g;
  u16x4 brc[4], brn[4];

  // --- Q fragments: B-operand, col = q_local = l16 ---
  const u16* qrow = qkv + (size_t)(rowbase + q0 + w * 16 + l16) * 2304 + h * 64;
  s16x8 qf0 = *(const s16x8*)(qrow + 8 * g);
  s16x8 qf1 = *(const s16x8*)(qrow + 32 + 8 * g);

  f32x4 oacc[4] = {};
  float mrun = -3.0e38f, lrun = 0.f;
  const int sw = l16 & 7;

  // prologue: stage tile 0 (K -> Ks[0], V -> Vt[0], bias -> brc)
  {
    char* kb = (char*)Ks[0] + w * 1024;
    gld16(kp0, kb); gld16(kp1, kb + 4096);
#pragma unroll
    for (int i = 0; i < 8; ++i) vr[i] = *(const u16x2*)(vp + (size_t)i * 2304);
#pragma unroll
    for (int mi = 0; mi < 4; ++mi) brc[mi] = *(const u16x4*)(bptr + 16 * mi);
    s16x8 vA, vB;
#pragma unroll
    for (int j = 0; j < 8; ++j){ vA[j] = (short)vr[j][0]; vB[j] = (short)vr[j][1]; }
    *(s16x8*)(Vt[0] + dh0 * 64 + ((vs ^ (dh0 & 7)) << 3)) = vA;
    *(s16x8*)(Vt[0] + (dh0 + 1) * 64 + ((vs ^ ((dh0 + 1) & 7)) << 3)) = vB;
  }
  __syncthreads();

  for (int t = 0; t < 32; ++t){
    const int cb = t & 1;
    if (t < 31){  // prefetch tile t+1: K -> Ks[cb^1], V -> regs, bias -> brn
      const size_t koff = (size_t)(t + 1) * 64 * 2304;
      char* kb = (char*)Ks[cb ^ 1] + w * 1024;
      gld16(kp0 + koff, kb); gld16(kp1 + koff, kb + 4096);
      const u16* p = vp + koff;
#pragma unroll
      for (int i = 0; i < 8; ++i) vr[i] = *(const u16x2*)(p + (size_t)i * 2304);
      const u16* bp = bptr + (t + 1) * 64;
#pragma unroll
      for (int mi = 0; mi < 4; ++mi) brn[mi] = *(const u16x4*)(bp + 16 * mi);
    }

    // S2^T = K * Q2^T (log2-domain scores): lane holds q = l16, kv = 16mi + 4g + r
    f32x4 st[4];
#pragma unroll
    for (int mi = 0; mi < 4; ++mi){
      const int row = l16 + 16 * mi;
      s16x8 kf0 = *(const s16x8*)(Ks[cb] + row * 64 + ((g ^ sw) << 3));
      s16x8 kf1 = *(const s16x8*)(Ks[cb] + row * 64 + (((g + 4) ^ sw) << 3));
      f32x4 z = {};
      z = mfma16(kf0, qf0, z);
      st[mi] = mfma16(kf1, qf1, z);
    }

    // + bias (regs) + online softmax (per lane, one q)
    float tmax = -3.0e38f;
#pragma unroll
    for (int mi = 0; mi < 4; ++mi){
#pragma unroll
      for (int r = 0; r < 4; ++r){
        float v = st[mi][r] + bf2f(brc[mi][r]);
        st[mi][r] = v;
        tmax = fmaxf(tmax, v);
      }
    }
    tmax = fmaxf(tmax, __shfl_xor(tmax, 16));
    tmax = fmaxf(tmax, __shfl_xor(tmax, 32));
    // defer-max (T13): only rescale when the running max grows by > 8 (log2)
    if (!__all(tmax <= mrun + 8.f)){
      float mnew = fmaxf(mrun, tmax);
      float al = fexp2(mrun - mnew);
      mrun = mnew;
      lrun *= al;
#pragma unroll
      for (int r = 0; r < 4; ++r){
        float aq = __shfl(al, 4 * g + r);
#pragma unroll
        for (int ni = 0; ni < 4; ++ni) oacc[ni][r] *= aq;
      }
    }
    float ssum = 0.f;
#pragma unroll
    for (int mi = 0; mi < 4; ++mi){
      u16x4 pk;
#pragma unroll
      for (int r = 0; r < 4; ++r){
        float pv = fexp2(st[mi][r] - mrun);
        ssum += pv;
        pk[r] = f2bf(pv);
      }
      *(u16x4*)(Pl[w] + l16 * 64 + (((2*mi + (g >> 1)) ^ sw) << 3) + 4 * (g & 1)) = pk;
    }
    ssum += __shfl_xor(ssum, 16);
    ssum += __shfl_xor(ssum, 32);
    lrun += ssum;

    // O += P @ V (reads Vt[cb])
#pragma unroll
    for (int ks2 = 0; ks2 < 2; ++ks2){
      s16x8 pf = *(const s16x8*)(Pl[w] + l16 * 64 + (((4*ks2 + g) ^ sw) << 3));
#pragma unroll
      for (int ni = 0; ni < 4; ++ni){
        const int dh = l16 + 16 * ni;
        s16x8 vf = *(const s16x8*)(Vt[cb] + dh * 64 + (((4*ks2 + g) ^ sw) << 3));
        oacc[ni] = mfma16(pf, vf, oacc[ni]);
      }
    }

    if (t < 31){  // write V(t+1) into Vt[cb^1]; safe: last read of Vt[cb^1] was PV(t-1)
      s16x8 vA, vB;
#pragma unroll
      for (int j = 0; j < 8; ++j){ vA[j] = (short)vr[j][0]; vB[j] = (short)vr[j][1]; }
      *(s16x8*)(Vt[cb ^ 1] + dh0 * 64 + ((vs ^ (dh0 & 7)) << 3)) = vA;
      *(s16x8*)(Vt[cb ^ 1] + (dh0 + 1) * 64 + ((vs ^ ((dh0 + 1) & 7)) << 3)) = vB;
#pragma unroll
      for (int mi = 0; mi < 4; ++mi) brc[mi] = brn[mi];
    }
    __syncthreads();   // single barrier: K(t+1) in LDS, Vt[cb^1] visible, WAR for next gld
  }

  // finalize: divide by l, write merged-head output; row q_local = 4g+r
#pragma unroll
  for (int r = 0; r < 4; ++r){
    float lq = __shfl(lrun, 4 * g + r);
    float inv = 1.0f / lq;
    const int row = rowbase + q0 + w * 16 + 4 * g + r;
#pragma unroll
    for (int ni = 0; ni < 4; ++ni)
      out[(size_t)row * 768 + h * 64 + l16 + 16 * ni] = f2bf(oacc[ni][r] * inv);
  }
}

// ============================== host ==============================
extern "C" void kernel_launch(void* const* d_in, const int* in_sizes, int n_in,
                              void* d_out, int out_size, void* d_ws, size_t ws_size,
                              hipStream_t stream){
  const float* in_x    = (const float*)d_in[0];
  const float* in_ctx  = (const float*)d_in[1];
  const float* in_bias = (const float*)d_in[2];
  const float* ln1_w = (const float*)d_in[3];
  const float* ln1_b = (const float*)d_in[4];
  const float* w_qkv = (const float*)d_in[5];
  const float* w_so  = (const float*)d_in[6];
  const float* b_so  = (const float*)d_in[7];
  const float* ln2_w = (const float*)d_in[8];
  const float* ln2_b = (const float*)d_in[9];
  const float* w_q   = (const float*)d_in[10];
  const float* w_k   = (const float*)d_in[11];
  const float* w_v   = (const float*)d_in[12];
  const float* w_co  = (const float*)d_in[13];
  const float* b_co  = (const float*)d_in[14];
  const float* ln3_w = (const float*)d_in[15];
  const float* ln3_b = (const float*)d_in[16];
  const float* w_f1  = (const float*)d_in[17];
  const float* b_f1  = (const float*)d_in[18];
  const float* w_f2  = (const float*)d_in[19];
  const float* b_f2  = (const float*)d_in[20];
  const float* lnout_w = (const float*)d_in[21];
  const float* lnout_b = (const float*)d_in[22];

  char* p = (char*)d_ws;
  float* xbuf  = (float*)p;  p += 4096ll * 768 * 4;
  u16* xn      = (u16*)p;    p += 4096ll * 768 * 2;
  u16* cn      = (u16*)p;    p += 4096ll * 768 * 2;
  u16* qkvb    = (u16*)p;    p += 4096ll * 2304 * 2;
  u16* attO    = (u16*)p;    p += 4096ll * 768 * 2;
  u16* ffh     = (u16*)p;    p += 4096ll * 3072 * 2;
  u16* wqkvT   = (u16*)p;    p += 4ll * 2304 * 768 * 2;
  u16* wsoT    = (u16*)p;    p += 4ll * 768 * 768 * 2;
  u16* wqT     = (u16*)p;    p += 4ll * 768 * 768 * 2;
  u16* wkvT    = (u16*)p;    p += 4ll * 1536 * 768 * 2;   // per layer: [k | v] row-blocks
  u16* wcoT    = (u16*)p;    p += 4ll * 768 * 768 * 2;
  u16* wf1T    = (u16*)p;    p += 4ll * 3072 * 768 * 2;
  u16* wf2T    = (u16*)p;    p += 4ll * 768 * 3072 * 2;
  u16* biasbf  = (u16*)p;    p += 12ll * 2048 * 2048 * 2;

  hipMemcpyAsync(xbuf, in_x, 4096ll * 768 * 4, hipMemcpyDeviceToDevice, stream);

  const dim3 tb(32, 8);
  transpose_cvt<<<dim3(72, 24, 4), tb, 0, stream>>>(w_qkv, wqkvT, 768, 2304, 2304ll*768);
  transpose_cvt<<<dim3(24, 24, 4), tb, 0, stream>>>(w_so,  wsoT,  768, 768,  768ll*768);
  transpose_cvt<<<dim3(24, 24, 4), tb, 0, stream>>>(w_q,   wqT,   768, 768,  768ll*768);
  transpose_cvt<<<dim3(24, 24, 4), tb, 0, stream>>>(w_k,   wkvT,             768, 768, 1536ll*768);
  transpose_cvt<<<dim3(24, 24, 4), tb, 0, stream>>>(w_v,   wkvT + 768ll*768, 768, 768, 1536ll*768);
  transpose_cvt<<<dim3(24, 24, 4), tb, 0, stream>>>(w_co,  wcoT,  768, 768,  768ll*768);
  transpose_cvt<<<dim3(96, 24, 4), tb, 0, stream>>>(w_f1,  wf1T,  768, 3072, 3072ll*768);
  transpose_cvt<<<dim3(24, 96, 4), tb, 0, stream>>>(w_f2,  wf2T,  3072, 768, 768ll*3072);
  cvt_bias<<<49152, 256, 0, stream>>>(in_bias, biasbf);

  const dim3 ag(32, 12, 2);
  for (int i = 0; i < 4; ++i){
    // self-attention block
    ln_kernel<u16><<<4096, 256, 0, stream>>>(xbuf, nullptr, ln1_w + i*768, ln1_b + i*768, xn, nullptr);
    gemm_bf16<128,3><<<dim3(32, 18), 256, 0, stream>>>(xn, 768, wqkvT + (size_t)i*2304*768, 768, 24,
                                                       qkvb, nullptr, 2304, nullptr, nullptr, nullptr, nullptr);
    attn_kernel<<<ag, 256, 0, stream>>>(qkvb, biasbf, attO);
    gemm_bf16<64,1><<<dim3(32, 12), 256, 0, stream>>>(attO, 768, wsoT + (size_t)i*768*768, 768, 24,
                                                      nullptr, xbuf, 768, b_so + i*768, xbuf, nullptr, nullptr);
    // cross-attention block (dual LN in one dispatch; merged q/k/v projection)
    ln_kernel<u16><<<8192, 256, 0, stream>>>(xbuf, in_ctx, ln2_w + i*768, ln2_b + i*768, xn, cn);
    gemm_bf16<64,4><<<dim3(32, 12, 3), 256, 0, stream>>>(xn, 768, wqT + (size_t)i*768*768, 768, 24,
                                                         qkvb, nullptr, 2304, nullptr, nullptr,
                                                         cn, wkvT + (size_t)i*1536*768);
    attn_kernel<<<ag, 256, 0, stream>>>(qkvb, biasbf, attO);
    gemm_bf16<64,1><<<dim3(32, 12), 256, 0, stream>>>(attO, 768, wcoT + (size_t)i*768*768, 768, 24,
                                                      nullptr, xbuf, 768, b_co + i*768, xbuf, nullptr, nullptr);
    // FFN block
    ln_kernel<u16><<<4096, 256, 0, stream>>>(xbuf, nullptr, ln3_w + i*768, ln3_b + i*768, xn, nullptr);
    gemm_bf16<128,2><<<dim3(32, 24), 256, 0, stream>>>(xn, 768, wf1T + (size_t)i*3072*768, 768, 24,
                                                       ffh, nullptr, 3072, b_f1 + i*3072, nullptr, nullptr, nullptr);
    gemm_bf16<64,1><<<dim3(32, 12), 256, 0, stream>>>(ffh, 3072, wf2T + (size_t)i*768*3072, 3072, 96,
                                                      nullptr, xbuf, 768, b_f2 + i*768, xbuf, nullptr, nullptr);
  }
  ln_kernel<float><<<4096, 256, 0, stream>>>(xbuf, nullptr, lnout_w, lnout_b, (float*)d_out, nullptr);
}

// Round 6
// 1418.934 us; speedup vs baseline: 1.5323x; 1.0280x over previous
//
#include <hip/hip_runtime.h>
#include <cstdint>
#include <cstddef>

#define DEV static __device__ __forceinline__

typedef float  f32x4 __attribute__((ext_vector_type(4)));
typedef short  s16x8 __attribute__((ext_vector_type(8)));
typedef unsigned short u16;
typedef unsigned short u16x2 __attribute__((ext_vector_type(2)));
typedef unsigned short u16x4 __attribute__((ext_vector_type(4)));
typedef unsigned short u16x8 __attribute__((ext_vector_type(8)));
typedef __bf16 bf16x8 __attribute__((ext_vector_type(8)));

#define LOG2E 1.4426950408889634f
#define QSCALE_CONST 0.18033688011112042f   /* 0.125 * log2(e) */

DEV float bf2f(u16 v){ union { unsigned u; float f; } x; x.u = ((unsigned)v) << 16; return x.f; }
DEV u16 f2bf(float f){ return __builtin_bit_cast(u16, (__bf16)f); }

DEV float fexp2(float x){
#if __has_builtin(__builtin_amdgcn_exp2f)
  return __builtin_amdgcn_exp2f(x);
#else
  return exp2f(x);
#endif
}

DEV f32x4 mfma16(s16x8 a, s16x8 b, f32x4 c){
  return __builtin_amdgcn_mfma_f32_16x16x32_bf16(
      __builtin_bit_cast(bf16x8, a), __builtin_bit_cast(bf16x8, b), c, 0, 0, 0);
}

// async global->LDS, 16B per lane; LDS dest = wave-uniform base + lane*16
DEV void gld16(const void* g, void* l){
  __builtin_amdgcn_global_load_lds(
      (const __attribute__((address_space(1))) void*)(uintptr_t)g,
      (__attribute__((address_space(3))) void*)(unsigned)(uintptr_t)l,
      16, 0, 0);
}

// ---------------- transpose + fp32->bf16 convert: src[K][N] -> dst[N][K] ----------------
__global__ void __launch_bounds__(256)
transpose_cvt(const float* __restrict__ src, u16* __restrict__ dst, int K, int N,
              size_t dzstride){
  int z = blockIdx.z;
  src += (size_t)z * K * N;
  dst += (size_t)z * dzstride;
  __shared__ float t[32][33];
  int n0 = blockIdx.x * 32, k0 = blockIdx.y * 32;
#pragma unroll
  for (int i = 0; i < 4; ++i)
    t[threadIdx.y + 8*i][threadIdx.x] = src[(size_t)(k0 + threadIdx.y + 8*i) * N + n0 + threadIdx.x];
  __syncthreads();
#pragma unroll
  for (int i = 0; i < 4; ++i)
    dst[(size_t)(n0 + threadIdx.y + 8*i) * K + k0 + threadIdx.x] = f2bf(t[threadIdx.x][threadIdx.y + 8*i]);
}

// ---------------- bias -> tiled bf16 (log2e-scaled) ----------------
// layout: biasT[((h*32+qt)*32+kvt)*4096 + tid*16 + mi*4 + r]
//   = bias[h][qt*64 + (tid>>6)*16 + (tid&15)][kvt*64 + ((tid>>4)&3)*4 + mi*16 + r] * LOG2E
// so attn lane tid reads its 16 values as 2 contiguous 16B loads.
__global__ void __launch_bounds__(256)
cvt_biasT(const float* __restrict__ in, u16* __restrict__ out){
  const int kvt = blockIdx.x, qt = blockIdx.y, h = blockIdx.z, tid = threadIdx.x;
  const int q  = qt * 64 + ((tid >> 6) << 4) + (tid & 15);
  const int c0 = kvt * 64 + ((tid >> 4) & 3) * 4;
  const float* src = in + ((size_t)h * 2048 + q) * 2048;
  u16x8 o0, o1;
#pragma unroll
  for (int mi = 0; mi < 4; ++mi){
    f32x4 v = *(const f32x4*)(src + c0 + mi * 16);
#pragma unroll
    for (int r = 0; r < 4; ++r){
      u16 bv = f2bf(v[r] * LOG2E);
      if (mi < 2) o0[(mi & 1) * 4 + r] = bv; else o1[(mi & 1) * 4 + r] = bv;
    }
  }
  u16* dst = out + ((size_t)(h * 32 + qt) * 32 + kvt) * 4096 + tid * 16;
  *(u16x8*)dst = o0;
  *(u16x8*)(dst + 8) = o1;
}

// ---------------- vectorized LayerNorm, one wave per row ----------------
// grid (1024, Z): row = bx*4 + wave; params offset by z*768, out by z*4096*768.
__global__ void __launch_bounds__(256)
lnv(const float* __restrict__ x, const float* __restrict__ w, const float* __restrict__ b,
    u16* __restrict__ out){
  const int wv = threadIdx.x >> 6, lane = threadIdx.x & 63;
  const float* wz = w + blockIdx.y * 768;
  const float* bz = b + blockIdx.y * 768;
  out += (size_t)blockIdx.y * 4096 * 768;
  const int row = blockIdx.x * 4 + wv;
  const float* xr = x + (size_t)row * 768;
  f32x4 t[3]; float s = 0.f, s2 = 0.f;
#pragma unroll
  for (int c = 0; c < 3; ++c){
    t[c] = *(const f32x4*)(xr + c * 256 + lane * 4);
#pragma unroll
    for (int j = 0; j < 4; ++j){ s += t[c][j]; s2 += t[c][j] * t[c][j]; }
  }
#pragma unroll
  for (int off = 1; off < 64; off <<= 1){ s += __shfl_xor(s, off); s2 += __shfl_xor(s2, off); }
  float m = s * (1.f/768.f);
  float rstd = rsqrtf(s2 * (1.f/768.f) - m * m + 1e-5f);
#pragma unroll
  for (int c = 0; c < 3; ++c){
    const int col = c * 256 + lane * 4;
    f32x4 wv4 = *(const f32x4*)(wz + col);
    f32x4 bv4 = *(const f32x4*)(bz + col);
    u16x4 o;
#pragma unroll
    for (int j = 0; j < 4; ++j) o[j] = f2bf((t[c][j] - m) * rstd * wv4[j] + bv4[j]);
    *(u16x4*)(out + (size_t)row * 768 + col) = o;
  }
}

// ---------------- fused splitK-reduce + bias + residual + LayerNorm ----------------
// xbuf_new = p0 + p1 + biasrow + xbuf_old (stored); out = LN(xbuf_new, lw, lb).
// OUT = u16 (bf16 xn) or float (final d_out).
template<typename OUT>
__global__ void __launch_bounds__(256)
red_ln(const float* __restrict__ p, const float* __restrict__ biasrow,
       float* __restrict__ xbuf, OUT* __restrict__ out,
       const float* __restrict__ lw, const float* __restrict__ lb){
  const int wv = threadIdx.x >> 6, lane = threadIdx.x & 63;
  const int row = blockIdx.x * 4 + wv;
  const float* p0 = p + (size_t)row * 768;
  const float* p1 = p0 + 4096ll * 768;
  float* xr = xbuf + (size_t)row * 768;
  f32x4 t[3]; float s = 0.f, s2 = 0.f;
#pragma unroll
  for (int c = 0; c < 3; ++c){
    const int col = c * 256 + lane * 4;
    f32x4 v0 = *(const f32x4*)(p0 + col);
    f32x4 v1 = *(const f32x4*)(p1 + col);
    f32x4 bv = *(const f32x4*)(biasrow + col);
    f32x4 xv = *(const f32x4*)(xr + col);
    f32x4 v = v0 + v1 + bv + xv;
    *(f32x4*)(xr + col) = v;
    t[c] = v;
#pragma unroll
    for (int j = 0; j < 4; ++j){ s += v[j]; s2 += v[j] * v[j]; }
  }
#pragma unroll
  for (int off = 1; off < 64; off <<= 1){ s += __shfl_xor(s, off); s2 += __shfl_xor(s2, off); }
  float m = s * (1.f/768.f);
  float rstd = rsqrtf(s2 * (1.f/768.f) - m * m + 1e-5f);
#pragma unroll
  for (int c = 0; c < 3; ++c){
    const int col = c * 256 + lane * 4;
    f32x4 wv4 = *(const f32x4*)(lw + col);
    f32x4 bv4 = *(const f32x4*)(lb + col);
    if constexpr (sizeof(OUT) == 2){
      u16x4 o;
#pragma unroll
      for (int j = 0; j < 4; ++j) o[j] = f2bf((t[c][j] - m) * rstd * wv4[j] + bv4[j]);
      *(u16x4*)((u16*)out + (size_t)row * 768 + col) = o;
    } else {
      f32x4 o;
#pragma unroll
      for (int j = 0; j < 4; ++j) o[j] = (t[c][j] - m) * rstd * wv4[j] + bv4[j];
      *(f32x4*)((float*)out + (size_t)row * 768 + col) = o;
    }
  }
}

// ---------------- bf16 GEMM, double-buffered, templated tile ----------------
// C[M,N] = A[M,K] @ B[K,N], B transposed [N][K]. 4 waves, wave = (BM/2)x(BN/2).
// EPI 2: bf16 gelu(acc+bias[col]); EPI 3: bf16, cols<768 * QSCALE;
// EPI 4: merged cross q/k/v (z=0: A scaled; z=1/2: A2 @ Bt2[+(z-1)*768*768]; out += z*768);
// EPI 5: split-K fp32 partials (z selects K-half, Cf += z*4096*768).
template<int BM, int BN, int EPI>
__global__ void __launch_bounds__(256)
gemm_bf16(const u16* __restrict__ A, int lda, const u16* __restrict__ Bt, int ldb,
          int nk, u16* __restrict__ Cb, float* __restrict__ Cf, int ldc,
          const float* __restrict__ bias,
          const u16* __restrict__ A2, const u16* __restrict__ Bt2){
  constexpr int MT = BM / 32, NT = BN / 32;
  __shared__ u16 As[2][BM * 32];
  __shared__ u16 Bs[2][BN * 32];
  float colscale = 1.0f;
  if constexpr (EPI == 4){
    const int z = blockIdx.z;
    if (z == 0){ colscale = QSCALE_CONST; }
    else { A = A2; Bt = Bt2 + (size_t)(z - 1) * 768 * 768; }
    Cb += z * 768;
  }
  if constexpr (EPI == 5){
    const int z = blockIdx.z;
    A  += (size_t)z * nk * 32;      // K-half offset (A cols)
    Bt += (size_t)z * nk * 32;      // K-half offset (Bt cols)
    Cf += (size_t)z * 4096 * 768;   // partial buffer
  }
  const int tid = threadIdx.x, w = tid >> 6, lane = tid & 63;
  const int l16 = lane & 15, g = lane >> 4;
  const int m0 = blockIdx.x * BM, n0 = blockIdx.y * BN;
  const int wm = (w >> 1) * (BM / 2), wn = (w & 1) * (BN / 2);
  f32x4 acc[MT][NT] = {};

  // staging: chunk tid covers row tid>>2, short-col (tid&3)*8 (64B rows)
  const u16* a0 = A + (size_t)(m0 + (tid >> 2)) * lda + (tid & 3) * 8;
  const u16* a1 = (BM == 128) ? A + (size_t)(m0 + (tid >> 2) + 64) * lda + (tid & 3) * 8 : nullptr;
  const u16* b0 = Bt + (size_t)(n0 + (tid >> 2)) * ldb + (tid & 3) * 8;
  const u16* b1 = (BN == 128) ? Bt + (size_t)(n0 + (tid >> 2) + 64) * ldb + (tid & 3) * 8 : nullptr;

  // prologue: stage k-tile 0
  {
    char* ab = (char*)As[0]; char* bb = (char*)Bs[0];
    gld16(a0, ab + w * 1024);
    if constexpr (BM == 128) gld16(a1, ab + 4096 + w * 1024);
    gld16(b0, bb + w * 1024);
    if constexpr (BN == 128) gld16(b1, bb + 4096 + w * 1024);
  }
  __syncthreads();

  int cb = 0;
  for (int kt = 0; kt < nk; ++kt){
    if (kt + 1 < nk){
      const int k1 = (kt + 1) * 32;
      char* ab = (char*)As[cb ^ 1]; char* bb = (char*)Bs[cb ^ 1];
      gld16(a0 + k1, ab + w * 1024);
      if constexpr (BM == 128) gld16(a1 + k1, ab + 4096 + w * 1024);
      gld16(b0 + k1, bb + w * 1024);
      if constexpr (BN == 128) gld16(b1 + k1, bb + 4096 + w * 1024);
    }
    const u16* Ab = As[cb]; const u16* Bb = Bs[cb];
    s16x8 af[MT], bfv[NT];
#pragma unroll
    for (int mi = 0; mi < MT; ++mi)
      af[mi] = *(const s16x8*)(Ab + (wm + mi*16 + l16) * 32 + 8 * g);
#pragma unroll
    for (int ni = 0; ni < NT; ++ni)
      bfv[ni] = *(const s16x8*)(Bb + (wn + ni*16 + l16) * 32 + 8 * g);
#pragma unroll
    for (int mi = 0; mi < MT; ++mi)
#pragma unroll
      for (int ni = 0; ni < NT; ++ni)
        acc[mi][ni] = mfma16(af[mi], bfv[ni], acc[mi][ni]);
    __syncthreads();
    cb ^= 1;
  }

  // epilogue: C/D layout col = lane&15, row = 4*(lane>>4)+r
#pragma unroll
  for (int mi = 0; mi < MT; ++mi){
    const int rg = m0 + wm + mi*16 + 4*g;
#pragma unroll
    for (int ni = 0; ni < NT; ++ni){
      const int col = n0 + wn + ni*16 + l16;
      f32x4 v = acc[mi][ni];
#pragma unroll
      for (int r = 0; r < 4; ++r){
        const int row = rg + r;
        if constexpr (EPI == 2){
          float t = v[r] + bias[col];
          float ge = 0.5f * t * (1.0f + erff(t * 0.7071067811865476f));
          Cb[(size_t)row * ldc + col] = f2bf(ge);
        } else if constexpr (EPI == 3){
          float sc = (col < 768) ? QSCALE_CONST : 1.0f;
          Cb[(size_t)row * ldc + col] = f2bf(v[r] * sc);
        } else if constexpr (EPI == 4){
          Cb[(size_t)row * ldc + col] = f2bf(v[r] * colscale);
        } else {
          Cf[(size_t)row * 768 + col] = v[r];
        }
      }
    }
  }
}

// ---------------- fused flash attention v4: tiled-coalesced bias regs ----------------
// q pre-scaled by 0.125*log2e; biasT pre-scaled by log2e and pre-tiled (see cvt_biasT).
// q-tile 64 (4 waves x 16 q-rows), KV step 64. grid (32, 12, 2). LDS 40KB -> 4 blocks/CU.
__global__ void __launch_bounds__(256)
attn_kernel(const u16* __restrict__ qkv, const u16* __restrict__ biasT, u16* __restrict__ out){
  __shared__ __align__(16) u16 Ks[2][4096];   // [buf][row64][chunk8*8], chunk c holds global chunk c^(row&7)
  __shared__ __align__(16) u16 Vt[2][4096];   // [buf][dh64][kv chunk swizzled]
  __shared__ __align__(16) u16 Pl[4][1024];   // per-wave P [q16][kv chunk swizzled]

  const int tid = threadIdx.x, w = tid >> 6, lane = tid & 63;
  const int l16 = lane & 15, g = lane >> 4;
  const int qt = blockIdx.x, h = blockIdx.y, b = blockIdx.z;
  const int rowbase = b * 2048, q0 = qt * 64;

  // --- K gld source addresses (pre-swizzled, 16B chunk granular) ---
  const int ci0 = w * 64 + lane, ci1 = ci0 + 256;
  const int r0 = ci0 >> 3, sc0 = ci0 & 7, r1 = ci1 >> 3, sc1 = ci1 & 7;
  const u16* kp0 = qkv + (size_t)(rowbase + r0) * 2304 + 768 + h * 64 + (((sc0 ^ (r0 & 7)) & 7) << 3);
  const u16* kp1 = qkv + (size_t)(rowbase + r1) * 2304 + 768 + h * 64 + (((sc1 ^ (r1 & 7)) & 7) << 3);
  // --- V staging: thread covers dh0,dh0+1 x kv rows vs*8..vs*8+7 ---
  const int dh0 = (tid & 31) * 2, vs = tid >> 5;
  const u16* vp = qkv + (size_t)(rowbase + vs * 8) * 2304 + 1536 + h * 64 + dh0;
  u16x2 vr[8];
  // --- bias: tiled-coalesced; lane reads 2x16B per tile ---
  const u16* bT = biasT + ((size_t)(h * 32 + qt) * 32) * 4096 + tid * 16;
  u16x8 brA, brB, bnA, bnB;

  // --- Q fragments: B-operand, col = q_local = l16 ---
  const u16* qrow = qkv + (size_t)(rowbase + q0 + w * 16 + l16) * 2304 + h * 64;
  s16x8 qf0 = *(const s16x8*)(qrow + 8 * g);
  s16x8 qf1 = *(const s16x8*)(qrow + 32 + 8 * g);

  f32x4 oacc[4] = {};
  float mrun = -3.0e38f, lrun = 0.f;
  const int sw = l16 & 7;

  // prologue: stage tile 0
  {
    char* kb = (char*)Ks[0] + w * 1024;
    gld16(kp0, kb); gld16(kp1, kb + 4096);
#pragma unroll
    for (int i = 0; i < 8; ++i) vr[i] = *(const u16x2*)(vp + (size_t)i * 2304);
    brA = *(const u16x8*)(bT);
    brB = *(const u16x8*)(bT + 8);
    s16x8 vA, vB;
#pragma unroll
    for (int j = 0; j < 8; ++j){ vA[j] = (short)vr[j][0]; vB[j] = (short)vr[j][1]; }
    *(s16x8*)(Vt[0] + dh0 * 64 + ((vs ^ (dh0 & 7)) << 3)) = vA;
    *(s16x8*)(Vt[0] + (dh0 + 1) * 64 + ((vs ^ ((dh0 + 1) & 7)) << 3)) = vB;
  }
  __syncthreads();

  for (int t = 0; t < 32; ++t){
    const int cb = t & 1;
    if (t < 31){  // prefetch tile t+1: K -> Ks[cb^1], V -> regs, bias -> regs
      const size_t koff = (size_t)(t + 1) * 64 * 2304;
      char* kb = (char*)Ks[cb ^ 1] + w * 1024;
      gld16(kp0 + koff, kb); gld16(kp1 + koff, kb + 4096);
      const u16* p = vp + koff;
#pragma unroll
      for (int i = 0; i < 8; ++i) vr[i] = *(const u16x2*)(p + (size_t)i * 2304);
      const u16* bp = bT + (size_t)(t + 1) * 4096;
      bnA = *(const u16x8*)(bp);
      bnB = *(const u16x8*)(bp + 8);
    }

    // S2^T = K * Q2^T (log2-domain scores): lane holds q = l16, kv = 16mi + 4g + r
    f32x4 st[4];
#pragma unroll
    for (int mi = 0; mi < 4; ++mi){
      const int row = l16 + 16 * mi;
      s16x8 kf0 = *(const s16x8*)(Ks[cb] + row * 64 + ((g ^ sw) << 3));
      s16x8 kf1 = *(const s16x8*)(Ks[cb] + row * 64 + (((g + 4) ^ sw) << 3));
      f32x4 z = {};
      z = mfma16(kf0, qf0, z);
      st[mi] = mfma16(kf1, qf1, z);
    }

    // + bias (regs, tiled layout: brc[mi][r] = (mi<2?brA:brB)[(mi&1)*4+r])
    float tmax = -3.0e38f;
#pragma unroll
    for (int mi = 0; mi < 4; ++mi){
#pragma unroll
      for (int r = 0; r < 4; ++r){
        float bval = bf2f(mi < 2 ? brA[(mi & 1) * 4 + r] : brB[(mi & 1) * 4 + r]);
        float v = st[mi][r] + bval;
        st[mi][r] = v;
        tmax = fmaxf(tmax, v);
      }
    }
    tmax = fmaxf(tmax, __shfl_xor(tmax, 16));
    tmax = fmaxf(tmax, __shfl_xor(tmax, 32));
    // defer-max (T13): only rescale when the running max grows by > 8 (log2)
    if (!__all(tmax <= mrun + 8.f)){
      float mnew = fmaxf(mrun, tmax);
      float al = fexp2(mrun - mnew);
      mrun = mnew;
      lrun *= al;
#pragma unroll
      for (int r = 0; r < 4; ++r){
        float aq = __shfl(al, 4 * g + r);
#pragma unroll
        for (int ni = 0; ni < 4; ++ni) oacc[ni][r] *= aq;
      }
    }
    float ssum = 0.f;
#pragma unroll
    for (int mi = 0; mi < 4; ++mi){
      u16x4 pk;
#pragma unroll
      for (int r = 0; r < 4; ++r){
        float pv = fexp2(st[mi][r] - mrun);
        ssum += pv;
        pk[r] = f2bf(pv);
      }
      *(u16x4*)(Pl[w] + l16 * 64 + (((2*mi + (g >> 1)) ^ sw) << 3) + 4 * (g & 1)) = pk;
    }
    ssum += __shfl_xor(ssum, 16);
    ssum += __shfl_xor(ssum, 32);
    lrun += ssum;

    // O += P @ V (reads Vt[cb])
#pragma unroll
    for (int ks2 = 0; ks2 < 2; ++ks2){
      s16x8 pf = *(const s16x8*)(Pl[w] + l16 * 64 + (((4*ks2 + g) ^ sw) << 3));
#pragma unroll
      for (int ni = 0; ni < 4; ++ni){
        const int dh = l16 + 16 * ni;
        s16x8 vf = *(const s16x8*)(Vt[cb] + dh * 64 + (((4*ks2 + g) ^ sw) << 3));
        oacc[ni] = mfma16(pf, vf, oacc[ni]);
      }
    }

    if (t < 31){  // write V(t+1) into Vt[cb^1]; carry bias regs
      s16x8 vA, vB;
#pragma unroll
      for (int j = 0; j < 8; ++j){ vA[j] = (short)vr[j][0]; vB[j] = (short)vr[j][1]; }
      *(s16x8*)(Vt[cb ^ 1] + dh0 * 64 + ((vs ^ (dh0 & 7)) << 3)) = vA;
      *(s16x8*)(Vt[cb ^ 1] + (dh0 + 1) * 64 + ((vs ^ ((dh0 + 1) & 7)) << 3)) = vB;
      brA = bnA; brB = bnB;
    }
    __syncthreads();   // single barrier: K(t+1) in LDS, Vt[cb^1] visible, WAR for next gld
  }

  // finalize: divide by l, write merged-head output; row q_local = 4g+r
#pragma unroll
  for (int r = 0; r < 4; ++r){
    float lq = __shfl(lrun, 4 * g + r);
    float inv = 1.0f / lq;
    const int row = rowbase + q0 + w * 16 + 4 * g + r;
#pragma unroll
    for (int ni = 0; ni < 4; ++ni)
      out[(size_t)row * 768 + h * 64 + l16 + 16 * ni] = f2bf(oacc[ni][r] * inv);
  }
}

// ============================== host ==============================
extern "C" void kernel_launch(void* const* d_in, const int* in_sizes, int n_in,
                              void* d_out, int out_size, void* d_ws, size_t ws_size,
                              hipStream_t stream){
  const float* in_x    = (const float*)d_in[0];
  const float* in_ctx  = (const float*)d_in[1];
  const float* in_bias = (const float*)d_in[2];
  const float* ln1_w = (const float*)d_in[3];
  const float* ln1_b = (const float*)d_in[4];
  const float* w_qkv = (const float*)d_in[5];
  const float* w_so  = (const float*)d_in[6];
  const float* b_so  = (const float*)d_in[7];
  const float* ln2_w = (const float*)d_in[8];
  const float* ln2_b = (const float*)d_in[9];
  const float* w_q   = (const float*)d_in[10];
  const float* w_k   = (const float*)d_in[11];
  const float* w_v   = (const float*)d_in[12];
  const float* w_co  = (const float*)d_in[13];
  const float* b_co  = (const float*)d_in[14];
  const float* ln3_w = (const float*)d_in[15];
  const float* ln3_b = (const float*)d_in[16];
  const float* w_f1  = (const float*)d_in[17];
  const float* b_f1  = (const float*)d_in[18];
  const float* w_f2  = (const float*)d_in[19];
  const float* b_f2  = (const float*)d_in[20];
  const float* lnout_w = (const float*)d_in[21];
  const float* lnout_b = (const float*)d_in[22];

  char* p = (char*)d_ws;
  float* xbuf  = (float*)p;  p += 4096ll * 768 * 4;
  float* pbuf  = (float*)p;  p += 2ll * 4096 * 768 * 4;    // split-K partials
  u16* xn      = (u16*)p;    p += 4096ll * 768 * 2;
  u16* cn      = (u16*)p;    p += 4ll * 4096 * 768 * 2;    // per-layer LN(context, ln2_i)
  u16* qkvb    = (u16*)p;    p += 4096ll * 2304 * 2;
  u16* attO    = (u16*)p;    p += 4096ll * 768 * 2;
  u16* ffh     = (u16*)p;    p += 4096ll * 3072 * 2;
  u16* wqkvT   = (u16*)p;    p += 4ll * 2304 * 768 * 2;
  u16* wsoT    = (u16*)p;    p += 4ll * 768 * 768 * 2;
  u16* wqT     = (u16*)p;    p += 4ll * 768 * 768 * 2;
  u16* wkvT    = (u16*)p;    p += 4ll * 1536 * 768 * 2;    // per layer: [k | v] row-blocks
  u16* wcoT    = (u16*)p;    p += 4ll * 768 * 768 * 2;
  u16* wf1T    = (u16*)p;    p += 4ll * 3072 * 768 * 2;
  u16* wf2T    = (u16*)p;    p += 4ll * 768 * 3072 * 2;
  u16* biasT   = (u16*)p;    p += 12ll * 2048 * 2048 * 2;

  hipMemcpyAsync(xbuf, in_x, 4096ll * 768 * 4, hipMemcpyDeviceToDevice, stream);

  const dim3 tb(32, 8);
  transpose_cvt<<<dim3(72, 24, 4), tb, 0, stream>>>(w_qkv, wqkvT, 768, 2304, 2304ll*768);
  transpose_cvt<<<dim3(24, 24, 4), tb, 0, stream>>>(w_so,  wsoT,  768, 768,  768ll*768);
  transpose_cvt<<<dim3(24, 24, 4), tb, 0, stream>>>(w_q,   wqT,   768, 768,  768ll*768);
  transpose_cvt<<<dim3(24, 24, 4), tb, 0, stream>>>(w_k,   wkvT,             768, 768, 1536ll*768);
  transpose_cvt<<<dim3(24, 24, 4), tb, 0, stream>>>(w_v,   wkvT + 768ll*768, 768, 768, 1536ll*768);
  transpose_cvt<<<dim3(24, 24, 4), tb, 0, stream>>>(w_co,  wcoT,  768, 768,  768ll*768);
  transpose_cvt<<<dim3(96, 24, 4), tb, 0, stream>>>(w_f1,  wf1T,  768, 3072, 3072ll*768);
  transpose_cvt<<<dim3(24, 96, 4), tb, 0, stream>>>(w_f2,  wf2T,  3072, 768, 768ll*3072);
  cvt_biasT<<<dim3(32, 32, 12), 256, 0, stream>>>(in_bias, biasT);
  lnv<<<dim3(1024, 4), 256, 0, stream>>>(in_ctx, ln2_w, ln2_b, cn);       // 4 layers of cn
  lnv<<<dim3(1024, 1), 256, 0, stream>>>(xbuf, ln1_w, ln1_b, xn);         // ln1[0]

  const dim3 ag(32, 12, 2);
  for (int i = 0; i < 4; ++i){
    // self-attention block
    gemm_bf16<64,128,3><<<dim3(64, 18), 256, 0, stream>>>(xn, 768, wqkvT + (size_t)i*2304*768, 768, 24,
                                                          qkvb, nullptr, 2304, nullptr, nullptr, nullptr);
    attn_kernel<<<ag, 256, 0, stream>>>(qkvb, biasT, attO);
    gemm_bf16<128,64,5><<<dim3(32, 12, 2), 256, 0, stream>>>(attO, 768, wsoT + (size_t)i*768*768, 768, 12,
                                                             nullptr, pbuf, 768, nullptr, nullptr, nullptr);
    red_ln<u16><<<1024, 256, 0, stream>>>(pbuf, b_so + i*768, xbuf, xn, ln2_w + i*768, ln2_b + i*768);
    // cross-attention block (merged q/k/v projection)
    gemm_bf16<64,128,4><<<dim3(64, 6, 3), 256, 0, stream>>>(xn, 768, wqT + (size_t)i*768*768, 768, 24,
                                                            qkvb, nullptr, 2304, nullptr,
                                                            cn + (size_t)i*4096*768, wkvT + (size_t)i*1536*768);
    attn_kernel<<<ag, 256, 0, stream>>>(qkvb, biasT, attO);
    gemm_bf16<128,64,5><<<dim3(32, 12, 2), 256, 0, stream>>>(attO, 768, wcoT + (size_t)i*768*768, 768, 12,
                                                             nullptr, pbuf, 768, nullptr, nullptr, nullptr);
    red_ln<u16><<<1024, 256, 0, stream>>>(pbuf, b_co + i*768, xbuf, xn, ln3_w + i*768, ln3_b + i*768);
    // FFN block
    gemm_bf16<64,128,2><<<dim3(64, 24), 256, 0, stream>>>(xn, 768, wf1T + (size_t)i*3072*768, 768, 24,
                                                          ffh, nullptr, 3072, b_f1 + i*3072, nullptr, nullptr);
    gemm_bf16<128,64,5><<<dim3(32, 12, 2), 256, 0, stream>>>(ffh, 3072, wf2T + (size_t)i*768*3072, 3072, 48,
                                                             nullptr, pbuf, 768, nullptr, nullptr, nullptr);
    if (i < 3)
      red_ln<u16><<<1024, 256, 0, stream>>>(pbuf, b_f2 + i*768, xbuf, xn, ln1_w + (i+1)*768, ln1_b + (i+1)*768);
    else
      red_ln<float><<<1024, 256, 0, stream>>>(pbuf, b_f2 + i*768, xbuf, (float*)d_out, lnout_w, lnout_b);
  }
}

// Round 8
// 1354.689 us; speedup vs baseline: 1.6050x; 1.0474x over previous
//
#include <hip/hip_runtime.h>
#include <cstdint>
#include <cstddef>

#define DEV static __device__ __forceinline__

typedef float  f32x4 __attribute__((ext_vector_type(4)));
typedef float  f32x2 __attribute__((ext_vector_type(2)));
typedef short  s16x8 __attribute__((ext_vector_type(8)));
typedef unsigned short u16;
typedef unsigned int   u32;
typedef unsigned int   u32x4 __attribute__((ext_vector_type(4)));
typedef unsigned short u16x2 __attribute__((ext_vector_type(2)));
typedef unsigned short u16x4 __attribute__((ext_vector_type(4)));
typedef __bf16 bf16x8 __attribute__((ext_vector_type(8)));

#define LOG2E 1.4426950408889634f
#define QSCALE_CONST 0.18033688011112042f   /* 0.125 * log2(e) */
#define BSCALE 256.0f                       /* bias fp8 pre-scale */
#define BINV   0.00390625f                  /* 1/256 */

DEV u16 f2bf(float f){ return __builtin_bit_cast(u16, (__bf16)f); }

DEV float fexp2(float x){
#if __has_builtin(__builtin_amdgcn_exp2f)
  return __builtin_amdgcn_exp2f(x);
#else
  return exp2f(x);
#endif
}

DEV f32x4 mfma16(s16x8 a, s16x8 b, f32x4 c){
  return __builtin_amdgcn_mfma_f32_16x16x32_bf16(
      __builtin_bit_cast(bf16x8, a), __builtin_bit_cast(bf16x8, b), c, 0, 0, 0);
}

// async global->LDS, 16B per lane
DEV void gld16(const void* g, void* l){
  __builtin_amdgcn_global_load_lds(
      (const __attribute__((address_space(1))) void*)(uintptr_t)g,
      (__attribute__((address_space(3))) void*)(unsigned)(uintptr_t)l,
      16, 0, 0);
}

// ---- fp8 e4m3 (OCP) pack/unpack; HI must be compile-time for the builtin ----
#if __has_builtin(__builtin_amdgcn_cvt_pk_fp8_f32) && __has_builtin(__builtin_amdgcn_cvt_pk_f32_fp8)
DEV u32 pk4_fp8(f32x4 v){
  int r = __builtin_amdgcn_cvt_pk_fp8_f32(v[0], v[1], 0, false);
  r     = __builtin_amdgcn_cvt_pk_fp8_f32(v[2], v[3], r, true);
  return (u32)r;
}
template<bool HI>
DEV f32x2 upk_fp8(u32 w){
  return __builtin_amdgcn_cvt_pk_f32_fp8((int)w, HI);
}
#else
DEV unsigned enc1(float x){
  union{float f; unsigned u;} c; c.f = x;
  unsigned s = (c.u >> 24) & 0x80;
  int e = (int)((c.u >> 23) & 0xff) - 127;
  unsigned m = c.u & 0x7fffff;
  if (e >= -6){
    unsigned mant = m >> 20, rem = m & 0xfffff;
    if (rem > 0x80000 || (rem == 0x80000 && (mant & 1))) mant++;
    unsigned eb = (unsigned)(e + 7);
    if (mant == 8){ mant = 0; eb++; }
    if (eb >= 16){ eb = 15; mant = 6; }
    return s | (eb << 3) | mant;
  }
  if (e < -10) return s;
  int sh = -6 - e;
  unsigned full = (1u << 23) | m;
  unsigned mant = full >> (20 + sh);
  unsigned rem  = full & ((1u << (20 + sh)) - 1);
  unsigned half = 1u << (19 + sh);
  if (rem > half || (rem == half && (mant & 1))) mant++;
  if (mant == 8) return s | (1u << 3);
  return s | mant;
}
DEV u32 pk4_fp8(f32x4 v){
  return enc1(v[0]) | (enc1(v[1]) << 8) | (enc1(v[2]) << 16) | (enc1(v[3]) << 24);
}
DEV float dec1(unsigned b){
  int s = (b >> 7) & 1, e = (b >> 3) & 15; float m = (float)(b & 7) * 0.125f;
  float v = e ? ldexpf(1.0f + m, e - 7) : ldexpf(m, -6);
  return s ? -v : v;
}
template<bool HI>
DEV f32x2 upk_fp8(u32 w){
  unsigned lo = HI ? ((w >> 16) & 0xff) : (w & 0xff);
  unsigned h2 = HI ? ((w >> 24) & 0xff) : ((w >> 8) & 0xff);
  f32x2 r; r[0] = dec1(lo); r[1] = dec1(h2); return r;
}
#endif

// ---------------- transpose + fp32->bf16 convert: src[K][N] -> dst[N][K] ----------------
__global__ void __launch_bounds__(256)
transpose_cvt(const float* __restrict__ src, u16* __restrict__ dst, int K, int N,
              size_t dzstride){
  int z = blockIdx.z;
  src += (size_t)z * K * N;
  dst += (size_t)z * dzstride;
  __shared__ float t[32][33];
  int n0 = blockIdx.x * 32, k0 = blockIdx.y * 32;
#pragma unroll
  for (int i = 0; i < 4; ++i)
    t[threadIdx.y + 8*i][threadIdx.x] = src[(size_t)(k0 + threadIdx.y + 8*i) * N + n0 + threadIdx.x];
  __syncthreads();
#pragma unroll
  for (int i = 0; i < 4; ++i)
    dst[(size_t)(n0 + threadIdx.y + 8*i) * K + k0 + threadIdx.x] = f2bf(t[threadIdx.x][threadIdx.y + 8*i]);
}

// ---------------- bias -> tiled fp8 (log2e*256-scaled) ----------------
// biasT[((h*32+qt)*32+kvt)*4096 + tid*16 + mi*4 + r] (bytes)
//   = fp8( bias[h][qt*64 + (tid>>6)*16 + (tid&15)][kvt*64 + ((tid>>4)&3)*4 + mi*16 + r] * LOG2E*256 )
__global__ void __launch_bounds__(256)
cvt_biasT(const float* __restrict__ in, unsigned char* __restrict__ out){
  const int kvt = blockIdx.x, qt = blockIdx.y, h = blockIdx.z, tid = threadIdx.x;
  const int q  = qt * 64 + ((tid >> 6) << 4) + (tid & 15);
  const int c0 = kvt * 64 + ((tid >> 4) & 3) * 4;
  const float* src = in + ((size_t)h * 2048 + q) * 2048;
  u32x4 wv;
#pragma unroll
  for (int mi = 0; mi < 4; ++mi){
    f32x4 v = *(const f32x4*)(src + c0 + mi * 16);
#pragma unroll
    for (int r = 0; r < 4; ++r) v[r] = fminf(fmaxf(v[r] * (LOG2E * BSCALE), -448.f), 448.f);
    wv[mi] = pk4_fp8(v);
  }
  *(u32x4*)(out + ((size_t)(h * 32 + qt) * 32 + kvt) * 4096 + tid * 16) = wv;
}

// ---------------- vectorized LayerNorm, one wave per row ----------------
__global__ void __launch_bounds__(256)
lnv(const float* __restrict__ x, const float* __restrict__ w, const float* __restrict__ b,
    u16* __restrict__ out){
  const int wv = threadIdx.x >> 6, lane = threadIdx.x & 63;
  const float* wz = w + blockIdx.y * 768;
  const float* bz = b + blockIdx.y * 768;
  out += (size_t)blockIdx.y * 4096 * 768;
  const int row = blockIdx.x * 4 + wv;
  const float* xr = x + (size_t)row * 768;
  f32x4 t[3]; float s = 0.f, s2 = 0.f;
#pragma unroll
  for (int c = 0; c < 3; ++c){
    t[c] = *(const f32x4*)(xr + c * 256 + lane * 4);
#pragma unroll
    for (int j = 0; j < 4; ++j){ s += t[c][j]; s2 += t[c][j] * t[c][j]; }
  }
#pragma unroll
  for (int off = 1; off < 64; off <<= 1){ s += __shfl_xor(s, off); s2 += __shfl_xor(s2, off); }
  float m = s * (1.f/768.f);
  float rstd = rsqrtf(s2 * (1.f/768.f) - m * m + 1e-5f);
#pragma unroll
  for (int c = 0; c < 3; ++c){
    const int col = c * 256 + lane * 4;
    f32x4 wv4 = *(const f32x4*)(wz + col);
    f32x4 bv4 = *(const f32x4*)(bz + col);
    u16x4 o;
#pragma unroll
    for (int j = 0; j < 4; ++j) o[j] = f2bf((t[c][j] - m) * rstd * wv4[j] + bv4[j]);
    *(u16x4*)(out + (size_t)row * 768 + col) = o;
  }
}

// ---------------- fused splitK(4)-reduce + bias + residual + LayerNorm ----------------
template<typename OUT>
__global__ void __launch_bounds__(256)
red_ln(const float* __restrict__ p, const float* __restrict__ biasrow,
       float* __restrict__ xbuf, OUT* __restrict__ out,
       const float* __restrict__ lw, const float* __restrict__ lb){
  const int wv = threadIdx.x >> 6, lane = threadIdx.x & 63;
  const int row = blockIdx.x * 4 + wv;
  const size_t S = 4096ll * 768;
  const float* p0 = p + (size_t)row * 768;
  float* xr = xbuf + (size_t)row * 768;
  f32x4 t[3]; float s = 0.f, s2 = 0.f;
#pragma unroll
  for (int c = 0; c < 3; ++c){
    const int col = c * 256 + lane * 4;
    f32x4 v = *(const f32x4*)(p0 + col);
    v += *(const f32x4*)(p0 + S + col);
    v += *(const f32x4*)(p0 + 2*S + col);
    v += *(const f32x4*)(p0 + 3*S + col);
    v += *(const f32x4*)(biasrow + col);
    v += *(const f32x4*)(xr + col);
    *(f32x4*)(xr + col) = v;
    t[c] = v;
#pragma unroll
    for (int j = 0; j < 4; ++j){ s += v[j]; s2 += v[j] * v[j]; }
  }
#pragma unroll
  for (int off = 1; off < 64; off <<= 1){ s += __shfl_xor(s, off); s2 += __shfl_xor(s2, off); }
  float m = s * (1.f/768.f);
  float rstd = rsqrtf(s2 * (1.f/768.f) - m * m + 1e-5f);
#pragma unroll
  for (int c = 0; c < 3; ++c){
    const int col = c * 256 + lane * 4;
    f32x4 wv4 = *(const f32x4*)(lw + col);
    f32x4 bv4 = *(const f32x4*)(lb + col);
    if constexpr (sizeof(OUT) == 2){
      u16x4 o;
#pragma unroll
      for (int j = 0; j < 4; ++j) o[j] = f2bf((t[c][j] - m) * rstd * wv4[j] + bv4[j]);
      *(u16x4*)((u16*)out + (size_t)row * 768 + col) = o;
    } else {
      f32x4 o;
#pragma unroll
      for (int j = 0; j < 4; ++j) o[j] = (t[c][j] - m) * rstd * wv4[j] + bv4[j];
      *(f32x4*)((float*)out + (size_t)row * 768 + col) = o;
    }
  }
}

// ---------------- bf16 GEMM, 128x128, double-buffered (m97 structure) ----------------
// EPI 2: bf16 gelu(acc+bias[col]); EPI 3: bf16, cols<768 * QSCALE;
// EPI 4: merged cross q/k/v (z=0: A scaled; z=1/2: A2 @ Bt2[+(z-1)*768*768]; out += z*768);
// EPI 5: split-K fp32 partials (z in 0..3 selects K-quarter; Cf += z*4096*768).
template<int EPI>
__global__ void __launch_bounds__(256)
gemm_bf16(const u16* __restrict__ A, int lda, const u16* __restrict__ Bt, int ldb,
          int nk, u16* __restrict__ Cb, float* __restrict__ Cf, int ldc,
          const float* __restrict__ bias,
          const u16* __restrict__ A2, const u16* __restrict__ Bt2){
  __shared__ u16 As[2][128 * 32];
  __shared__ u16 Bs[2][128 * 32];
  float colscale = 1.0f;
  if constexpr (EPI == 4){
    const int z = blockIdx.z;
    if (z == 0){ colscale = QSCALE_CONST; }
    else { A = A2; Bt = Bt2 + (size_t)(z - 1) * 768 * 768; }
    Cb += z * 768;
  }
  if constexpr (EPI == 5){
    const int z = blockIdx.z;
    A  += (size_t)z * nk * 32;
    Bt += (size_t)z * nk * 32;
    Cf += (size_t)z * 4096 * 768;
  }
  const int tid = threadIdx.x, w = tid >> 6, lane = tid & 63;
  const int l16 = lane & 15, g = lane >> 4;
  const int m0 = blockIdx.x * 128, n0 = blockIdx.y * 128;
  const int wm = (w >> 1) * 64, wn = (w & 1) * 64;
  f32x4 acc[4][4] = {};

  // staging: chunk tid covers row tid>>2, short-col (tid&3)*8; second half rows +64
  const u16* a0 = A  + (size_t)(m0 + (tid >> 2)) * lda + (tid & 3) * 8;
  const u16* a1 = A  + (size_t)(m0 + (tid >> 2) + 64) * lda + (tid & 3) * 8;
  const u16* b0 = Bt + (size_t)(n0 + (tid >> 2)) * ldb + (tid & 3) * 8;
  const u16* b1 = Bt + (size_t)(n0 + (tid >> 2) + 64) * ldb + (tid & 3) * 8;

  {
    char* ab = (char*)As[0]; char* bb = (char*)Bs[0];
    gld16(a0, ab + w * 1024); gld16(a1, ab + 4096 + w * 1024);
    gld16(b0, bb + w * 1024); gld16(b1, bb + 4096 + w * 1024);
  }
  __syncthreads();

  int cb = 0;
  for (int kt = 0; kt < nk; ++kt){
    if (kt + 1 < nk){
      const int k1 = (kt + 1) * 32;
      char* ab = (char*)As[cb ^ 1]; char* bb = (char*)Bs[cb ^ 1];
      gld16(a0 + k1, ab + w * 1024); gld16(a1 + k1, ab + 4096 + w * 1024);
      gld16(b0 + k1, bb + w * 1024); gld16(b1 + k1, bb + 4096 + w * 1024);
    }
    const u16* Ab = As[cb]; const u16* Bb = Bs[cb];
    s16x8 af[4], bfv[4];
#pragma unroll
    for (int mi = 0; mi < 4; ++mi)
      af[mi] = *(const s16x8*)(Ab + (wm + mi*16 + l16) * 32 + 8 * g);
#pragma unroll
    for (int ni = 0; ni < 4; ++ni)
      bfv[ni] = *(const s16x8*)(Bb + (wn + ni*16 + l16) * 32 + 8 * g);
#pragma unroll
    for (int mi = 0; mi < 4; ++mi)
#pragma unroll
      for (int ni = 0; ni < 4; ++ni)
        acc[mi][ni] = mfma16(af[mi], bfv[ni], acc[mi][ni]);
    __syncthreads();
    cb ^= 1;
  }

  // epilogue: C/D layout col = lane&15, row = 4*(lane>>4)+r
#pragma unroll
  for (int mi = 0; mi < 4; ++mi){
    const int rg = m0 + wm + mi*16 + 4*g;
#pragma unroll
    for (int ni = 0; ni < 4; ++ni){
      const int col = n0 + wn + ni*16 + l16;
      f32x4 v = acc[mi][ni];
#pragma unroll
      for (int r = 0; r < 4; ++r){
        const int row = rg + r;
        if constexpr (EPI == 2){
          float t = v[r] + bias[col];
          float ge = 0.5f * t * (1.0f + erff(t * 0.7071067811865476f));
          Cb[(size_t)row * ldc + col] = f2bf(ge);
        } else if constexpr (EPI == 3){
          float sc = (col < 768) ? QSCALE_CONST : 1.0f;
          Cb[(size_t)row * ldc + col] = f2bf(v[r] * sc);
        } else if constexpr (EPI == 4){
          Cb[(size_t)row * ldc + col] = f2bf(v[r] * colscale);
        } else {
          Cf[(size_t)row * 768 + col] = v[r];
        }
      }
    }
  }
}

// ---------------- fused flash attention v5: fp8 bias regs, setprio ----------------
// q pre-scaled by 0.125*log2e; biasT fp8 pre-scaled by log2e*256 and pre-tiled.
// q-tile 64 (4 waves x 16 q-rows), KV step 64. grid (32, 12, 2). LDS 40KB.
__global__ void __launch_bounds__(256)
attn_kernel(const u16* __restrict__ qkv, const unsigned char* __restrict__ biasT,
            u16* __restrict__ out){
  __shared__ __align__(16) u16 Ks[2][4096];   // [buf][row64][chunk8*8], chunk c holds global chunk c^(row&7)
  __shared__ __align__(16) u16 Vt[2][4096];   // [buf][dh64][kv chunk swizzled]
  __shared__ __align__(16) u16 Pl[4][1024];   // per-wave P [q16][kv chunk swizzled]

  const int tid = threadIdx.x, w = tid >> 6, lane = tid & 63;
  const int l16 = lane & 15, g = lane >> 4;
  const int qt = blockIdx.x, h = blockIdx.y, b = blockIdx.z;
  const int rowbase = b * 2048, q0 = qt * 64;

  // K gld source addresses (pre-swizzled, 16B chunk granular)
  const int ci0 = w * 64 + lane, ci1 = ci0 + 256;
  const int r0 = ci0 >> 3, sc0 = ci0 & 7, r1 = ci1 >> 3, sc1 = ci1 & 7;
  const u16* kp0 = qkv + (size_t)(rowbase + r0) * 2304 + 768 + h * 64 + (((sc0 ^ (r0 & 7)) & 7) << 3);
  const u16* kp1 = qkv + (size_t)(rowbase + r1) * 2304 + 768 + h * 64 + (((sc1 ^ (r1 & 7)) & 7) << 3);
  // V staging: thread covers dh0,dh0+1 x kv rows vs*8..vs*8+7
  const int dh0 = (tid & 31) * 2, vs = tid >> 5;
  const u16* vp = qkv + (size_t)(rowbase + vs * 8) * 2304 + 1536 + h * 64 + dh0;
  u16x2 vr[8];
  // bias: tiled fp8; lane reads one 16B dwordx4 per tile
  const unsigned char* bT = biasT + ((size_t)(h * 32 + qt) * 32) * 4096 + tid * 16;
  u32x4 brW, bnW;

  // Q fragments: B-operand, col = q_local = l16
  const u16* qrow = qkv + (size_t)(rowbase + q0 + w * 16 + l16) * 2304 + h * 64;
  s16x8 qf0 = *(const s16x8*)(qrow + 8 * g);
  s16x8 qf1 = *(const s16x8*)(qrow + 32 + 8 * g);

  f32x4 oacc[4] = {};
  float mrun = -3.0e38f, lrun = 0.f;
  const int sw = l16 & 7;

  // prologue: stage tile 0
  {
    char* kb = (char*)Ks[0] + w * 1024;
    gld16(kp0, kb); gld16(kp1, kb + 4096);
#pragma unroll
    for (int i = 0; i < 8; ++i) vr[i] = *(const u16x2*)(vp + (size_t)i * 2304);
    brW = *(const u32x4*)(bT);
    s16x8 vA, vB;
#pragma unroll
    for (int j = 0; j < 8; ++j){ vA[j] = (short)vr[j][0]; vB[j] = (short)vr[j][1]; }
    *(s16x8*)(Vt[0] + dh0 * 64 + ((vs ^ (dh0 & 7)) << 3)) = vA;
    *(s16x8*)(Vt[0] + (dh0 + 1) * 64 + ((vs ^ ((dh0 + 1) & 7)) << 3)) = vB;
  }
  __syncthreads();

  for (int t = 0; t < 32; ++t){
    const int cb = t & 1;
    if (t < 31){  // prefetch tile t+1
      const size_t koff = (size_t)(t + 1) * 64 * 2304;
      char* kb = (char*)Ks[cb ^ 1] + w * 1024;
      gld16(kp0 + koff, kb); gld16(kp1 + koff, kb + 4096);
      const u16* p = vp + koff;
#pragma unroll
      for (int i = 0; i < 8; ++i) vr[i] = *(const u16x2*)(p + (size_t)i * 2304);
      bnW = *(const u32x4*)(bT + (size_t)(t + 1) * 4096);
    }

    // S2^T = K * Q2^T: lane holds q = l16, kv = 16mi + 4g + r
    f32x4 st[4];
    __builtin_amdgcn_s_setprio(1);
#pragma unroll
    for (int mi = 0; mi < 4; ++mi){
      const int row = l16 + 16 * mi;
      s16x8 kf0 = *(const s16x8*)(Ks[cb] + row * 64 + ((g ^ sw) << 3));
      s16x8 kf1 = *(const s16x8*)(Ks[cb] + row * 64 + (((g + 4) ^ sw) << 3));
      f32x4 z = {};
      z = mfma16(kf0, qf0, z);
      st[mi] = mfma16(kf1, qf1, z);
    }
    __builtin_amdgcn_s_setprio(0);

    // + fp8 bias (regs) + online softmax
    float tmax = -3.0e38f;
#pragma unroll
    for (int mi = 0; mi < 4; ++mi){
      f32x2 lo = upk_fp8<false>(brW[mi]);
      f32x2 hi = upk_fp8<true>(brW[mi]);
      st[mi][0] = fmaf(lo[0], BINV, st[mi][0]);
      st[mi][1] = fmaf(lo[1], BINV, st[mi][1]);
      st[mi][2] = fmaf(hi[0], BINV, st[mi][2]);
      st[mi][3] = fmaf(hi[1], BINV, st[mi][3]);
#pragma unroll
      for (int r = 0; r < 4; ++r) tmax = fmaxf(tmax, st[mi][r]);
    }
    tmax = fmaxf(tmax, __shfl_xor(tmax, 16));
    tmax = fmaxf(tmax, __shfl_xor(tmax, 32));
    // defer-max (T13)
    if (!__all(tmax <= mrun + 8.f)){
      float mnew = fmaxf(mrun, tmax);
      float al = fexp2(mrun - mnew);
      mrun = mnew;
      lrun *= al;
#pragma unroll
      for (int r = 0; r < 4; ++r){
        float aq = __shfl(al, 4 * g + r);
#pragma unroll
        for (int ni = 0; ni < 4; ++ni) oacc[ni][r] *= aq;
      }
    }
    float ssum = 0.f;
#pragma unroll
    for (int mi = 0; mi < 4; ++mi){
      u16x4 pk;
#pragma unroll
      for (int r = 0; r < 4; ++r){
        float pv = fexp2(st[mi][r] - mrun);
        ssum += pv;
        pk[r] = f2bf(pv);
      }
      *(u16x4*)(Pl[w] + l16 * 64 + (((2*mi + (g >> 1)) ^ sw) << 3) + 4 * (g & 1)) = pk;
    }
    ssum += __shfl_xor(ssum, 16);
    ssum += __shfl_xor(ssum, 32);
    lrun += ssum;

    // O += P @ V (reads Vt[cb])
    __builtin_amdgcn_s_setprio(1);
#pragma unroll
    for (int ks2 = 0; ks2 < 2; ++ks2){
      s16x8 pf = *(const s16x8*)(Pl[w] + l16 * 64 + (((4*ks2 + g) ^ sw) << 3));
#pragma unroll
      for (int ni = 0; ni < 4; ++ni){
        const int dh = l16 + 16 * ni;
        s16x8 vf = *(const s16x8*)(Vt[cb] + dh * 64 + (((4*ks2 + g) ^ sw) << 3));
        oacc[ni] = mfma16(pf, vf, oacc[ni]);
      }
    }
    __builtin_amdgcn_s_setprio(0);

    if (t < 31){  // write V(t+1) into Vt[cb^1]; carry bias regs
      s16x8 vA, vB;
#pragma unroll
      for (int j = 0; j < 8; ++j){ vA[j] = (short)vr[j][0]; vB[j] = (short)vr[j][1]; }
      *(s16x8*)(Vt[cb ^ 1] + dh0 * 64 + ((vs ^ (dh0 & 7)) << 3)) = vA;
      *(s16x8*)(Vt[cb ^ 1] + (dh0 + 1) * 64 + ((vs ^ ((dh0 + 1) & 7)) << 3)) = vB;
      brW = bnW;
    }
    __syncthreads();
  }

  // finalize
#pragma unroll
  for (int r = 0; r < 4; ++r){
    float lq = __shfl(lrun, 4 * g + r);
    float inv = 1.0f / lq;
    const int row = rowbase + q0 + w * 16 + 4 * g + r;
#pragma unroll
    for (int ni = 0; ni < 4; ++ni)
      out[(size_t)row * 768 + h * 64 + l16 + 16 * ni] = f2bf(oacc[ni][r] * inv);
  }
}

// ============================== host ==============================
extern "C" void kernel_launch(void* const* d_in, const int* in_sizes, int n_in,
                              void* d_out, int out_size, void* d_ws, size_t ws_size,
                              hipStream_t stream){
  const float* in_x    = (const float*)d_in[0];
  const float* in_ctx  = (const float*)d_in[1];
  const float* in_bias = (const float*)d_in[2];
  const float* ln1_w = (const float*)d_in[3];
  const float* ln1_b = (const float*)d_in[4];
  const float* w_qkv = (const float*)d_in[5];
  const float* w_so  = (const float*)d_in[6];
  const float* b_so  = (const float*)d_in[7];
  const float* ln2_w = (const float*)d_in[8];
  const float* ln2_b = (const float*)d_in[9];
  const float* w_q   = (const float*)d_in[10];
  const float* w_k   = (const float*)d_in[11];
  const float* w_v   = (const float*)d_in[12];
  const float* w_co  = (const float*)d_in[13];
  const float* b_co  = (const float*)d_in[14];
  const float* ln3_w = (const float*)d_in[15];
  const float* ln3_b = (const float*)d_in[16];
  const float* w_f1  = (const float*)d_in[17];
  const float* b_f1  = (const float*)d_in[18];
  const float* w_f2  = (const float*)d_in[19];
  const float* b_f2  = (const float*)d_in[20];
  const float* lnout_w = (const float*)d_in[21];
  const float* lnout_b = (const float*)d_in[22];

  char* p = (char*)d_ws;
  float* xbuf  = (float*)p;  p += 4096ll * 768 * 4;
  float* pbuf  = (float*)p;  p += 4ll * 4096 * 768 * 4;    // split-K partials (4)
  u16* xn      = (u16*)p;    p += 4096ll * 768 * 2;
  u16* cn      = (u16*)p;    p += 4ll * 4096 * 768 * 2;    // per-layer LN(context)
  u16* qkvb    = (u16*)p;    p += 4096ll * 2304 * 2;
  u16* attO    = (u16*)p;    p += 4096ll * 768 * 2;
  u16* ffh     = (u16*)p;    p += 4096ll * 3072 * 2;
  u16* wqkvT   = (u16*)p;    p += 4ll * 2304 * 768 * 2;
  u16* wsoT    = (u16*)p;    p += 4ll * 768 * 768 * 2;
  u16* wqT     = (u16*)p;    p += 4ll * 768 * 768 * 2;
  u16* wkvT    = (u16*)p;    p += 4ll * 1536 * 768 * 2;
  u16* wcoT    = (u16*)p;    p += 4ll * 768 * 768 * 2;
  u16* wf1T    = (u16*)p;    p += 4ll * 3072 * 768 * 2;
  u16* wf2T    = (u16*)p;    p += 4ll * 768 * 3072 * 2;
  unsigned char* biasT = (unsigned char*)p; p += 12ll * 2048 * 2048;

  hipMemcpyAsync(xbuf, in_x, 4096ll * 768 * 4, hipMemcpyDeviceToDevice, stream);

  const dim3 tb(32, 8);
  transpose_cvt<<<dim3(72, 24, 4), tb, 0, stream>>>(w_qkv, wqkvT, 768, 2304, 2304ll*768);
  transpose_cvt<<<dim3(24, 24, 4), tb, 0, stream>>>(w_so,  wsoT,  768, 768,  768ll*768);
  transpose_cvt<<<dim3(24, 24, 4), tb, 0, stream>>>(w_q,   wqT,   768, 768,  768ll*768);
  transpose_cvt<<<dim3(24, 24, 4), tb, 0, stream>>>(w_k,   wkvT,             768, 768, 1536ll*768);
  transpose_cvt<<<dim3(24, 24, 4), tb, 0, stream>>>(w_v,   wkvT + 768ll*768, 768, 768, 1536ll*768);
  transpose_cvt<<<dim3(24, 24, 4), tb, 0, stream>>>(w_co,  wcoT,  768, 768,  768ll*768);
  transpose_cvt<<<dim3(96, 24, 4), tb, 0, stream>>>(w_f1,  wf1T,  768, 3072, 3072ll*768);
  transpose_cvt<<<dim3(24, 96, 4), tb, 0, stream>>>(w_f2,  wf2T,  3072, 768, 768ll*3072);
  cvt_biasT<<<dim3(32, 32, 12), 256, 0, stream>>>(in_bias, biasT);
  lnv<<<dim3(1024, 4), 256, 0, stream>>>(in_ctx, ln2_w, ln2_b, cn);
  lnv<<<dim3(1024, 1), 256, 0, stream>>>(xbuf, ln1_w, ln1_b, xn);

  const dim3 ag(32, 12, 2);
  for (int i = 0; i < 4; ++i){
    // self-attention block
    gemm_bf16<3><<<dim3(32, 18), 256, 0, stream>>>(xn, 768, wqkvT + (size_t)i*2304*768, 768, 24,
                                                   qkvb, nullptr, 2304, nullptr, nullptr, nullptr);
    attn_kernel<<<ag, 256, 0, stream>>>(qkvb, biasT, attO);
    gemm_bf16<5><<<dim3(32, 6, 4), 256, 0, stream>>>(attO, 768, wsoT + (size_t)i*768*768, 768, 6,
                                                     nullptr, pbuf, 768, nullptr, nullptr, nullptr);
    red_ln<u16><<<1024, 256, 0, stream>>>(pbuf, b_so + i*768, xbuf, xn, ln2_w + i*768, ln2_b + i*768);
    // cross-attention block (merged q/k/v projection)
    gemm_bf16<4><<<dim3(32, 6, 3), 256, 0, stream>>>(xn, 768, wqT + (size_t)i*768*768, 768, 24,
                                                     qkvb, nullptr, 2304, nullptr,
                                                     cn + (size_t)i*4096*768, wkvT + (size_t)i*1536*768);
    attn_kernel<<<ag, 256, 0, stream>>>(qkvb, biasT, attO);
    gemm_bf16<5><<<dim3(32, 6, 4), 256, 0, stream>>>(attO, 768, wcoT + (size_t)i*768*768, 768, 6,
                                                     nullptr, pbuf, 768, nullptr, nullptr, nullptr);
    red_ln<u16><<<1024, 256, 0, stream>>>(pbuf, b_co + i*768, xbuf, xn, ln3_w + i*768, ln3_b + i*768);
    // FFN block
    gemm_bf16<2><<<dim3(32, 24), 256, 0, stream>>>(xn, 768, wf1T + (size_t)i*3072*768, 768, 24,
                                                   ffh, nullptr, 3072, b_f1 + i*3072, nullptr, nullptr);
    gemm_bf16<5><<<dim3(32, 6, 4), 256, 0, stream>>>(ffh, 3072, wf2T + (size_t)i*768*3072, 3072, 24,
                                                     nullptr, pbuf, 768, nullptr, nullptr, nullptr);
    if (i < 3)
      red_ln<u16><<<1024, 256, 0, stream>>>(pbuf, b_f2 + i*768, xbuf, xn, ln1_w + (i+1)*768, ln1_b + (i+1)*768);
    else
      red_ln<float><<<1024, 256, 0, stream>>>(pbuf, b_f2 + i*768, xbuf, (float*)d_out, lnout_w, lnout_b);
  }
}

// Round 9
// 1312.822 us; speedup vs baseline: 1.6562x; 1.0319x over previous
//
#include <hip/hip_runtime.h>
#include <cstdint>
#include <cstddef>

#define DEV static __device__ __forceinline__

typedef float  f32x4 __attribute__((ext_vector_type(4)));
typedef float  f32x2 __attribute__((ext_vector_type(2)));
typedef short  s16x8 __attribute__((ext_vector_type(8)));
typedef unsigned short u16;
typedef unsigned int   u32;
typedef unsigned int   u32x4 __attribute__((ext_vector_type(4)));
typedef unsigned short u16x2 __attribute__((ext_vector_type(2)));
typedef unsigned short u16x4 __attribute__((ext_vector_type(4)));
typedef __bf16 bf16x8 __attribute__((ext_vector_type(8)));

#define LOG2E 1.4426950408889634f
#define QSCALE_CONST 0.18033688011112042f   /* 0.125 * log2(e) */
#define BSCALE 256.0f                       /* bias fp8 pre-scale */
#define BINV   0.00390625f                  /* 1/256 */

DEV u16 f2bf(float f){ return __builtin_bit_cast(u16, (__bf16)f); }
DEV float bf2f(u16 v){ union { unsigned u; float f; } x; x.u = ((unsigned)v) << 16; return x.f; }

DEV float fexp2(float x){
#if __has_builtin(__builtin_amdgcn_exp2f)
  return __builtin_amdgcn_exp2f(x);
#else
  return exp2f(x);
#endif
}

DEV f32x4 mfma16(s16x8 a, s16x8 b, f32x4 c){
  return __builtin_amdgcn_mfma_f32_16x16x32_bf16(
      __builtin_bit_cast(bf16x8, a), __builtin_bit_cast(bf16x8, b), c, 0, 0, 0);
}

// async global->LDS, 16B per lane
DEV void gld16(const void* g, void* l){
  __builtin_amdgcn_global_load_lds(
      (const __attribute__((address_space(1))) void*)(uintptr_t)g,
      (__attribute__((address_space(3))) void*)(unsigned)(uintptr_t)l,
      16, 0, 0);
}

// ---- fp8 e4m3 (OCP) pack/unpack; HI is compile-time for the builtin ----
#if __has_builtin(__builtin_amdgcn_cvt_pk_fp8_f32) && __has_builtin(__builtin_amdgcn_cvt_pk_f32_fp8)
DEV u32 pk4_fp8(f32x4 v){
  int r = __builtin_amdgcn_cvt_pk_fp8_f32(v[0], v[1], 0, false);
  r     = __builtin_amdgcn_cvt_pk_fp8_f32(v[2], v[3], r, true);
  return (u32)r;
}
template<bool HI>
DEV f32x2 upk_fp8(u32 w){
  return __builtin_amdgcn_cvt_pk_f32_fp8((int)w, HI);
}
#else
DEV unsigned enc1(float x){
  union{float f; unsigned u;} c; c.f = x;
  unsigned s = (c.u >> 24) & 0x80;
  int e = (int)((c.u >> 23) & 0xff) - 127;
  unsigned m = c.u & 0x7fffff;
  if (e >= -6){
    unsigned mant = m >> 20, rem = m & 0xfffff;
    if (rem > 0x80000 || (rem == 0x80000 && (mant & 1))) mant++;
    unsigned eb = (unsigned)(e + 7);
    if (mant == 8){ mant = 0; eb++; }
    if (eb >= 16){ eb = 15; mant = 6; }
    return s | (eb << 3) | mant;
  }
  if (e < -10) return s;
  int sh = -6 - e;
  unsigned full = (1u << 23) | m;
  unsigned mant = full >> (20 + sh);
  unsigned rem  = full & ((1u << (20 + sh)) - 1);
  unsigned half = 1u << (19 + sh);
  if (rem > half || (rem == half && (mant & 1))) mant++;
  if (mant == 8) return s | (1u << 3);
  return s | mant;
}
DEV u32 pk4_fp8(f32x4 v){
  return enc1(v[0]) | (enc1(v[1]) << 8) | (enc1(v[2]) << 16) | (enc1(v[3]) << 24);
}
DEV float dec1(unsigned b){
  int s = (b >> 7) & 1, e = (b >> 3) & 15; float m = (float)(b & 7) * 0.125f;
  float v = e ? ldexpf(1.0f + m, e - 7) : ldexpf(m, -6);
  return s ? -v : v;
}
template<bool HI>
DEV f32x2 upk_fp8(u32 w){
  unsigned lo = HI ? ((w >> 16) & 0xff) : (w & 0xff);
  unsigned h2 = HI ? ((w >> 24) & 0xff) : ((w >> 8) & 0xff);
  f32x2 r; r[0] = dec1(lo); r[1] = dec1(h2); return r;
}
#endif

// ---------------- transpose + fp32->bf16 convert: src[K][N] -> dst[N][K] ----------------
__global__ void __launch_bounds__(256)
transpose_cvt(const float* __restrict__ src, u16* __restrict__ dst, int K, int N,
              size_t dzstride){
  int z = blockIdx.z;
  src += (size_t)z * K * N;
  dst += (size_t)z * dzstride;
  __shared__ float t[32][33];
  int n0 = blockIdx.x * 32, k0 = blockIdx.y * 32;
#pragma unroll
  for (int i = 0; i < 4; ++i)
    t[threadIdx.y + 8*i][threadIdx.x] = src[(size_t)(k0 + threadIdx.y + 8*i) * N + n0 + threadIdx.x];
  __syncthreads();
#pragma unroll
  for (int i = 0; i < 4; ++i)
    dst[(size_t)(n0 + threadIdx.y + 8*i) * K + k0 + threadIdx.x] = f2bf(t[threadIdx.x][threadIdx.y + 8*i]);
}

// ---------------- batched 768x768 transpose (20 weights in one dispatch) ----------------
struct TPtrs { const float* src[20]; u16* dst[20]; };
__global__ void __launch_bounds__(256)
transpose_cvt_batch(TPtrs tp){
  const float* src = tp.src[blockIdx.z];
  u16* dst = tp.dst[blockIdx.z];
  __shared__ float t[32][33];
  int n0 = blockIdx.x * 32, k0 = blockIdx.y * 32;
#pragma unroll
  for (int i = 0; i < 4; ++i)
    t[threadIdx.y + 8*i][threadIdx.x] = src[(size_t)(k0 + threadIdx.y + 8*i) * 768 + n0 + threadIdx.x];
  __syncthreads();
#pragma unroll
  for (int i = 0; i < 4; ++i)
    dst[(size_t)(n0 + threadIdx.y + 8*i) * 768 + k0 + threadIdx.x] = f2bf(t[threadIdx.x][threadIdx.y + 8*i]);
}

// ---------------- bias -> tiled fp8 (log2e*256-scaled) ----------------
__global__ void __launch_bounds__(256)
cvt_biasT(const float* __restrict__ in, unsigned char* __restrict__ out){
  const int kvt = blockIdx.x, qt = blockIdx.y, h = blockIdx.z, tid = threadIdx.x;
  const int q  = qt * 64 + ((tid >> 6) << 4) + (tid & 15);
  const int c0 = kvt * 64 + ((tid >> 4) & 3) * 4;
  const float* src = in + ((size_t)h * 2048 + q) * 2048;
  u32x4 wv;
#pragma unroll
  for (int mi = 0; mi < 4; ++mi){
    f32x4 v = *(const f32x4*)(src + c0 + mi * 16);
#pragma unroll
    for (int r = 0; r < 4; ++r) v[r] = fminf(fmaxf(v[r] * (LOG2E * BSCALE), -448.f), 448.f);
    wv[mi] = pk4_fp8(v);
  }
  *(u32x4*)(out + ((size_t)(h * 32 + qt) * 32 + kvt) * 4096 + tid * 16) = wv;
}

// ---------------- vectorized LayerNorm, one wave per row ----------------
__global__ void __launch_bounds__(256)
lnv(const float* __restrict__ x, const float* __restrict__ w, const float* __restrict__ b,
    u16* __restrict__ out){
  const int wv = threadIdx.x >> 6, lane = threadIdx.x & 63;
  const float* wz = w + blockIdx.y * 768;
  const float* bz = b + blockIdx.y * 768;
  out += (size_t)blockIdx.y * 4096 * 768;
  const int row = blockIdx.x * 4 + wv;
  const float* xr = x + (size_t)row * 768;
  f32x4 t[3]; float s = 0.f, s2 = 0.f;
#pragma unroll
  for (int c = 0; c < 3; ++c){
    t[c] = *(const f32x4*)(xr + c * 256 + lane * 4);
#pragma unroll
    for (int j = 0; j < 4; ++j){ s += t[c][j]; s2 += t[c][j] * t[c][j]; }
  }
#pragma unroll
  for (int off = 1; off < 64; off <<= 1){ s += __shfl_xor(s, off); s2 += __shfl_xor(s2, off); }
  float m = s * (1.f/768.f);
  float rstd = rsqrtf(s2 * (1.f/768.f) - m * m + 1e-5f);
#pragma unroll
  for (int c = 0; c < 3; ++c){
    const int col = c * 256 + lane * 4;
    f32x4 wv4 = *(const f32x4*)(wz + col);
    f32x4 bv4 = *(const f32x4*)(bz + col);
    u16x4 o;
#pragma unroll
    for (int j = 0; j < 4; ++j) o[j] = f2bf((t[c][j] - m) * rstd * wv4[j] + bv4[j]);
    *(u16x4*)(out + (size_t)row * 768 + col) = o;
  }
}

// ---------------- fused splitK(4)-reduce (bf16 partials) + bias + residual + LN --------
template<typename OUT>
__global__ void __launch_bounds__(256)
red_ln(const u16* __restrict__ pb, const float* __restrict__ biasrow,
       float* __restrict__ xbuf, OUT* __restrict__ out,
       const float* __restrict__ lw, const float* __restrict__ lb){
  const int wv = threadIdx.x >> 6, lane = threadIdx.x & 63;
  const int row = blockIdx.x * 4 + wv;
  const size_t S = 4096ll * 768;
  const u16* p0 = pb + (size_t)row * 768;
  float* xr = xbuf + (size_t)row * 768;
  f32x4 t[3]; float s = 0.f, s2 = 0.f;
#pragma unroll
  for (int c = 0; c < 3; ++c){
    const int col = c * 256 + lane * 4;
    f32x4 v = *(const f32x4*)(biasrow + col);
    v += *(const f32x4*)(xr + col);
#pragma unroll
    for (int z = 0; z < 4; ++z){
      u16x4 pv = *(const u16x4*)(p0 + z * S + col);
#pragma unroll
      for (int j = 0; j < 4; ++j) v[j] += bf2f(pv[j]);
    }
    *(f32x4*)(xr + col) = v;
    t[c] = v;
#pragma unroll
    for (int j = 0; j < 4; ++j){ s += v[j]; s2 += v[j] * v[j]; }
  }
#pragma unroll
  for (int off = 1; off < 64; off <<= 1){ s += __shfl_xor(s, off); s2 += __shfl_xor(s2, off); }
  float m = s * (1.f/768.f);
  float rstd = rsqrtf(s2 * (1.f/768.f) - m * m + 1e-5f);
#pragma unroll
  for (int c = 0; c < 3; ++c){
    const int col = c * 256 + lane * 4;
    f32x4 wv4 = *(const f32x4*)(lw + col);
    f32x4 bv4 = *(const f32x4*)(lb + col);
    if constexpr (sizeof(OUT) == 2){
      u16x4 o;
#pragma unroll
      for (int j = 0; j < 4; ++j) o[j] = f2bf((t[c][j] - m) * rstd * wv4[j] + bv4[j]);
      *(u16x4*)((u16*)out + (size_t)row * 768 + col) = o;
    } else {
      f32x4 o;
#pragma unroll
      for (int j = 0; j < 4; ++j) o[j] = (t[c][j] - m) * rstd * wv4[j] + bv4[j];
      *(f32x4*)((float*)out + (size_t)row * 768 + col) = o;
    }
  }
}

// ---------------- bf16 GEMM, 128x128, double-buffered, XCD-swizzled ----------------
// EPI 2: bf16 gelu(acc+bias[col]); EPI 3: bf16, cols<768 * QSCALE;
// EPI 4: merged cross q/k/v (z=0: A scaled; z=1/2: A2 @ Bt2[+(z-1)*768*768]; out += z*768);
// EPI 5: split-K bf16 partials (z in 0..3 selects K-quarter; Cb += z*4096*768).
template<int EPI>
__global__ void __launch_bounds__(256)
gemm_bf16(const u16* __restrict__ A, int lda, const u16* __restrict__ Bt, int ldb,
          int nk, u16* __restrict__ Cb, int ldc,
          const float* __restrict__ bias,
          const u16* __restrict__ A2, const u16* __restrict__ Bt2){
  __shared__ u16 As[2][128 * 32];
  __shared__ u16 Bs[2][128 * 32];
  float colscale = 1.0f;
  if constexpr (EPI == 4){
    const int z = blockIdx.z;
    if (z == 0){ colscale = QSCALE_CONST; }
    else { A = A2; Bt = Bt2 + (size_t)(z - 1) * 768 * 768; }
    Cb += z * 768;
  }
  if constexpr (EPI == 5){
    const int z = blockIdx.z;
    A  += (size_t)z * nk * 32;
    Bt += (size_t)z * nk * 32;
    Cb += (size_t)z * 4096 * 768;
  }
  // bijective XCD-chunked swizzle (m204) on the 2D slice
  const int gx = gridDim.x, nwg = gx * gridDim.y;
  int lin = blockIdx.y * gx + blockIdx.x;
  {
    const int qq = nwg >> 3, rr = nwg & 7;
    const int xc = lin & 7, oo = lin >> 3;
    lin = (xc < rr ? xc * (qq + 1) : rr * (qq + 1) + (xc - rr) * qq) + oo;
  }
  const int m0 = (lin % gx) * 128, n0 = (lin / gx) * 128;

  const int tid = threadIdx.x, w = tid >> 6, lane = tid & 63;
  const int l16 = lane & 15, g = lane >> 4;
  const int wm = (w >> 1) * 64, wn = (w & 1) * 64;
  f32x4 acc[4][4] = {};

  const u16* a0 = A  + (size_t)(m0 + (tid >> 2)) * lda + (tid & 3) * 8;
  const u16* a1 = A  + (size_t)(m0 + (tid >> 2) + 64) * lda + (tid & 3) * 8;
  const u16* b0 = Bt + (size_t)(n0 + (tid >> 2)) * ldb + (tid & 3) * 8;
  const u16* b1 = Bt + (size_t)(n0 + (tid >> 2) + 64) * ldb + (tid & 3) * 8;

  {
    char* ab = (char*)As[0]; char* bb = (char*)Bs[0];
    gld16(a0, ab + w * 1024); gld16(a1, ab + 4096 + w * 1024);
    gld16(b0, bb + w * 1024); gld16(b1, bb + 4096 + w * 1024);
  }
  __syncthreads();

  int cb = 0;
  for (int kt = 0; kt < nk; ++kt){
    if (kt + 1 < nk){
      const int k1 = (kt + 1) * 32;
      char* ab = (char*)As[cb ^ 1]; char* bb = (char*)Bs[cb ^ 1];
      gld16(a0 + k1, ab + w * 1024); gld16(a1 + k1, ab + 4096 + w * 1024);
      gld16(b0 + k1, bb + w * 1024); gld16(b1 + k1, bb + 4096 + w * 1024);
    }
    const u16* Ab = As[cb]; const u16* Bb = Bs[cb];
    s16x8 af[4], bfv[4];
#pragma unroll
    for (int mi = 0; mi < 4; ++mi)
      af[mi] = *(const s16x8*)(Ab + (wm + mi*16 + l16) * 32 + 8 * g);
#pragma unroll
    for (int ni = 0; ni < 4; ++ni)
      bfv[ni] = *(const s16x8*)(Bb + (wn + ni*16 + l16) * 32 + 8 * g);
#pragma unroll
    for (int mi = 0; mi < 4; ++mi)
#pragma unroll
      for (int ni = 0; ni < 4; ++ni)
        acc[mi][ni] = mfma16(af[mi], bfv[ni], acc[mi][ni]);
    __syncthreads();
    cb ^= 1;
  }

  // epilogue: C/D layout col = lane&15, row = 4*(lane>>4)+r
#pragma unroll
  for (int mi = 0; mi < 4; ++mi){
    const int rg = m0 + wm + mi*16 + 4*g;
#pragma unroll
    for (int ni = 0; ni < 4; ++ni){
      const int col = n0 + wn + ni*16 + l16;
      f32x4 v = acc[mi][ni];
#pragma unroll
      for (int r = 0; r < 4; ++r){
        const int row = rg + r;
        if constexpr (EPI == 2){
          float t = v[r] + bias[col];
          float ge = 0.5f * t * (1.0f + erff(t * 0.7071067811865476f));
          Cb[(size_t)row * ldc + col] = f2bf(ge);
        } else if constexpr (EPI == 3){
          float sc = (col < 768) ? QSCALE_CONST : 1.0f;
          Cb[(size_t)row * ldc + col] = f2bf(v[r] * sc);
        } else if constexpr (EPI == 4){
          Cb[(size_t)row * ldc + col] = f2bf(v[r] * colscale);
        } else {
          Cb[(size_t)row * 768 + col] = f2bf(v[r]);
        }
      }
    }
  }
}

// ---------------- fused flash attention v5: fp8 bias regs, setprio ----------------
__global__ void __launch_bounds__(256)
attn_kernel(const u16* __restrict__ qkv, const unsigned char* __restrict__ biasT,
            u16* __restrict__ out){
  __shared__ __align__(16) u16 Ks[2][4096];
  __shared__ __align__(16) u16 Vt[2][4096];
  __shared__ __align__(16) u16 Pl[4][1024];

  const int tid = threadIdx.x, w = tid >> 6, lane = tid & 63;
  const int l16 = lane & 15, g = lane >> 4;
  const int qt = blockIdx.x, h = blockIdx.y, b = blockIdx.z;
  const int rowbase = b * 2048, q0 = qt * 64;

  const int ci0 = w * 64 + lane, ci1 = ci0 + 256;
  const int r0 = ci0 >> 3, sc0 = ci0 & 7, r1 = ci1 >> 3, sc1 = ci1 & 7;
  const u16* kp0 = qkv + (size_t)(rowbase + r0) * 2304 + 768 + h * 64 + (((sc0 ^ (r0 & 7)) & 7) << 3);
  const u16* kp1 = qkv + (size_t)(rowbase + r1) * 2304 + 768 + h * 64 + (((sc1 ^ (r1 & 7)) & 7) << 3);
  const int dh0 = (tid & 31) * 2, vs = tid >> 5;
  const u16* vp = qkv + (size_t)(rowbase + vs * 8) * 2304 + 1536 + h * 64 + dh0;
  u16x2 vr[8];
  const unsigned char* bT = biasT + ((size_t)(h * 32 + qt) * 32) * 4096 + tid * 16;
  u32x4 brW, bnW;

  const u16* qrow = qkv + (size_t)(rowbase + q0 + w * 16 + l16) * 2304 + h * 64;
  s16x8 qf0 = *(const s16x8*)(qrow + 8 * g);
  s16x8 qf1 = *(const s16x8*)(qrow + 32 + 8 * g);

  f32x4 oacc[4] = {};
  float mrun = -3.0e38f, lrun = 0.f;
  const int sw = l16 & 7;

  {
    char* kb = (char*)Ks[0] + w * 1024;
    gld16(kp0, kb); gld16(kp1, kb + 4096);
#pragma unroll
    for (int i = 0; i < 8; ++i) vr[i] = *(const u16x2*)(vp + (size_t)i * 2304);
    brW = *(const u32x4*)(bT);
    s16x8 vA, vB;
#pragma unroll
    for (int j = 0; j < 8; ++j){ vA[j] = (short)vr[j][0]; vB[j] = (short)vr[j][1]; }
    *(s16x8*)(Vt[0] + dh0 * 64 + ((vs ^ (dh0 & 7)) << 3)) = vA;
    *(s16x8*)(Vt[0] + (dh0 + 1) * 64 + ((vs ^ ((dh0 + 1) & 7)) << 3)) = vB;
  }
  __syncthreads();

  for (int t = 0; t < 32; ++t){
    const int cb = t & 1;
    if (t < 31){
      const size_t koff = (size_t)(t + 1) * 64 * 2304;
      char* kb = (char*)Ks[cb ^ 1] + w * 1024;
      gld16(kp0 + koff, kb); gld16(kp1 + koff, kb + 4096);
      const u16* p = vp + koff;
#pragma unroll
      for (int i = 0; i < 8; ++i) vr[i] = *(const u16x2*)(p + (size_t)i * 2304);
      bnW = *(const u32x4*)(bT + (size_t)(t + 1) * 4096);
    }

    f32x4 st[4];
    __builtin_amdgcn_s_setprio(1);
#pragma unroll
    for (int mi = 0; mi < 4; ++mi){
      const int row = l16 + 16 * mi;
      s16x8 kf0 = *(const s16x8*)(Ks[cb] + row * 64 + ((g ^ sw) << 3));
      s16x8 kf1 = *(const s16x8*)(Ks[cb] + row * 64 + (((g + 4) ^ sw) << 3));
      f32x4 z = {};
      z = mfma16(kf0, qf0, z);
      st[mi] = mfma16(kf1, qf1, z);
    }
    __builtin_amdgcn_s_setprio(0);

    float tmax = -3.0e38f;
#pragma unroll
    for (int mi = 0; mi < 4; ++mi){
      f32x2 lo = upk_fp8<false>(brW[mi]);
      f32x2 hi = upk_fp8<true>(brW[mi]);
      st[mi][0] = fmaf(lo[0], BINV, st[mi][0]);
      st[mi][1] = fmaf(lo[1], BINV, st[mi][1]);
      st[mi][2] = fmaf(hi[0], BINV, st[mi][2]);
      st[mi][3] = fmaf(hi[1], BINV, st[mi][3]);
#pragma unroll
      for (int r = 0; r < 4; ++r) tmax = fmaxf(tmax, st[mi][r]);
    }
    tmax = fmaxf(tmax, __shfl_xor(tmax, 16));
    tmax = fmaxf(tmax, __shfl_xor(tmax, 32));
    if (!__all(tmax <= mrun + 8.f)){
      float mnew = fmaxf(mrun, tmax);
      float al = fexp2(mrun - mnew);
      mrun = mnew;
      lrun *= al;
#pragma unroll
      for (int r = 0; r < 4; ++r){
        float aq = __shfl(al, 4 * g + r);
#pragma unroll
        for (int ni = 0; ni < 4; ++ni) oacc[ni][r] *= aq;
      }
    }
    float ssum = 0.f;
#pragma unroll
    for (int mi = 0; mi < 4; ++mi){
      u16x4 pk;
#pragma unroll
      for (int r = 0; r < 4; ++r){
        float pv = fexp2(st[mi][r] - mrun);
        ssum += pv;
        pk[r] = f2bf(pv);
      }
      *(u16x4*)(Pl[w] + l16 * 64 + (((2*mi + (g >> 1)) ^ sw) << 3) + 4 * (g & 1)) = pk;
    }
    ssum += __shfl_xor(ssum, 16);
    ssum += __shfl_xor(ssum, 32);
    lrun += ssum;

    __builtin_amdgcn_s_setprio(1);
#pragma unroll
    for (int ks2 = 0; ks2 < 2; ++ks2){
      s16x8 pf = *(const s16x8*)(Pl[w] + l16 * 64 + (((4*ks2 + g) ^ sw) << 3));
#pragma unroll
      for (int ni = 0; ni < 4; ++ni){
        const int dh = l16 + 16 * ni;
        s16x8 vf = *(const s16x8*)(Vt[cb] + dh * 64 + (((4*ks2 + g) ^ sw) << 3));
        oacc[ni] = mfma16(pf, vf, oacc[ni]);
      }
    }
    __builtin_amdgcn_s_setprio(0);

    if (t < 31){
      s16x8 vA, vB;
#pragma unroll
      for (int j = 0; j < 8; ++j){ vA[j] = (short)vr[j][0]; vB[j] = (short)vr[j][1]; }
      *(s16x8*)(Vt[cb ^ 1] + dh0 * 64 + ((vs ^ (dh0 & 7)) << 3)) = vA;
      *(s16x8*)(Vt[cb ^ 1] + (dh0 + 1) * 64 + ((vs ^ ((dh0 + 1) & 7)) << 3)) = vB;
      brW = bnW;
    }
    __syncthreads();
  }

#pragma unroll
  for (int r = 0; r < 4; ++r){
    float lq = __shfl(lrun, 4 * g + r);
    float inv = 1.0f / lq;
    const int row = rowbase + q0 + w * 16 + 4 * g + r;
#pragma unroll
    for (int ni = 0; ni < 4; ++ni)
      out[(size_t)row * 768 + h * 64 + l16 + 16 * ni] = f2bf(oacc[ni][r] * inv);
  }
}

// ============================== host ==============================
extern "C" void kernel_launch(void* const* d_in, const int* in_sizes, int n_in,
                              void* d_out, int out_size, void* d_ws, size_t ws_size,
                              hipStream_t stream){
  const float* in_x    = (const float*)d_in[0];
  const float* in_ctx  = (const float*)d_in[1];
  const float* in_bias = (const float*)d_in[2];
  const float* ln1_w = (const float*)d_in[3];
  const float* ln1_b = (const float*)d_in[4];
  const float* w_qkv = (const float*)d_in[5];
  const float* w_so  = (const float*)d_in[6];
  const float* b_so  = (const float*)d_in[7];
  const float* ln2_w = (const float*)d_in[8];
  const float* ln2_b = (const float*)d_in[9];
  const float* w_q   = (const float*)d_in[10];
  const float* w_k   = (const float*)d_in[11];
  const float* w_v   = (const float*)d_in[12];
  const float* w_co  = (const float*)d_in[13];
  const float* b_co  = (const float*)d_in[14];
  const float* ln3_w = (const float*)d_in[15];
  const float* ln3_b = (const float*)d_in[16];
  const float* w_f1  = (const float*)d_in[17];
  const float* b_f1  = (const float*)d_in[18];
  const float* w_f2  = (const float*)d_in[19];
  const float* b_f2  = (const float*)d_in[20];
  const float* lnout_w = (const float*)d_in[21];
  const float* lnout_b = (const float*)d_in[22];

  char* p = (char*)d_ws;
  float* xbuf  = (float*)p;  p += 4096ll * 768 * 4;
  u16* pbuf    = (u16*)p;    p += 4ll * 4096 * 768 * 2;    // split-K bf16 partials
  u16* xn      = (u16*)p;    p += 4096ll * 768 * 2;
  u16* cn      = (u16*)p;    p += 4ll * 4096 * 768 * 2;    // per-layer LN(context)
  u16* qkvb    = (u16*)p;    p += 4096ll * 2304 * 2;
  u16* attO    = (u16*)p;    p += 4096ll * 768 * 2;
  u16* ffh     = (u16*)p;    p += 4096ll * 3072 * 2;
  u16* wqkvT   = (u16*)p;    p += 4ll * 2304 * 768 * 2;
  u16* wsoT    = (u16*)p;    p += 4ll * 768 * 768 * 2;
  u16* wqT     = (u16*)p;    p += 4ll * 768 * 768 * 2;
  u16* wkvT    = (u16*)p;    p += 4ll * 1536 * 768 * 2;
  u16* wcoT    = (u16*)p;    p += 4ll * 768 * 768 * 2;
  u16* wf1T    = (u16*)p;    p += 4ll * 3072 * 768 * 2;
  u16* wf2T    = (u16*)p;    p += 4ll * 768 * 3072 * 2;
  unsigned char* biasT = (unsigned char*)p; p += 12ll * 2048 * 2048;

  hipMemcpyAsync(xbuf, in_x, 4096ll * 768 * 4, hipMemcpyDeviceToDevice, stream);

  const dim3 tb(32, 8);
  transpose_cvt<<<dim3(72, 24, 4), tb, 0, stream>>>(w_qkv, wqkvT, 768, 2304, 2304ll*768);
  transpose_cvt<<<dim3(96, 24, 4), tb, 0, stream>>>(w_f1,  wf1T,  768, 3072, 3072ll*768);
  transpose_cvt<<<dim3(24, 96, 4), tb, 0, stream>>>(w_f2,  wf2T,  3072, 768, 768ll*3072);
  {
    TPtrs tp;
    for (int i = 0; i < 4; ++i){
      tp.src[i*5+0] = w_so + (size_t)i*768*768;  tp.dst[i*5+0] = wsoT + (size_t)i*768*768;
      tp.src[i*5+1] = w_q  + (size_t)i*768*768;  tp.dst[i*5+1] = wqT  + (size_t)i*768*768;
      tp.src[i*5+2] = w_k  + (size_t)i*768*768;  tp.dst[i*5+2] = wkvT + (size_t)i*1536*768;
      tp.src[i*5+3] = w_v  + (size_t)i*768*768;  tp.dst[i*5+3] = wkvT + (size_t)i*1536*768 + 768ll*768;
      tp.src[i*5+4] = w_co + (size_t)i*768*768;  tp.dst[i*5+4] = wcoT + (size_t)i*768*768;
    }
    transpose_cvt_batch<<<dim3(24, 24, 20), tb, 0, stream>>>(tp);
  }
  cvt_biasT<<<dim3(32, 32, 12), 256, 0, stream>>>(in_bias, biasT);
  lnv<<<dim3(1024, 4), 256, 0, stream>>>(in_ctx, ln2_w, ln2_b, cn);
  lnv<<<dim3(1024, 1), 256, 0, stream>>>(xbuf, ln1_w, ln1_b, xn);

  const dim3 ag(32, 12, 2);
  for (int i = 0; i < 4; ++i){
    // self-attention block
    gemm_bf16<3><<<dim3(32, 18), 256, 0, stream>>>(xn, 768, wqkvT + (size_t)i*2304*768, 768, 24,
                                                   qkvb, 2304, nullptr, nullptr, nullptr);
    attn_kernel<<<ag, 256, 0, stream>>>(qkvb, biasT, attO);
    gemm_bf16<5><<<dim3(32, 6, 4), 256, 0, stream>>>(attO, 768, wsoT + (size_t)i*768*768, 768, 6,
                                                     pbuf, 768, nullptr, nullptr, nullptr);
    red_ln<u16><<<1024, 256, 0, stream>>>(pbuf, b_so + i*768, xbuf, xn, ln2_w + i*768, ln2_b + i*768);
    // cross-attention block (merged q/k/v projection)
    gemm_bf16<4><<<dim3(32, 6, 3), 256, 0, stream>>>(xn, 768, wqT + (size_t)i*768*768, 768, 24,
                                                     qkvb, 2304, nullptr,
                                                     cn + (size_t)i*4096*768, wkvT + (size_t)i*1536*768);
    attn_kernel<<<ag, 256, 0, stream>>>(qkvb, biasT, attO);
    gemm_bf16<5><<<dim3(32, 6, 4), 256, 0, stream>>>(attO, 768, wcoT + (size_t)i*768*768, 768, 6,
                                                     pbuf, 768, nullptr, nullptr, nullptr);
    red_ln<u16><<<1024, 256, 0, stream>>>(pbuf, b_co + i*768, xbuf, xn, ln3_w + i*768, ln3_b + i*768);
    // FFN block
    gemm_bf16<2><<<dim3(32, 24), 256, 0, stream>>>(xn, 768, wf1T + (size_t)i*3072*768, 768, 24,
                                                   ffh, 3072, b_f1 + i*3072, nullptr, nullptr);
    gemm_bf16<5><<<dim3(32, 6, 4), 256, 0, stream>>>(ffh, 3072, wf2T + (size_t)i*768*3072, 3072, 24,
                                                     pbuf, 768, nullptr, nullptr, nullptr);
    if (i < 3)
      red_ln<u16><<<1024, 256, 0, stream>>>(pbuf, b_f2 + i*768, xbuf, xn, ln1_w + (i+1)*768, ln1_b + (i+1)*768);
    else
      red_ln<float><<<1024, 256, 0, stream>>>(pbuf, b_f2 + i*768, xbuf, (float*)d_out, lnout_w, lnout_b);
  }
}

// Round 10
// 1273.415 us; speedup vs baseline: 1.7074x; 1.0309x over previous
//
#include <hip/hip_runtime.h>
#include <cstdint>
#include <cstddef>

#define DEV static __device__ __forceinline__

typedef float  f32x4 __attribute__((ext_vector_type(4)));
typedef float  f32x2 __attribute__((ext_vector_type(2)));
typedef short  s16x8 __attribute__((ext_vector_type(8)));
typedef unsigned short u16;
typedef unsigned int   u32;
typedef unsigned int   u32x4 __attribute__((ext_vector_type(4)));
typedef unsigned short u16x2 __attribute__((ext_vector_type(2)));
typedef unsigned short u16x4 __attribute__((ext_vector_type(4)));
typedef __bf16 bf16x8 __attribute__((ext_vector_type(8)));

#define LOG2E 1.4426950408889634f
#define QSCALE_CONST 0.18033688011112042f   /* 0.125 * log2(e) */
#define BSCALE 256.0f                       /* bias fp8 pre-scale */
#define BINV   0.00390625f                  /* 1/256 */

DEV u16 f2bf(float f){ return __builtin_bit_cast(u16, (__bf16)f); }
DEV float bf2f(u16 v){ union { unsigned u; float f; } x; x.u = ((unsigned)v) << 16; return x.f; }

DEV float fexp2(float x){
#if __has_builtin(__builtin_amdgcn_exp2f)
  return __builtin_amdgcn_exp2f(x);
#else
  return exp2f(x);
#endif
}

DEV f32x4 mfma16(s16x8 a, s16x8 b, f32x4 c){
  return __builtin_amdgcn_mfma_f32_16x16x32_bf16(
      __builtin_bit_cast(bf16x8, a), __builtin_bit_cast(bf16x8, b), c, 0, 0, 0);
}

// async global->LDS, 16B per lane
DEV void gld16(const void* g, void* l){
  __builtin_amdgcn_global_load_lds(
      (const __attribute__((address_space(1))) void*)(uintptr_t)g,
      (__attribute__((address_space(3))) void*)(unsigned)(uintptr_t)l,
      16, 0, 0);
}

// ---- fp8 e4m3 (OCP) pack/unpack; HI is compile-time for the builtin ----
#if __has_builtin(__builtin_amdgcn_cvt_pk_fp8_f32) && __has_builtin(__builtin_amdgcn_cvt_pk_f32_fp8)
DEV u32 pk4_fp8(f32x4 v){
  int r = __builtin_amdgcn_cvt_pk_fp8_f32(v[0], v[1], 0, false);
  r     = __builtin_amdgcn_cvt_pk_fp8_f32(v[2], v[3], r, true);
  return (u32)r;
}
template<bool HI>
DEV f32x2 upk_fp8(u32 w){
  return __builtin_amdgcn_cvt_pk_f32_fp8((int)w, HI);
}
#else
DEV unsigned enc1(float x){
  union{float f; unsigned u;} c; c.f = x;
  unsigned s = (c.u >> 24) & 0x80;
  int e = (int)((c.u >> 23) & 0xff) - 127;
  unsigned m = c.u & 0x7fffff;
  if (e >= -6){
    unsigned mant = m >> 20, rem = m & 0xfffff;
    if (rem > 0x80000 || (rem == 0x80000 && (mant & 1))) mant++;
    unsigned eb = (unsigned)(e + 7);
    if (mant == 8){ mant = 0; eb++; }
    if (eb >= 16){ eb = 15; mant = 6; }
    return s | (eb << 3) | mant;
  }
  if (e < -10) return s;
  int sh = -6 - e;
  unsigned full = (1u << 23) | m;
  unsigned mant = full >> (20 + sh);
  unsigned rem  = full & ((1u << (20 + sh)) - 1);
  unsigned half = 1u << (19 + sh);
  if (rem > half || (rem == half && (mant & 1))) mant++;
  if (mant == 8) return s | (1u << 3);
  return s | mant;
}
DEV u32 pk4_fp8(f32x4 v){
  return enc1(v[0]) | (enc1(v[1]) << 8) | (enc1(v[2]) << 16) | (enc1(v[3]) << 24);
}
DEV float dec1(unsigned b){
  int s = (b >> 7) & 1, e = (b >> 3) & 15; float m = (float)(b & 7) * 0.125f;
  float v = e ? ldexpf(1.0f + m, e - 7) : ldexpf(m, -6);
  return s ? -v : v;
}
template<bool HI>
DEV f32x2 upk_fp8(u32 w){
  unsigned lo = HI ? ((w >> 16) & 0xff) : (w & 0xff);
  unsigned h2 = HI ? ((w >> 24) & 0xff) : ((w >> 8) & 0xff);
  f32x2 r; r[0] = dec1(lo); r[1] = dec1(h2); return r;
}
#endif

// ---------------- transpose + fp32->bf16 convert: src[K][N] -> dst[N][K] ----------------
__global__ void __launch_bounds__(256)
transpose_cvt(const float* __restrict__ src, u16* __restrict__ dst, int K, int N,
              size_t dzstride){
  int z = blockIdx.z;
  src += (size_t)z * K * N;
  dst += (size_t)z * dzstride;
  __shared__ float t[32][33];
  int n0 = blockIdx.x * 32, k0 = blockIdx.y * 32;
#pragma unroll
  for (int i = 0; i < 4; ++i)
    t[threadIdx.y + 8*i][threadIdx.x] = src[(size_t)(k0 + threadIdx.y + 8*i) * N + n0 + threadIdx.x];
  __syncthreads();
#pragma unroll
  for (int i = 0; i < 4; ++i)
    dst[(size_t)(n0 + threadIdx.y + 8*i) * K + k0 + threadIdx.x] = f2bf(t[threadIdx.x][threadIdx.y + 8*i]);
}

// ---------------- batched 768x768 transpose (20 weights in one dispatch) ----------------
struct TPtrs { const float* src[20]; u16* dst[20]; };
__global__ void __launch_bounds__(256)
transpose_cvt_batch(TPtrs tp){
  const float* src = tp.src[blockIdx.z];
  u16* dst = tp.dst[blockIdx.z];
  __shared__ float t[32][33];
  int n0 = blockIdx.x * 32, k0 = blockIdx.y * 32;
#pragma unroll
  for (int i = 0; i < 4; ++i)
    t[threadIdx.y + 8*i][threadIdx.x] = src[(size_t)(k0 + threadIdx.y + 8*i) * 768 + n0 + threadIdx.x];
  __syncthreads();
#pragma unroll
  for (int i = 0; i < 4; ++i)
    dst[(size_t)(n0 + threadIdx.y + 8*i) * 768 + k0 + threadIdx.x] = f2bf(t[threadIdx.x][threadIdx.y + 8*i]);
}

// ---------------- bias -> tiled fp8 (log2e*256-scaled) ----------------
__global__ void __launch_bounds__(256)
cvt_biasT(const float* __restrict__ in, unsigned char* __restrict__ out){
  const int kvt = blockIdx.x, qt = blockIdx.y, h = blockIdx.z, tid = threadIdx.x;
  const int q  = qt * 64 + ((tid >> 6) << 4) + (tid & 15);
  const int c0 = kvt * 64 + ((tid >> 4) & 3) * 4;
  const float* src = in + ((size_t)h * 2048 + q) * 2048;
  u32x4 wv;
#pragma unroll
  for (int mi = 0; mi < 4; ++mi){
    f32x4 v = *(const f32x4*)(src + c0 + mi * 16);
#pragma unroll
    for (int r = 0; r < 4; ++r) v[r] = fminf(fmaxf(v[r] * (LOG2E * BSCALE), -448.f), 448.f);
    wv[mi] = pk4_fp8(v);
  }
  *(u32x4*)(out + ((size_t)(h * 32 + qt) * 32 + kvt) * 4096 + tid * 16) = wv;
}

// ---------------- vectorized LayerNorm (fp32 in, bf16 out), one wave per row ------------
__global__ void __launch_bounds__(256)
lnv(const float* __restrict__ x, const float* __restrict__ w, const float* __restrict__ b,
    u16* __restrict__ out){
  const int wv = threadIdx.x >> 6, lane = threadIdx.x & 63;
  const float* wz = w + blockIdx.y * 768;
  const float* bz = b + blockIdx.y * 768;
  out += (size_t)blockIdx.y * 4096 * 768;
  const int row = blockIdx.x * 4 + wv;
  const float* xr = x + (size_t)row * 768;
  f32x4 t[3]; float s = 0.f, s2 = 0.f;
#pragma unroll
  for (int c = 0; c < 3; ++c){
    t[c] = *(const f32x4*)(xr + c * 256 + lane * 4);
#pragma unroll
    for (int j = 0; j < 4; ++j){ s += t[c][j]; s2 += t[c][j] * t[c][j]; }
  }
#pragma unroll
  for (int off = 1; off < 64; off <<= 1){ s += __shfl_xor(s, off); s2 += __shfl_xor(s2, off); }
  float m = s * (1.f/768.f);
  float rstd = rsqrtf(s2 * (1.f/768.f) - m * m + 1e-5f);
#pragma unroll
  for (int c = 0; c < 3; ++c){
    const int col = c * 256 + lane * 4;
    f32x4 wv4 = *(const f32x4*)(wz + col);
    f32x4 bv4 = *(const f32x4*)(bz + col);
    u16x4 o;
#pragma unroll
    for (int j = 0; j < 4; ++j) o[j] = f2bf((t[c][j] - m) * rstd * wv4[j] + bv4[j]);
    *(u16x4*)(out + (size_t)row * 768 + col) = o;
  }
}

// ---------------- init: xbuf(bf16) = x, xn = LN(x, ln1[0]) ----------------
__global__ void __launch_bounds__(256)
ln_init(const float* __restrict__ x, const float* __restrict__ w, const float* __restrict__ b,
        u16* __restrict__ xn, u16* __restrict__ xbuf){
  const int wv = threadIdx.x >> 6, lane = threadIdx.x & 63;
  const int row = blockIdx.x * 4 + wv;
  const float* xr = x + (size_t)row * 768;
  f32x4 t[3]; float s = 0.f, s2 = 0.f;
#pragma unroll
  for (int c = 0; c < 3; ++c){
    t[c] = *(const f32x4*)(xr + c * 256 + lane * 4);
#pragma unroll
    for (int j = 0; j < 4; ++j){ s += t[c][j]; s2 += t[c][j] * t[c][j]; }
  }
#pragma unroll
  for (int off = 1; off < 64; off <<= 1){ s += __shfl_xor(s, off); s2 += __shfl_xor(s2, off); }
  float m = s * (1.f/768.f);
  float rstd = rsqrtf(s2 * (1.f/768.f) - m * m + 1e-5f);
#pragma unroll
  for (int c = 0; c < 3; ++c){
    const int col = c * 256 + lane * 4;
    f32x4 wv4 = *(const f32x4*)(w + col);
    f32x4 bv4 = *(const f32x4*)(b + col);
    u16x4 o, xb;
#pragma unroll
    for (int j = 0; j < 4; ++j){
      o[j]  = f2bf((t[c][j] - m) * rstd * wv4[j] + bv4[j]);
      xb[j] = f2bf(t[c][j]);
    }
    *(u16x4*)(xn   + (size_t)row * 768 + col) = o;
    *(u16x4*)(xbuf + (size_t)row * 768 + col) = xb;
  }
}

// ---------------- fused splitK(NZ)-reduce (bf16 partials) + bias + bf16 residual + LN ---
template<typename OUT, int NZ>
__global__ void __launch_bounds__(256)
red_ln(const u16* __restrict__ pb, const float* __restrict__ biasrow,
       u16* __restrict__ xbuf, OUT* __restrict__ out,
       const float* __restrict__ lw, const float* __restrict__ lb){
  const int wv = threadIdx.x >> 6, lane = threadIdx.x & 63;
  const int row = blockIdx.x * 4 + wv;
  const size_t S = 4096ll * 768;
  const u16* p0 = pb + (size_t)row * 768;
  u16* xr = xbuf + (size_t)row * 768;
  f32x4 t[3]; float s = 0.f, s2 = 0.f;
#pragma unroll
  for (int c = 0; c < 3; ++c){
    const int col = c * 256 + lane * 4;
    f32x4 v = *(const f32x4*)(biasrow + col);
    u16x4 xv = *(const u16x4*)(xr + col);
#pragma unroll
    for (int j = 0; j < 4; ++j) v[j] += bf2f(xv[j]);
#pragma unroll
    for (int z = 0; z < NZ; ++z){
      u16x4 pv = *(const u16x4*)(p0 + z * S + col);
#pragma unroll
      for (int j = 0; j < 4; ++j) v[j] += bf2f(pv[j]);
    }
    u16x4 xo;
#pragma unroll
    for (int j = 0; j < 4; ++j) xo[j] = f2bf(v[j]);
    *(u16x4*)(xr + col) = xo;
    t[c] = v;
#pragma unroll
    for (int j = 0; j < 4; ++j){ s += v[j]; s2 += v[j] * v[j]; }
  }
#pragma unroll
  for (int off = 1; off < 64; off <<= 1){ s += __shfl_xor(s, off); s2 += __shfl_xor(s2, off); }
  float m = s * (1.f/768.f);
  float rstd = rsqrtf(s2 * (1.f/768.f) - m * m + 1e-5f);
#pragma unroll
  for (int c = 0; c < 3; ++c){
    const int col = c * 256 + lane * 4;
    f32x4 wv4 = *(const f32x4*)(lw + col);
    f32x4 bv4 = *(const f32x4*)(lb + col);
    if constexpr (sizeof(OUT) == 2){
      u16x4 o;
#pragma unroll
      for (int j = 0; j < 4; ++j) o[j] = f2bf((t[c][j] - m) * rstd * wv4[j] + bv4[j]);
      *(u16x4*)((u16*)out + (size_t)row * 768 + col) = o;
    } else {
      f32x4 o;
#pragma unroll
      for (int j = 0; j < 4; ++j) o[j] = (t[c][j] - m) * rstd * wv4[j] + bv4[j];
      *(f32x4*)((float*)out + (size_t)row * 768 + col) = o;
    }
  }
}

// ---------------- bf16 GEMM, 128x128, double-buffered, XCD-swizzled ----------------
// EPI 2: bf16 gelu(acc+bias[col]); EPI 3: bf16, cols<768 * QSCALE;
// EPI 4: merged cross q/k/v (z=0: A scaled; z=1/2: A2 @ Bt2[+(z-1)*768*768]; out += z*768);
// EPI 5: split-K bf16 partials (z selects K-chunk of nk steps; Cb += z*4096*768).
template<int EPI>
__global__ void __launch_bounds__(256)
gemm_bf16(const u16* __restrict__ A, int lda, const u16* __restrict__ Bt, int ldb,
          int nk, u16* __restrict__ Cb, int ldc,
          const float* __restrict__ bias,
          const u16* __restrict__ A2, const u16* __restrict__ Bt2){
  __shared__ u16 As[2][128 * 32];
  __shared__ u16 Bs[2][128 * 32];
  float colscale = 1.0f;
  if constexpr (EPI == 4){
    const int z = blockIdx.z;
    if (z == 0){ colscale = QSCALE_CONST; }
    else { A = A2; Bt = Bt2 + (size_t)(z - 1) * 768 * 768; }
    Cb += z * 768;
  }
  if constexpr (EPI == 5){
    const int z = blockIdx.z;
    A  += (size_t)z * nk * 32;
    Bt += (size_t)z * nk * 32;
    Cb += (size_t)z * 4096 * 768;
  }
  // bijective XCD-chunked swizzle (m204) on the 2D slice
  const int gx = gridDim.x, nwg = gx * gridDim.y;
  int lin = blockIdx.y * gx + blockIdx.x;
  {
    const int qq = nwg >> 3, rr = nwg & 7;
    const int xc = lin & 7, oo = lin >> 3;
    lin = (xc < rr ? xc * (qq + 1) : rr * (qq + 1) + (xc - rr) * qq) + oo;
  }
  const int m0 = (lin % gx) * 128, n0 = (lin / gx) * 128;

  const int tid = threadIdx.x, w = tid >> 6, lane = tid & 63;
  const int l16 = lane & 15, g = lane >> 4;
  const int wm = (w >> 1) * 64, wn = (w & 1) * 64;
  f32x4 acc[4][4] = {};

  const u16* a0 = A  + (size_t)(m0 + (tid >> 2)) * lda + (tid & 3) * 8;
  const u16* a1 = A  + (size_t)(m0 + (tid >> 2) + 64) * lda + (tid & 3) * 8;
  const u16* b0 = Bt + (size_t)(n0 + (tid >> 2)) * ldb + (tid & 3) * 8;
  const u16* b1 = Bt + (size_t)(n0 + (tid >> 2) + 64) * ldb + (tid & 3) * 8;

  {
    char* ab = (char*)As[0]; char* bb = (char*)Bs[0];
    gld16(a0, ab + w * 1024); gld16(a1, ab + 4096 + w * 1024);
    gld16(b0, bb + w * 1024); gld16(b1, bb + 4096 + w * 1024);
  }
  __syncthreads();

  int cb = 0;
  for (int kt = 0; kt < nk; ++kt){
    if (kt + 1 < nk){
      const int k1 = (kt + 1) * 32;
      char* ab = (char*)As[cb ^ 1]; char* bb = (char*)Bs[cb ^ 1];
      gld16(a0 + k1, ab + w * 1024); gld16(a1 + k1, ab + 4096 + w * 1024);
      gld16(b0 + k1, bb + w * 1024); gld16(b1 + k1, bb + 4096 + w * 1024);
    }
    const u16* Ab = As[cb]; const u16* Bb = Bs[cb];
    s16x8 af[4], bfv[4];
#pragma unroll
    for (int mi = 0; mi < 4; ++mi)
      af[mi] = *(const s16x8*)(Ab + (wm + mi*16 + l16) * 32 + 8 * g);
#pragma unroll
    for (int ni = 0; ni < 4; ++ni)
      bfv[ni] = *(const s16x8*)(Bb + (wn + ni*16 + l16) * 32 + 8 * g);
#pragma unroll
    for (int mi = 0; mi < 4; ++mi)
#pragma unroll
      for (int ni = 0; ni < 4; ++ni)
        acc[mi][ni] = mfma16(af[mi], bfv[ni], acc[mi][ni]);
    __syncthreads();
    cb ^= 1;
  }

  // epilogue: C/D layout col = lane&15, row = 4*(lane>>4)+r
#pragma unroll
  for (int mi = 0; mi < 4; ++mi){
    const int rg = m0 + wm + mi*16 + 4*g;
#pragma unroll
    for (int ni = 0; ni < 4; ++ni){
      const int col = n0 + wn + ni*16 + l16;
      f32x4 v = acc[mi][ni];
#pragma unroll
      for (int r = 0; r < 4; ++r){
        const int row = rg + r;
        if constexpr (EPI == 2){
          float t = v[r] + bias[col];
          float ge = 0.5f * t * (1.0f + erff(t * 0.7071067811865476f));
          Cb[(size_t)row * ldc + col] = f2bf(ge);
        } else if constexpr (EPI == 3){
          float sc = (col < 768) ? QSCALE_CONST : 1.0f;
          Cb[(size_t)row * ldc + col] = f2bf(v[r] * sc);
        } else if constexpr (EPI == 4){
          Cb[(size_t)row * ldc + col] = f2bf(v[r] * colscale);
        } else {
          Cb[(size_t)row * 768 + col] = f2bf(v[r]);
        }
      }
    }
  }
}

// ---------------- fused flash attention v5: fp8 bias regs, setprio ----------------
__global__ void __launch_bounds__(256)
attn_kernel(const u16* __restrict__ qkv, const unsigned char* __restrict__ biasT,
            u16* __restrict__ out){
  __shared__ __align__(16) u16 Ks[2][4096];
  __shared__ __align__(16) u16 Vt[2][4096];
  __shared__ __align__(16) u16 Pl[4][1024];

  const int tid = threadIdx.x, w = tid >> 6, lane = tid & 63;
  const int l16 = lane & 15, g = lane >> 4;
  const int qt = blockIdx.x, h = blockIdx.y, b = blockIdx.z;
  const int rowbase = b * 2048, q0 = qt * 64;

  const int ci0 = w * 64 + lane, ci1 = ci0 + 256;
  const int r0 = ci0 >> 3, sc0 = ci0 & 7, r1 = ci1 >> 3, sc1 = ci1 & 7;
  const u16* kp0 = qkv + (size_t)(rowbase + r0) * 2304 + 768 + h * 64 + (((sc0 ^ (r0 & 7)) & 7) << 3);
  const u16* kp1 = qkv + (size_t)(rowbase + r1) * 2304 + 768 + h * 64 + (((sc1 ^ (r1 & 7)) & 7) << 3);
  const int dh0 = (tid & 31) * 2, vs = tid >> 5;
  const u16* vp = qkv + (size_t)(rowbase + vs * 8) * 2304 + 1536 + h * 64 + dh0;
  u16x2 vr[8];
  const unsigned char* bT = biasT + ((size_t)(h * 32 + qt) * 32) * 4096 + tid * 16;
  u32x4 brW, bnW;

  const u16* qrow = qkv + (size_t)(rowbase + q0 + w * 16 + l16) * 2304 + h * 64;
  s16x8 qf0 = *(const s16x8*)(qrow + 8 * g);
  s16x8 qf1 = *(const s16x8*)(qrow + 32 + 8 * g);

  f32x4 oacc[4] = {};
  float mrun = -3.0e38f, lrun = 0.f;
  const int sw = l16 & 7;

  {
    char* kb = (char*)Ks[0] + w * 1024;
    gld16(kp0, kb); gld16(kp1, kb + 4096);
#pragma unroll
    for (int i = 0; i < 8; ++i) vr[i] = *(const u16x2*)(vp + (size_t)i * 2304);
    brW = *(const u32x4*)(bT);
    s16x8 vA, vB;
#pragma unroll
    for (int j = 0; j < 8; ++j){ vA[j] = (short)vr[j][0]; vB[j] = (short)vr[j][1]; }
    *(s16x8*)(Vt[0] + dh0 * 64 + ((vs ^ (dh0 & 7)) << 3)) = vA;
    *(s16x8*)(Vt[0] + (dh0 + 1) * 64 + ((vs ^ ((dh0 + 1) & 7)) << 3)) = vB;
  }
  __syncthreads();

  for (int t = 0; t < 32; ++t){
    const int cb = t & 1;
    if (t < 31){
      const size_t koff = (size_t)(t + 1) * 64 * 2304;
      char* kb = (char*)Ks[cb ^ 1] + w * 1024;
      gld16(kp0 + koff, kb); gld16(kp1 + koff, kb + 4096);
      const u16* p = vp + koff;
#pragma unroll
      for (int i = 0; i < 8; ++i) vr[i] = *(const u16x2*)(p + (size_t)i * 2304);
      bnW = *(const u32x4*)(bT + (size_t)(t + 1) * 4096);
    }

    f32x4 st[4];
    __builtin_amdgcn_s_setprio(1);
#pragma unroll
    for (int mi = 0; mi < 4; ++mi){
      const int row = l16 + 16 * mi;
      s16x8 kf0 = *(const s16x8*)(Ks[cb] + row * 64 + ((g ^ sw) << 3));
      s16x8 kf1 = *(const s16x8*)(Ks[cb] + row * 64 + (((g + 4) ^ sw) << 3));
      f32x4 z = {};
      z = mfma16(kf0, qf0, z);
      st[mi] = mfma16(kf1, qf1, z);
    }
    __builtin_amdgcn_s_setprio(0);

    float tmax = -3.0e38f;
#pragma unroll
    for (int mi = 0; mi < 4; ++mi){
      f32x2 lo = upk_fp8<false>(brW[mi]);
      f32x2 hi = upk_fp8<true>(brW[mi]);
      st[mi][0] = fmaf(lo[0], BINV, st[mi][0]);
      st[mi][1] = fmaf(lo[1], BINV, st[mi][1]);
      st[mi][2] = fmaf(hi[0], BINV, st[mi][2]);
      st[mi][3] = fmaf(hi[1], BINV, st[mi][3]);
#pragma unroll
      for (int r = 0; r < 4; ++r) tmax = fmaxf(tmax, st[mi][r]);
    }
    tmax = fmaxf(tmax, __shfl_xor(tmax, 16));
    tmax = fmaxf(tmax, __shfl_xor(tmax, 32));
    if (!__all(tmax <= mrun + 8.f)){
      float mnew = fmaxf(mrun, tmax);
      float al = fexp2(mrun - mnew);
      mrun = mnew;
      lrun *= al;
#pragma unroll
      for (int r = 0; r < 4; ++r){
        float aq = __shfl(al, 4 * g + r);
#pragma unroll
        for (int ni = 0; ni < 4; ++ni) oacc[ni][r] *= aq;
      }
    }
    float ssum = 0.f;
#pragma unroll
    for (int mi = 0; mi < 4; ++mi){
      u16x4 pk;
#pragma unroll
      for (int r = 0; r < 4; ++r){
        float pv = fexp2(st[mi][r] - mrun);
        ssum += pv;
        pk[r] = f2bf(pv);
      }
      *(u16x4*)(Pl[w] + l16 * 64 + (((2*mi + (g >> 1)) ^ sw) << 3) + 4 * (g & 1)) = pk;
    }
    ssum += __shfl_xor(ssum, 16);
    ssum += __shfl_xor(ssum, 32);
    lrun += ssum;

    __builtin_amdgcn_s_setprio(1);
#pragma unroll
    for (int ks2 = 0; ks2 < 2; ++ks2){
      s16x8 pf = *(const s16x8*)(Pl[w] + l16 * 64 + (((4*ks2 + g) ^ sw) << 3));
#pragma unroll
      for (int ni = 0; ni < 4; ++ni){
        const int dh = l16 + 16 * ni;
        s16x8 vf = *(const s16x8*)(Vt[cb] + dh * 64 + (((4*ks2 + g) ^ sw) << 3));
        oacc[ni] = mfma16(pf, vf, oacc[ni]);
      }
    }
    __builtin_amdgcn_s_setprio(0);

    if (t < 31){
      s16x8 vA, vB;
#pragma unroll
      for (int j = 0; j < 8; ++j){ vA[j] = (short)vr[j][0]; vB[j] = (short)vr[j][1]; }
      *(s16x8*)(Vt[cb ^ 1] + dh0 * 64 + ((vs ^ (dh0 & 7)) << 3)) = vA;
      *(s16x8*)(Vt[cb ^ 1] + (dh0 + 1) * 64 + ((vs ^ ((dh0 + 1) & 7)) << 3)) = vB;
      brW = bnW;
    }
    __syncthreads();
  }

#pragma unroll
  for (int r = 0; r < 4; ++r){
    float lq = __shfl(lrun, 4 * g + r);
    float inv = 1.0f / lq;
    const int row = rowbase + q0 + w * 16 + 4 * g + r;
#pragma unroll
    for (int ni = 0; ni < 4; ++ni)
      out[(size_t)row * 768 + h * 64 + l16 + 16 * ni] = f2bf(oacc[ni][r] * inv);
  }
}

// ============================== host ==============================
extern "C" void kernel_launch(void* const* d_in, const int* in_sizes, int n_in,
                              void* d_out, int out_size, void* d_ws, size_t ws_size,
                              hipStream_t stream){
  const float* in_x    = (const float*)d_in[0];
  const float* in_ctx  = (const float*)d_in[1];
  const float* in_bias = (const float*)d_in[2];
  const float* ln1_w = (const float*)d_in[3];
  const float* ln1_b = (const float*)d_in[4];
  const float* w_qkv = (const float*)d_in[5];
  const float* w_so  = (const float*)d_in[6];
  const float* b_so  = (const float*)d_in[7];
  const float* ln2_w = (const float*)d_in[8];
  const float* ln2_b = (const float*)d_in[9];
  const float* w_q   = (const float*)d_in[10];
  const float* w_k   = (const float*)d_in[11];
  const float* w_v   = (const float*)d_in[12];
  const float* w_co  = (const float*)d_in[13];
  const float* b_co  = (const float*)d_in[14];
  const float* ln3_w = (const float*)d_in[15];
  const float* ln3_b = (const float*)d_in[16];
  const float* w_f1  = (const float*)d_in[17];
  const float* b_f1  = (const float*)d_in[18];
  const float* w_f2  = (const float*)d_in[19];
  const float* b_f2  = (const float*)d_in[20];
  const float* lnout_w = (const float*)d_in[21];
  const float* lnout_b = (const float*)d_in[22];

  char* p = (char*)d_ws;
  u16* xbuf    = (u16*)p;    p += 4096ll * 768 * 2;        // bf16 residual stream
  u16* pbuf    = (u16*)p;    p += 4ll * 4096 * 768 * 2;    // split-K bf16 partials
  u16* xn      = (u16*)p;    p += 4096ll * 768 * 2;
  u16* cn      = (u16*)p;    p += 4ll * 4096 * 768 * 2;    // per-layer LN(context)
  u16* qkvb    = (u16*)p;    p += 4096ll * 2304 * 2;
  u16* attO    = (u16*)p;    p += 4096ll * 768 * 2;
  u16* ffh     = (u16*)p;    p += 4096ll * 3072 * 2;
  u16* wqkvT   = (u16*)p;    p += 4ll * 2304 * 768 * 2;
  u16* wsoT    = (u16*)p;    p += 4ll * 768 * 768 * 2;
  u16* wqT     = (u16*)p;    p += 4ll * 768 * 768 * 2;
  u16* wkvT    = (u16*)p;    p += 4ll * 1536 * 768 * 2;
  u16* wcoT    = (u16*)p;    p += 4ll * 768 * 768 * 2;
  u16* wf1T    = (u16*)p;    p += 4ll * 3072 * 768 * 2;
  u16* wf2T    = (u16*)p;    p += 4ll * 768 * 3072 * 2;
  unsigned char* biasT = (unsigned char*)p; p += 12ll * 2048 * 2048;

  const dim3 tb(32, 8);
  transpose_cvt<<<dim3(72, 24, 4), tb, 0, stream>>>(w_qkv, wqkvT, 768, 2304, 2304ll*768);
  transpose_cvt<<<dim3(96, 24, 4), tb, 0, stream>>>(w_f1,  wf1T,  768, 3072, 3072ll*768);
  transpose_cvt<<<dim3(24, 96, 4), tb, 0, stream>>>(w_f2,  wf2T,  3072, 768, 768ll*3072);
  {
    TPtrs tp;
    for (int i = 0; i < 4; ++i){
      tp.src[i*5+0] = w_so + (size_t)i*768*768;  tp.dst[i*5+0] = wsoT + (size_t)i*768*768;
      tp.src[i*5+1] = w_q  + (size_t)i*768*768;  tp.dst[i*5+1] = wqT  + (size_t)i*768*768;
      tp.src[i*5+2] = w_k  + (size_t)i*768*768;  tp.dst[i*5+2] = wkvT + (size_t)i*1536*768;
      tp.src[i*5+3] = w_v  + (size_t)i*768*768;  tp.dst[i*5+3] = wkvT + (size_t)i*1536*768 + 768ll*768;
      tp.src[i*5+4] = w_co + (size_t)i*768*768;  tp.dst[i*5+4] = wcoT + (size_t)i*768*768;
    }
    transpose_cvt_batch<<<dim3(24, 24, 20), tb, 0, stream>>>(tp);
  }
  cvt_biasT<<<dim3(32, 32, 12), 256, 0, stream>>>(in_bias, biasT);
  lnv<<<dim3(1024, 4), 256, 0, stream>>>(in_ctx, ln2_w, ln2_b, cn);
  ln_init<<<1024, 256, 0, stream>>>(in_x, ln1_w, ln1_b, xn, xbuf);

  const dim3 ag(32, 12, 2);
  for (int i = 0; i < 4; ++i){
    // self-attention block
    gemm_bf16<3><<<dim3(32, 18), 256, 0, stream>>>(xn, 768, wqkvT + (size_t)i*2304*768, 768, 24,
                                                   qkvb, 2304, nullptr, nullptr, nullptr);
    attn_kernel<<<ag, 256, 0, stream>>>(qkvb, biasT, attO);
    gemm_bf16<5><<<dim3(32, 6, 2), 256, 0, stream>>>(attO, 768, wsoT + (size_t)i*768*768, 768, 12,
                                                     pbuf, 768, nullptr, nullptr, nullptr);
    red_ln<u16,2><<<1024, 256, 0, stream>>>(pbuf, b_so + i*768, xbuf, xn, ln2_w + i*768, ln2_b + i*768);
    // cross-attention block (merged q/k/v projection)
    gemm_bf16<4><<<dim3(32, 6, 3), 256, 0, stream>>>(xn, 768, wqT + (size_t)i*768*768, 768, 24,
                                                     qkvb, 2304, nullptr,
                                                     cn + (size_t)i*4096*768, wkvT + (size_t)i*1536*768);
    attn_kernel<<<ag, 256, 0, stream>>>(qkvb, biasT, attO);
    gemm_bf16<5><<<dim3(32, 6, 2), 256, 0, stream>>>(attO, 768, wcoT + (size_t)i*768*768, 768, 12,
                                                     pbuf, 768, nullptr, nullptr, nullptr);
    red_ln<u16,2><<<1024, 256, 0, stream>>>(pbuf, b_co + i*768, xbuf, xn, ln3_w + i*768, ln3_b + i*768);
    // FFN block
    gemm_bf16<2><<<dim3(32, 24), 256, 0, stream>>>(xn, 768, wf1T + (size_t)i*3072*768, 768, 24,
                                                   ffh, 3072, b_f1 + i*3072, nullptr, nullptr);
    gemm_bf16<5><<<dim3(32, 6, 4), 256, 0, stream>>>(ffh, 3072, wf2T + (size_t)i*768*3072, 3072, 24,
                                                     pbuf, 768, nullptr, nullptr, nullptr);
    if (i < 3)
      red_ln<u16,4><<<1024, 256, 0, stream>>>(pbuf, b_f2 + i*768, xbuf, xn, ln1_w + (i+1)*768, ln1_b + (i+1)*768);
    else
      red_ln<float,4><<<1024, 256, 0, stream>>>(pbuf, b_f2 + i*768, xbuf, (float*)d_out, lnout_w, lnout_b);
  }
}

// Round 11
// 1272.664 us; speedup vs baseline: 1.7084x; 1.0006x over previous
//
#include <hip/hip_runtime.h>
#include <cstdint>
#include <cstddef>

#define DEV static __device__ __forceinline__

typedef float  f32x4 __attribute__((ext_vector_type(4)));
typedef float  f32x2 __attribute__((ext_vector_type(2)));
typedef short  s16x8 __attribute__((ext_vector_type(8)));
typedef unsigned short u16;
typedef unsigned int   u32;
typedef unsigned int   u32x4 __attribute__((ext_vector_type(4)));
typedef unsigned short u16x2 __attribute__((ext_vector_type(2)));
typedef unsigned short u16x4 __attribute__((ext_vector_type(4)));
typedef __bf16 bf16x8 __attribute__((ext_vector_type(8)));

#define LOG2E 1.4426950408889634f
#define QSCALE_CONST 0.18033688011112042f   /* 0.125 * log2(e) */
#define BSCALE 256.0f                       /* bias fp8 pre-scale */
#define BINV   0.00390625f                  /* 1/256 */

DEV u16 f2bf(float f){ return __builtin_bit_cast(u16, (__bf16)f); }
DEV float bf2f(u16 v){ union { unsigned u; float f; } x; x.u = ((unsigned)v) << 16; return x.f; }

DEV float fexp2(float x){
#if __has_builtin(__builtin_amdgcn_exp2f)
  return __builtin_amdgcn_exp2f(x);
#else
  return exp2f(x);
#endif
}

DEV f32x4 mfma16(s16x8 a, s16x8 b, f32x4 c){
  return __builtin_amdgcn_mfma_f32_16x16x32_bf16(
      __builtin_bit_cast(bf16x8, a), __builtin_bit_cast(bf16x8, b), c, 0, 0, 0);
}

// async global->LDS, 16B per lane
DEV void gld16(const void* g, void* l){
  __builtin_amdgcn_global_load_lds(
      (const __attribute__((address_space(1))) void*)(uintptr_t)g,
      (__attribute__((address_space(3))) void*)(unsigned)(uintptr_t)l,
      16, 0, 0);
}

// ---- fp8 e4m3 (OCP) pack/unpack; HI is compile-time for the builtin ----
#if __has_builtin(__builtin_amdgcn_cvt_pk_fp8_f32) && __has_builtin(__builtin_amdgcn_cvt_pk_f32_fp8)
DEV u32 pk4_fp8(f32x4 v){
  int r = __builtin_amdgcn_cvt_pk_fp8_f32(v[0], v[1], 0, false);
  r     = __builtin_amdgcn_cvt_pk_fp8_f32(v[2], v[3], r, true);
  return (u32)r;
}
template<bool HI>
DEV f32x2 upk_fp8(u32 w){
  return __builtin_amdgcn_cvt_pk_f32_fp8((int)w, HI);
}
#else
DEV unsigned enc1(float x){
  union{float f; unsigned u;} c; c.f = x;
  unsigned s = (c.u >> 24) & 0x80;
  int e = (int)((c.u >> 23) & 0xff) - 127;
  unsigned m = c.u & 0x7fffff;
  if (e >= -6){
    unsigned mant = m >> 20, rem = m & 0xfffff;
    if (rem > 0x80000 || (rem == 0x80000 && (mant & 1))) mant++;
    unsigned eb = (unsigned)(e + 7);
    if (mant == 8){ mant = 0; eb++; }
    if (eb >= 16){ eb = 15; mant = 6; }
    return s | (eb << 3) | mant;
  }
  if (e < -10) return s;
  int sh = -6 - e;
  unsigned full = (1u << 23) | m;
  unsigned mant = full >> (20 + sh);
  unsigned rem  = full & ((1u << (20 + sh)) - 1);
  unsigned half = 1u << (19 + sh);
  if (rem > half || (rem == half && (mant & 1))) mant++;
  if (mant == 8) return s | (1u << 3);
  return s | mant;
}
DEV u32 pk4_fp8(f32x4 v){
  return enc1(v[0]) | (enc1(v[1]) << 8) | (enc1(v[2]) << 16) | (enc1(v[3]) << 24);
}
DEV float dec1(unsigned b){
  int s = (b >> 7) & 1, e = (b >> 3) & 15; float m = (float)(b & 7) * 0.125f;
  float v = e ? ldexpf(1.0f + m, e - 7) : ldexpf(m, -6);
  return s ? -v : v;
}
template<bool HI>
DEV f32x2 upk_fp8(u32 w){
  unsigned lo = HI ? ((w >> 16) & 0xff) : (w & 0xff);
  unsigned h2 = HI ? ((w >> 24) & 0xff) : ((w >> 8) & 0xff);
  f32x2 r; r[0] = dec1(lo); r[1] = dec1(h2); return r;
}
#endif

// ---------------- transpose + fp32->bf16 convert: src[K][N] -> dst[N][K] ----------------
__global__ void __launch_bounds__(256)
transpose_cvt(const float* __restrict__ src, u16* __restrict__ dst, int K, int N,
              size_t dzstride){
  int z = blockIdx.z;
  src += (size_t)z * K * N;
  dst += (size_t)z * dzstride;
  __shared__ float t[32][33];
  int n0 = blockIdx.x * 32, k0 = blockIdx.y * 32;
#pragma unroll
  for (int i = 0; i < 4; ++i)
    t[threadIdx.y + 8*i][threadIdx.x] = src[(size_t)(k0 + threadIdx.y + 8*i) * N + n0 + threadIdx.x];
  __syncthreads();
#pragma unroll
  for (int i = 0; i < 4; ++i)
    dst[(size_t)(n0 + threadIdx.y + 8*i) * K + k0 + threadIdx.x] = f2bf(t[threadIdx.x][threadIdx.y + 8*i]);
}

// ---------------- batched 768x768 transpose (20 weights in one dispatch) ----------------
struct TPtrs { const float* src[20]; u16* dst[20]; };
__global__ void __launch_bounds__(256)
transpose_cvt_batch(TPtrs tp){
  const float* src = tp.src[blockIdx.z];
  u16* dst = tp.dst[blockIdx.z];
  __shared__ float t[32][33];
  int n0 = blockIdx.x * 32, k0 = blockIdx.y * 32;
#pragma unroll
  for (int i = 0; i < 4; ++i)
    t[threadIdx.y + 8*i][threadIdx.x] = src[(size_t)(k0 + threadIdx.y + 8*i) * 768 + n0 + threadIdx.x];
  __syncthreads();
#pragma unroll
  for (int i = 0; i < 4; ++i)
    dst[(size_t)(n0 + threadIdx.y + 8*i) * 768 + k0 + threadIdx.x] = f2bf(t[threadIdx.x][threadIdx.y + 8*i]);
}

// ---------------- bias -> tiled fp8 (log2e*256-scaled) ----------------
__global__ void __launch_bounds__(256)
cvt_biasT(const float* __restrict__ in, unsigned char* __restrict__ out){
  const int kvt = blockIdx.x, qt = blockIdx.y, h = blockIdx.z, tid = threadIdx.x;
  const int q  = qt * 64 + ((tid >> 6) << 4) + (tid & 15);
  const int c0 = kvt * 64 + ((tid >> 4) & 3) * 4;
  const float* src = in + ((size_t)h * 2048 + q) * 2048;
  u32x4 wv;
#pragma unroll
  for (int mi = 0; mi < 4; ++mi){
    f32x4 v = *(const f32x4*)(src + c0 + mi * 16);
#pragma unroll
    for (int r = 0; r < 4; ++r) v[r] = fminf(fmaxf(v[r] * (LOG2E * BSCALE), -448.f), 448.f);
    wv[mi] = pk4_fp8(v);
  }
  *(u32x4*)(out + ((size_t)(h * 32 + qt) * 32 + kvt) * 4096 + tid * 16) = wv;
}

// ---------------- pre-pass LN: stats computed ONCE per row ----------------
// y==0: row from x   -> xbuf(bf16 copy) + xn = LN(x, w1,b1)         [ln1 layer 0]
// y==1: row from ctx -> cn[i] = LN(ctx, w2+i*768, b2+i*768), i=0..3  [all ln2 layers]
__global__ void __launch_bounds__(256)
ln_pre(const float* __restrict__ x, const float* __restrict__ ctx,
       const float* __restrict__ w1, const float* __restrict__ b1,
       const float* __restrict__ w2, const float* __restrict__ b2,
       u16* __restrict__ xn, u16* __restrict__ xbuf, u16* __restrict__ cn){
  const int wv = threadIdx.x >> 6, lane = threadIdx.x & 63;
  const int row = blockIdx.x * 4 + wv;
  const float* xr = (blockIdx.y == 0 ? x : ctx) + (size_t)row * 768;
  f32x4 t[3]; float s = 0.f, s2 = 0.f;
#pragma unroll
  for (int c = 0; c < 3; ++c){
    t[c] = *(const f32x4*)(xr + c * 256 + lane * 4);
#pragma unroll
    for (int j = 0; j < 4; ++j){ s += t[c][j]; s2 += t[c][j] * t[c][j]; }
  }
#pragma unroll
  for (int off = 1; off < 64; off <<= 1){ s += __shfl_xor(s, off); s2 += __shfl_xor(s2, off); }
  float m = s * (1.f/768.f);
  float rstd = rsqrtf(s2 * (1.f/768.f) - m * m + 1e-5f);
  if (blockIdx.y == 0){
#pragma unroll
    for (int c = 0; c < 3; ++c){
      const int col = c * 256 + lane * 4;
      f32x4 wv4 = *(const f32x4*)(w1 + col);
      f32x4 bv4 = *(const f32x4*)(b1 + col);
      u16x4 o, xb;
#pragma unroll
      for (int j = 0; j < 4; ++j){
        o[j]  = f2bf((t[c][j] - m) * rstd * wv4[j] + bv4[j]);
        xb[j] = f2bf(t[c][j]);
      }
      *(u16x4*)(xn   + (size_t)row * 768 + col) = o;
      *(u16x4*)(xbuf + (size_t)row * 768 + col) = xb;
    }
  } else {
#pragma unroll
    for (int i = 0; i < 4; ++i){
      u16* dst = cn + (size_t)i * 4096 * 768 + (size_t)row * 768;
#pragma unroll
      for (int c = 0; c < 3; ++c){
        const int col = c * 256 + lane * 4;
        f32x4 wv4 = *(const f32x4*)(w2 + i * 768 + col);
        f32x4 bv4 = *(const f32x4*)(b2 + i * 768 + col);
        u16x4 o;
#pragma unroll
        for (int j = 0; j < 4; ++j) o[j] = f2bf((t[c][j] - m) * rstd * wv4[j] + bv4[j]);
        *(u16x4*)(dst + col) = o;
      }
    }
  }
}

// ---------------- fused splitK(NZ)-reduce + bias + bf16 residual + LN, 2 rows/wave -----
template<typename OUT, int NZ>
__global__ void __launch_bounds__(256)
red_ln(const u16* __restrict__ pb, const float* __restrict__ biasrow,
       u16* __restrict__ xbuf, OUT* __restrict__ out,
       const float* __restrict__ lw, const float* __restrict__ lb){
  const int wv = threadIdx.x >> 6, lane = threadIdx.x & 63;
  const int row0 = blockIdx.x * 8 + wv * 2;
  const size_t S = 4096ll * 768;
  f32x4 t[2][3]; float s[2] = {0.f, 0.f}, s2[2] = {0.f, 0.f};
#pragma unroll
  for (int rr = 0; rr < 2; ++rr){
    const int row = row0 + rr;
    const u16* p0 = pb + (size_t)row * 768;
    u16* xr = xbuf + (size_t)row * 768;
#pragma unroll
    for (int c = 0; c < 3; ++c){
      const int col = c * 256 + lane * 4;
      f32x4 v = *(const f32x4*)(biasrow + col);
      u16x4 xv = *(const u16x4*)(xr + col);
#pragma unroll
      for (int j = 0; j < 4; ++j) v[j] += bf2f(xv[j]);
#pragma unroll
      for (int z = 0; z < NZ; ++z){
        u16x4 pv = *(const u16x4*)(p0 + z * S + col);
#pragma unroll
        for (int j = 0; j < 4; ++j) v[j] += bf2f(pv[j]);
      }
      u16x4 xo;
#pragma unroll
      for (int j = 0; j < 4; ++j) xo[j] = f2bf(v[j]);
      *(u16x4*)(xr + col) = xo;
      t[rr][c] = v;
#pragma unroll
      for (int j = 0; j < 4; ++j){ s[rr] += v[j]; s2[rr] += v[j] * v[j]; }
    }
  }
#pragma unroll
  for (int off = 1; off < 64; off <<= 1){
#pragma unroll
    for (int rr = 0; rr < 2; ++rr){
      s[rr]  += __shfl_xor(s[rr], off);
      s2[rr] += __shfl_xor(s2[rr], off);
    }
  }
#pragma unroll
  for (int rr = 0; rr < 2; ++rr){
    const int row = row0 + rr;
    float m = s[rr] * (1.f/768.f);
    float rstd = rsqrtf(s2[rr] * (1.f/768.f) - m * m + 1e-5f);
#pragma unroll
    for (int c = 0; c < 3; ++c){
      const int col = c * 256 + lane * 4;
      f32x4 wv4 = *(const f32x4*)(lw + col);
      f32x4 bv4 = *(const f32x4*)(lb + col);
      if constexpr (sizeof(OUT) == 2){
        u16x4 o;
#pragma unroll
        for (int j = 0; j < 4; ++j) o[j] = f2bf((t[rr][c][j] - m) * rstd * wv4[j] + bv4[j]);
        *(u16x4*)((u16*)out + (size_t)row * 768 + col) = o;
      } else {
        f32x4 o;
#pragma unroll
        for (int j = 0; j < 4; ++j) o[j] = (t[rr][c][j] - m) * rstd * wv4[j] + bv4[j];
        *(f32x4*)((float*)out + (size_t)row * 768 + col) = o;
      }
    }
  }
}

// ---------------- bf16 GEMM, 128x128, double-buffered, XCD-swizzled ----------------
// EPI 2: bf16 gelu(acc+bias[col]); EPI 3: bf16, cols<768 * QSCALE;
// EPI 4: merged cross q/k/v (z=0: A scaled; z=1/2: A2 @ Bt2[+(z-1)*768*768]; out += z*768);
// EPI 5: split-K bf16 partials (z selects K-chunk of nk steps; Cb += z*4096*768).
template<int EPI>
__global__ void __launch_bounds__(256)
gemm_bf16(const u16* __restrict__ A, int lda, const u16* __restrict__ Bt, int ldb,
          int nk, u16* __restrict__ Cb, int ldc,
          const float* __restrict__ bias,
          const u16* __restrict__ A2, const u16* __restrict__ Bt2){
  __shared__ u16 As[2][128 * 32];
  __shared__ u16 Bs[2][128 * 32];
  float colscale = 1.0f;
  if constexpr (EPI == 4){
    const int z = blockIdx.z;
    if (z == 0){ colscale = QSCALE_CONST; }
    else { A = A2; Bt = Bt2 + (size_t)(z - 1) * 768 * 768; }
    Cb += z * 768;
  }
  if constexpr (EPI == 5){
    const int z = blockIdx.z;
    A  += (size_t)z * nk * 32;
    Bt += (size_t)z * nk * 32;
    Cb += (size_t)z * 4096 * 768;
  }
  // bijective XCD-chunked swizzle (m204) on the 2D slice
  const int gx = gridDim.x, nwg = gx * gridDim.y;
  int lin = blockIdx.y * gx + blockIdx.x;
  {
    const int qq = nwg >> 3, rr = nwg & 7;
    const int xc = lin & 7, oo = lin >> 3;
    lin = (xc < rr ? xc * (qq + 1) : rr * (qq + 1) + (xc - rr) * qq) + oo;
  }
  const int m0 = (lin % gx) * 128, n0 = (lin / gx) * 128;

  const int tid = threadIdx.x, w = tid >> 6, lane = tid & 63;
  const int l16 = lane & 15, g = lane >> 4;
  const int wm = (w >> 1) * 64, wn = (w & 1) * 64;
  f32x4 acc[4][4] = {};

  const u16* a0 = A  + (size_t)(m0 + (tid >> 2)) * lda + (tid & 3) * 8;
  const u16* a1 = A  + (size_t)(m0 + (tid >> 2) + 64) * lda + (tid & 3) * 8;
  const u16* b0 = Bt + (size_t)(n0 + (tid >> 2)) * ldb + (tid & 3) * 8;
  const u16* b1 = Bt + (size_t)(n0 + (tid >> 2) + 64) * ldb + (tid & 3) * 8;

  {
    char* ab = (char*)As[0]; char* bb = (char*)Bs[0];
    gld16(a0, ab + w * 1024); gld16(a1, ab + 4096 + w * 1024);
    gld16(b0, bb + w * 1024); gld16(b1, bb + 4096 + w * 1024);
  }
  __syncthreads();

  int cb = 0;
  for (int kt = 0; kt < nk; ++kt){
    if (kt + 1 < nk){
      const int k1 = (kt + 1) * 32;
      char* ab = (char*)As[cb ^ 1]; char* bb = (char*)Bs[cb ^ 1];
      gld16(a0 + k1, ab + w * 1024); gld16(a1 + k1, ab + 4096 + w * 1024);
      gld16(b0 + k1, bb + w * 1024); gld16(b1 + k1, bb + 4096 + w * 1024);
    }
    const u16* Ab = As[cb]; const u16* Bb = Bs[cb];
    s16x8 af[4], bfv[4];
#pragma unroll
    for (int mi = 0; mi < 4; ++mi)
      af[mi] = *(const s16x8*)(Ab + (wm + mi*16 + l16) * 32 + 8 * g);
#pragma unroll
    for (int ni = 0; ni < 4; ++ni)
      bfv[ni] = *(const s16x8*)(Bb + (wn + ni*16 + l16) * 32 + 8 * g);
#pragma unroll
    for (int mi = 0; mi < 4; ++mi)
#pragma unroll
      for (int ni = 0; ni < 4; ++ni)
        acc[mi][ni] = mfma16(af[mi], bfv[ni], acc[mi][ni]);
    __syncthreads();
    cb ^= 1;
  }

  // epilogue: C/D layout col = lane&15, row = 4*(lane>>4)+r
#pragma unroll
  for (int mi = 0; mi < 4; ++mi){
    const int rg = m0 + wm + mi*16 + 4*g;
#pragma unroll
    for (int ni = 0; ni < 4; ++ni){
      const int col = n0 + wn + ni*16 + l16;
      f32x4 v = acc[mi][ni];
#pragma unroll
      for (int r = 0; r < 4; ++r){
        const int row = rg + r;
        if constexpr (EPI == 2){
          float t = v[r] + bias[col];
          float ge = 0.5f * t * (1.0f + erff(t * 0.7071067811865476f));
          Cb[(size_t)row * ldc + col] = f2bf(ge);
        } else if constexpr (EPI == 3){
          float sc = (col < 768) ? QSCALE_CONST : 1.0f;
          Cb[(size_t)row * ldc + col] = f2bf(v[r] * sc);
        } else if constexpr (EPI == 4){
          Cb[(size_t)row * ldc + col] = f2bf(v[r] * colscale);
        } else {
          Cb[(size_t)row * 768 + col] = f2bf(v[r]);
        }
      }
    }
  }
}

// ---------------- fused flash attention v5.1: fp8 bias regs, setprio, tree-max ---------
__global__ void __launch_bounds__(256)
attn_kernel(const u16* __restrict__ qkv, const unsigned char* __restrict__ biasT,
            u16* __restrict__ out){
  __shared__ __align__(16) u16 Ks[2][4096];
  __shared__ __align__(16) u16 Vt[2][4096];
  __shared__ __align__(16) u16 Pl[4][1024];

  const int tid = threadIdx.x, w = tid >> 6, lane = tid & 63;
  const int l16 = lane & 15, g = lane >> 4;
  const int qt = blockIdx.x, h = blockIdx.y, b = blockIdx.z;
  const int rowbase = b * 2048, q0 = qt * 64;

  const int ci0 = w * 64 + lane, ci1 = ci0 + 256;
  const int r0 = ci0 >> 3, sc0 = ci0 & 7, r1 = ci1 >> 3, sc1 = ci1 & 7;
  const u16* kp0 = qkv + (size_t)(rowbase + r0) * 2304 + 768 + h * 64 + (((sc0 ^ (r0 & 7)) & 7) << 3);
  const u16* kp1 = qkv + (size_t)(rowbase + r1) * 2304 + 768 + h * 64 + (((sc1 ^ (r1 & 7)) & 7) << 3);
  const int dh0 = (tid & 31) * 2, vs = tid >> 5;
  const u16* vp = qkv + (size_t)(rowbase + vs * 8) * 2304 + 1536 + h * 64 + dh0;
  u16x2 vr[8];
  const unsigned char* bT = biasT + ((size_t)(h * 32 + qt) * 32) * 4096 + tid * 16;
  u32x4 brW, bnW;

  const u16* qrow = qkv + (size_t)(rowbase + q0 + w * 16 + l16) * 2304 + h * 64;
  s16x8 qf0 = *(const s16x8*)(qrow + 8 * g);
  s16x8 qf1 = *(const s16x8*)(qrow + 32 + 8 * g);

  f32x4 oacc[4] = {};
  float mrun = -3.0e38f, lrun = 0.f;
  const int sw = l16 & 7;

  {
    char* kb = (char*)Ks[0] + w * 1024;
    gld16(kp0, kb); gld16(kp1, kb + 4096);
#pragma unroll
    for (int i = 0; i < 8; ++i) vr[i] = *(const u16x2*)(vp + (size_t)i * 2304);
    brW = *(const u32x4*)(bT);
    s16x8 vA, vB;
#pragma unroll
    for (int j = 0; j < 8; ++j){ vA[j] = (short)vr[j][0]; vB[j] = (short)vr[j][1]; }
    *(s16x8*)(Vt[0] + dh0 * 64 + ((vs ^ (dh0 & 7)) << 3)) = vA;
    *(s16x8*)(Vt[0] + (dh0 + 1) * 64 + ((vs ^ ((dh0 + 1) & 7)) << 3)) = vB;
  }
  __syncthreads();

  for (int t = 0; t < 32; ++t){
    const int cb = t & 1;
    if (t < 31){
      const size_t koff = (size_t)(t + 1) * 64 * 2304;
      char* kb = (char*)Ks[cb ^ 1] + w * 1024;
      gld16(kp0 + koff, kb); gld16(kp1 + koff, kb + 4096);
      const u16* p = vp + koff;
#pragma unroll
      for (int i = 0; i < 8; ++i) vr[i] = *(const u16x2*)(p + (size_t)i * 2304);
      bnW = *(const u32x4*)(bT + (size_t)(t + 1) * 4096);
    }

    f32x4 st[4];
    __builtin_amdgcn_s_setprio(1);
#pragma unroll
    for (int mi = 0; mi < 4; ++mi){
      const int row = l16 + 16 * mi;
      s16x8 kf0 = *(const s16x8*)(Ks[cb] + row * 64 + ((g ^ sw) << 3));
      s16x8 kf1 = *(const s16x8*)(Ks[cb] + row * 64 + (((g + 4) ^ sw) << 3));
      f32x4 z = {};
      z = mfma16(kf0, qf0, z);
      st[mi] = mfma16(kf1, qf1, z);
    }
    __builtin_amdgcn_s_setprio(0);

    float mloc[4];
#pragma unroll
    for (int mi = 0; mi < 4; ++mi){
      f32x2 lo = upk_fp8<false>(brW[mi]);
      f32x2 hi = upk_fp8<true>(brW[mi]);
      st[mi][0] = fmaf(lo[0], BINV, st[mi][0]);
      st[mi][1] = fmaf(lo[1], BINV, st[mi][1]);
      st[mi][2] = fmaf(hi[0], BINV, st[mi][2]);
      st[mi][3] = fmaf(hi[1], BINV, st[mi][3]);
      mloc[mi] = fmaxf(fmaxf(st[mi][0], st[mi][1]), fmaxf(st[mi][2], st[mi][3]));
    }
    float tmax = fmaxf(fmaxf(mloc[0], mloc[1]), fmaxf(mloc[2], mloc[3]));
    tmax = fmaxf(tmax, __shfl_xor(tmax, 16));
    tmax = fmaxf(tmax, __shfl_xor(tmax, 32));
    if (!__all(tmax <= mrun + 8.f)){
      float mnew = fmaxf(mrun, tmax);
      float al = fexp2(mrun - mnew);
      mrun = mnew;
      lrun *= al;
#pragma unroll
      for (int r = 0; r < 4; ++r){
        float aq = __shfl(al, 4 * g + r);
#pragma unroll
        for (int ni = 0; ni < 4; ++ni) oacc[ni][r] *= aq;
      }
    }
    float ssum = 0.f;
#pragma unroll
    for (int mi = 0; mi < 4; ++mi){
      u16x4 pk;
#pragma unroll
      for (int r = 0; r < 4; ++r){
        float pv = fexp2(st[mi][r] - mrun);
        ssum += pv;
        pk[r] = f2bf(pv);
      }
      *(u16x4*)(Pl[w] + l16 * 64 + (((2*mi + (g >> 1)) ^ sw) << 3) + 4 * (g & 1)) = pk;
    }
    ssum += __shfl_xor(ssum, 16);
    ssum += __shfl_xor(ssum, 32);
    lrun += ssum;

    __builtin_amdgcn_s_setprio(1);
#pragma unroll
    for (int ks2 = 0; ks2 < 2; ++ks2){
      s16x8 pf = *(const s16x8*)(Pl[w] + l16 * 64 + (((4*ks2 + g) ^ sw) << 3));
#pragma unroll
      for (int ni = 0; ni < 4; ++ni){
        const int dh = l16 + 16 * ni;
        s16x8 vf = *(const s16x8*)(Vt[cb] + dh * 64 + (((4*ks2 + g) ^ sw) << 3));
        oacc[ni] = mfma16(pf, vf, oacc[ni]);
      }
    }
    __builtin_amdgcn_s_setprio(0);

    if (t < 31){
      s16x8 vA, vB;
#pragma unroll
      for (int j = 0; j < 8; ++j){ vA[j] = (short)vr[j][0]; vB[j] = (short)vr[j][1]; }
      *(s16x8*)(Vt[cb ^ 1] + dh0 * 64 + ((vs ^ (dh0 & 7)) << 3)) = vA;
      *(s16x8*)(Vt[cb ^ 1] + (dh0 + 1) * 64 + ((vs ^ ((dh0 + 1) & 7)) << 3)) = vB;
      brW = bnW;
    }
    __syncthreads();
  }

#pragma unroll
  for (int r = 0; r < 4; ++r){
    float lq = __shfl(lrun, 4 * g + r);
    float inv = 1.0f / lq;
    const int row = rowbase + q0 + w * 16 + 4 * g + r;
#pragma unroll
    for (int ni = 0; ni < 4; ++ni)
      out[(size_t)row * 768 + h * 64 + l16 + 16 * ni] = f2bf(oacc[ni][r] * inv);
  }
}

// ============================== host ==============================
extern "C" void kernel_launch(void* const* d_in, const int* in_sizes, int n_in,
                              void* d_out, int out_size, void* d_ws, size_t ws_size,
                              hipStream_t stream){
  const float* in_x    = (const float*)d_in[0];
  const float* in_ctx  = (const float*)d_in[1];
  const float* in_bias = (const float*)d_in[2];
  const float* ln1_w = (const float*)d_in[3];
  const float* ln1_b = (const float*)d_in[4];
  const float* w_qkv = (const float*)d_in[5];
  const float* w_so  = (const float*)d_in[6];
  const float* b_so  = (const float*)d_in[7];
  const float* ln2_w = (const float*)d_in[8];
  const float* ln2_b = (const float*)d_in[9];
  const float* w_q   = (const float*)d_in[10];
  const float* w_k   = (const float*)d_in[11];
  const float* w_v   = (const float*)d_in[12];
  const float* w_co  = (const float*)d_in[13];
  const float* b_co  = (const float*)d_in[14];
  const float* ln3_w = (const float*)d_in[15];
  const float* ln3_b = (const float*)d_in[16];
  const float* w_f1  = (const float*)d_in[17];
  const float* b_f1  = (const float*)d_in[18];
  const float* w_f2  = (const float*)d_in[19];
  const float* b_f2  = (const float*)d_in[20];
  const float* lnout_w = (const float*)d_in[21];
  const float* lnout_b = (const float*)d_in[22];

  char* p = (char*)d_ws;
  u16* xbuf    = (u16*)p;    p += 4096ll * 768 * 2;        // bf16 residual stream
  u16* pbuf    = (u16*)p;    p += 4ll * 4096 * 768 * 2;    // split-K bf16 partials
  u16* xn      = (u16*)p;    p += 4096ll * 768 * 2;
  u16* cn      = (u16*)p;    p += 4ll * 4096 * 768 * 2;    // per-layer LN(context)
  u16* qkvb    = (u16*)p;    p += 4096ll * 2304 * 2;
  u16* attO    = (u16*)p;    p += 4096ll * 768 * 2;
  u16* ffh     = (u16*)p;    p += 4096ll * 3072 * 2;
  u16* wqkvT   = (u16*)p;    p += 4ll * 2304 * 768 * 2;
  u16* wsoT    = (u16*)p;    p += 4ll * 768 * 768 * 2;
  u16* wqT     = (u16*)p;    p += 4ll * 768 * 768 * 2;
  u16* wkvT    = (u16*)p;    p += 4ll * 1536 * 768 * 2;
  u16* wcoT    = (u16*)p;    p += 4ll * 768 * 768 * 2;
  u16* wf1T    = (u16*)p;    p += 4ll * 3072 * 768 * 2;
  u16* wf2T    = (u16*)p;    p += 4ll * 768 * 3072 * 2;
  unsigned char* biasT = (unsigned char*)p; p += 12ll * 2048 * 2048;

  const dim3 tb(32, 8);
  transpose_cvt<<<dim3(72, 24, 4), tb, 0, stream>>>(w_qkv, wqkvT, 768, 2304, 2304ll*768);
  transpose_cvt<<<dim3(96, 24, 4), tb, 0, stream>>>(w_f1,  wf1T,  768, 3072, 3072ll*768);
  transpose_cvt<<<dim3(24, 96, 4), tb, 0, stream>>>(w_f2,  wf2T,  3072, 768, 768ll*3072);
  {
    TPtrs tp;
    for (int i = 0; i < 4; ++i){
      tp.src[i*5+0] = w_so + (size_t)i*768*768;  tp.dst[i*5+0] = wsoT + (size_t)i*768*768;
      tp.src[i*5+1] = w_q  + (size_t)i*768*768;  tp.dst[i*5+1] = wqT  + (size_t)i*768*768;
      tp.src[i*5+2] = w_k  + (size_t)i*768*768;  tp.dst[i*5+2] = wkvT + (size_t)i*1536*768;
      tp.src[i*5+3] = w_v  + (size_t)i*768*768;  tp.dst[i*5+3] = wkvT + (size_t)i*1536*768 + 768ll*768;
      tp.src[i*5+4] = w_co + (size_t)i*768*768;  tp.dst[i*5+4] = wcoT + (size_t)i*768*768;
    }
    transpose_cvt_batch<<<dim3(24, 24, 20), tb, 0, stream>>>(tp);
  }
  cvt_biasT<<<dim3(32, 32, 12), 256, 0, stream>>>(in_bias, biasT);
  ln_pre<<<dim3(1024, 2), 256, 0, stream>>>(in_x, in_ctx, ln1_w, ln1_b, ln2_w, ln2_b,
                                            xn, xbuf, cn);

  const dim3 ag(32, 12, 2);
  for (int i = 0; i < 4; ++i){
    // self-attention block
    gemm_bf16<3><<<dim3(32, 18), 256, 0, stream>>>(xn, 768, wqkvT + (size_t)i*2304*768, 768, 24,
                                                   qkvb, 2304, nullptr, nullptr, nullptr);
    attn_kernel<<<ag, 256, 0, stream>>>(qkvb, biasT, attO);
    gemm_bf16<5><<<dim3(32, 6, 2), 256, 0, stream>>>(attO, 768, wsoT + (size_t)i*768*768, 768, 12,
                                                     pbuf, 768, nullptr, nullptr, nullptr);
    red_ln<u16,2><<<512, 256, 0, stream>>>(pbuf, b_so + i*768, xbuf, xn, ln2_w + i*768, ln2_b + i*768);
    // cross-attention block (merged q/k/v projection)
    gemm_bf16<4><<<dim3(32, 6, 3), 256, 0, stream>>>(xn, 768, wqT + (size_t)i*768*768, 768, 24,
                                                     qkvb, 2304, nullptr,
                                                     cn + (size_t)i*4096*768, wkvT + (size_t)i*1536*768);
    attn_kernel<<<ag, 256, 0, stream>>>(qkvb, biasT, attO);
    gemm_bf16<5><<<dim3(32, 6, 2), 256, 0, stream>>>(attO, 768, wcoT + (size_t)i*768*768, 768, 12,
                                                     pbuf, 768, nullptr, nullptr, nullptr);
    red_ln<u16,2><<<512, 256, 0, stream>>>(pbuf, b_co + i*768, xbuf, xn, ln3_w + i*768, ln3_b + i*768);
    // FFN block
    gemm_bf16<2><<<dim3(32, 24), 256, 0, stream>>>(xn, 768, wf1T + (size_t)i*3072*768, 768, 24,
                                                   ffh, 3072, b_f1 + i*3072, nullptr, nullptr);
    gemm_bf16<5><<<dim3(32, 6, 4), 256, 0, stream>>>(ffh, 3072, wf2T + (size_t)i*768*3072, 3072, 24,
                                                     pbuf, 768, nullptr, nullptr, nullptr);
    if (i < 3)
      red_ln<u16,4><<<512, 256, 0, stream>>>(pbuf, b_f2 + i*768, xbuf, xn, ln1_w + (i+1)*768, ln1_b + (i+1)*768);
    else
      red_ln<float,4><<<512, 256, 0, stream>>>(pbuf, b_f2 + i*768, xbuf, (float*)d_out, lnout_w, lnout_b);
  }
}